// Round 1
// baseline (1142.940 us; speedup 1.0000x reference)
//
#include <hip/hip_runtime.h>

enum { EP_NONE = 0, EP_MEAN_RELU = 1, EP_BIAS = 2 };

// Y[n,OUTC] = X[n,K] @ W[K,OUTC]  (+ optional epilogue)
// EP_MEAN_RELU: Y = relu(X@W + agg/max(deg,1) + bias)
// EP_BIAS:      Y = X@W + bias
template<int K, int OUTC, int EP>
__global__ __launch_bounds__(256)
void gemm_ep(const float* __restrict__ X, const float* __restrict__ W,
             const float* __restrict__ bias, const float* __restrict__ agg,
             const float* __restrict__ deg, float* __restrict__ Y, int n)
{
    __shared__ float sW[K * OUTC];
    __shared__ float sX[4][K];
    for (int i = threadIdx.x; i < K * OUTC; i += 256) sW[i] = W[i];
    __syncthreads();

    const int lane = threadIdx.x & 63;
    const int wid  = threadIdx.x >> 6;
    const int gw   = blockIdx.x * 4 + wid;
    const int nw   = gridDim.x * 4;
    constexpr int OPL = (OUTC + 63) / 64;

    for (int row = gw; row < n; row += nw) {
        const float* xrow = X + (size_t)row * K;
        #pragma unroll
        for (int i = lane; i < K; i += 64) sX[wid][i] = xrow[i];
        // wave-local LDS write->read: drain LDS queue (no cross-wave dep, no barrier)
        asm volatile("s_waitcnt lgkmcnt(0)" ::: "memory");

        float acc[OPL];
        #pragma unroll
        for (int c = 0; c < OPL; ++c) acc[c] = 0.f;

        #pragma unroll 8
        for (int k = 0; k < K; ++k) {
            float xk = sX[wid][k];            // LDS broadcast (same addr, all lanes)
            #pragma unroll
            for (int c = 0; c < OPL; ++c) {
                int col = lane + c * 64;
                if (col < OUTC) acc[c] += xk * sW[k * OUTC + col];
            }
        }

        #pragma unroll
        for (int c = 0; c < OPL; ++c) {
            int col = lane + c * 64;
            if (col < OUTC) {
                float v = acc[c];
                if (EP == EP_MEAN_RELU) {
                    float d = deg[row];
                    d = d > 1.f ? d : 1.f;
                    v += agg[(size_t)row * OUTC + col] / d + bias[col];
                    v = v > 0.f ? v : 0.f;
                } else if (EP == EP_BIAS) {
                    v += bias[col];
                }
                Y[(size_t)row * OUTC + col] = v;
            }
        }
    }
}

// agg[dst,:] += feat[src,:]  for each edge; 64 feats, lane = feature
__global__ __launch_bounds__(256)
void scatter_add64(const float* __restrict__ feat, const int* __restrict__ srcIdx,
                   const int* __restrict__ dstIdx, float* __restrict__ agg, int E)
{
    const int lane = threadIdx.x & 63;
    const int wid  = threadIdx.x >> 6;
    long w  = (long)blockIdx.x * 4 + wid;
    long nw = (long)gridDim.x * 4;
    for (long e = w; e < E; e += nw) {
        int s = srcIdx[e];
        int d = dstIdx[e];
        float v = feat[(size_t)s * 64 + lane];
        atomicAdd(&agg[(size_t)d * 64 + lane], v);
    }
}

__global__ __launch_bounds__(256)
void deg_kernel(const int* __restrict__ dstIdx, float* __restrict__ deg, int E)
{
    for (long i = (long)blockIdx.x * blockDim.x + threadIdx.x; i < E;
         i += (long)gridDim.x * blockDim.x)
        atomicAdd(&deg[dstIdx[i]], 1.0f);
}

extern "C" void kernel_launch(void* const* d_in, const int* in_sizes, int n_in,
                              void* d_out, int out_size, void* d_ws, size_t ws_size,
                              hipStream_t stream)
{
    const float* x   = (const float*)d_in[0];
    const int*   ei  = (const int*)d_in[1];
    const float* W1l = (const float*)d_in[2];
    const float* b1  = (const float*)d_in[3];
    const float* W1r = (const float*)d_in[4];
    const float* W2l = (const float*)d_in[5];
    const float* b2  = (const float*)d_in[6];
    const float* W2r = (const float*)d_in[7];
    const float* Wo  = (const float*)d_in[8];
    const float* bo  = (const float*)d_in[9];
    float* out = (float*)d_out;

    const int n = in_sizes[0] / 128;
    const int E = in_sizes[1] / 2;
    const int* srcI = ei;
    const int* dstI = ei + E;

    float* A   = (float*)d_ws;               // n*64  (transformed feats / h2)
    float* B   = A + (size_t)n * 64;         // n*64  (aggregation buffer)
    float* H   = B + (size_t)n * 64;         // n*64  (h1)
    float* deg = H + (size_t)n * 64;         // n

    hipMemsetAsync(deg, 0, (size_t)n * sizeof(float), stream);
    hipMemsetAsync(B,   0, (size_t)n * 64 * sizeof(float), stream);
    deg_kernel<<<1024, 256, 0, stream>>>(dstI, deg, E);

    // ---- layer 1 ----
    gemm_ep<128, 64, EP_NONE><<<2048, 256, 0, stream>>>(x, W1l, nullptr, nullptr, nullptr, A, n);
    scatter_add64<<<4096, 256, 0, stream>>>(A, srcI, dstI, B, E);
    gemm_ep<128, 64, EP_MEAN_RELU><<<2048, 256, 0, stream>>>(x, W1r, b1, B, deg, H, n);

    // ---- layer 2 ----
    hipMemsetAsync(B, 0, (size_t)n * 64 * sizeof(float), stream);
    gemm_ep<64, 64, EP_NONE><<<2048, 256, 0, stream>>>(H, W2l, nullptr, nullptr, nullptr, A, n);
    scatter_add64<<<4096, 256, 0, stream>>>(A, srcI, dstI, B, E);
    gemm_ep<64, 64, EP_MEAN_RELU><<<2048, 256, 0, stream>>>(H, W2r, b2, B, deg, A, n);

    // ---- output projection ----
    gemm_ep<64, 112, EP_BIAS><<<2048, 256, 0, stream>>>(A, Wo, bo, nullptr, nullptr, out, n);
}

// Round 2
// 694.541 us; speedup vs baseline: 1.6456x; 1.6456x over previous
//
#include <hip/hip_runtime.h>

// ---------------- CSR build ----------------

__global__ __launch_bounds__(256)
void deg_int_kernel(const int* __restrict__ dstIdx, int* __restrict__ degi, int E)
{
    for (long i = (long)blockIdx.x * blockDim.x + threadIdx.x; i < E;
         i += (long)gridDim.x * blockDim.x)
        atomicAdd(&degi[dstIdx[i]], 1);
}

// chunk = 1024 nodes per block (256 thr x 4). Writes chunk-local exclusive scan
// into rowptr and chunk total into partial[b].
__global__ __launch_bounds__(256)
void scan_chunk(const int* __restrict__ degi, int* __restrict__ rowptr,
                int* __restrict__ partial, int n)
{
    __shared__ int s[256];
    const int b = blockIdx.x, t = threadIdx.x;
    const int base = b * 1024 + t * 4;
    int v[4], sum = 0;
    #pragma unroll
    for (int j = 0; j < 4; ++j) {
        int idx = base + j;
        v[j] = (idx < n) ? degi[idx] : 0;
        sum += v[j];
    }
    s[t] = sum;
    __syncthreads();
    #pragma unroll
    for (int off = 1; off < 256; off <<= 1) {
        int x = (t >= off) ? s[t - off] : 0;
        __syncthreads();
        s[t] += x;
        __syncthreads();
    }
    int run = s[t] - sum;                 // exclusive prefix for this thread
    if (t == 255) partial[b] = s[255];
    #pragma unroll
    for (int j = 0; j < 4; ++j) {
        int idx = base + j;
        if (idx < n) { rowptr[idx] = run; run += v[j]; }
    }
}

__global__ void scan_partials(int* partial, int nchunk)
{
    if (blockIdx.x == 0 && threadIdx.x == 0) {
        int acc = 0;
        for (int i = 0; i < nchunk; ++i) { int p = partial[i]; partial[i] = acc; acc += p; }
    }
}

__global__ __launch_bounds__(256)
void finalize_rowptr(int* __restrict__ rowptr, const int* __restrict__ partial,
                     int* __restrict__ cursor, int n, int E)
{
    int i = blockIdx.x * blockDim.x + threadIdx.x;
    if (i < n) {
        int v = rowptr[i] + partial[i >> 10];
        rowptr[i] = v;
        cursor[i] = v;
    }
    if (i == n) rowptr[n] = E;
}

__global__ __launch_bounds__(256)
void csr_fill(const int* __restrict__ srcIdx, const int* __restrict__ dstIdx,
              int* __restrict__ cursor, int* __restrict__ csr, int E)
{
    for (long i = (long)blockIdx.x * blockDim.x + threadIdx.x; i < E;
         i += (long)gridDim.x * blockDim.x) {
        int p = atomicAdd(&cursor[dstIdx[i]], 1);
        csr[p] = srcIdx[i];
    }
}

// ---------------- pull aggregation (sum; mean applied later) ----------------
// wave per dst node, lane = feature (64)
__global__ __launch_bounds__(256)
void pull_agg(const float* __restrict__ feat, const int* __restrict__ rowptr,
              const int* __restrict__ csr, float* __restrict__ B, int n)
{
    const int lane = threadIdx.x & 63;
    const int wid  = threadIdx.x >> 6;
    const long w   = (long)blockIdx.x * 4 + wid;
    const long nw  = (long)gridDim.x * 4;
    for (long row = w; row < n; row += nw) {
        const int s = rowptr[row], e = rowptr[row + 1];
        float acc = 0.f;
        int i = s;
        for (; i + 4 <= e; i += 4) {
            int s0 = csr[i], s1 = csr[i + 1], s2 = csr[i + 2], s3 = csr[i + 3];
            float v0 = feat[(size_t)s0 * 64 + lane];
            float v1 = feat[(size_t)s1 * 64 + lane];
            float v2 = feat[(size_t)s2 * 64 + lane];
            float v3 = feat[(size_t)s3 * 64 + lane];
            acc += v0; acc += v1; acc += v2; acc += v3;
        }
        for (; i < e; ++i) acc += feat[(size_t)csr[i] * 64 + lane];
        B[(size_t)row * 64 + lane] = acc;
    }
}

// ---------------- GEMMs ----------------

// Yl = X@Wl, Yr = X@Wr  (K x 64 weights each, interleaved in LDS)
template<int K>
__global__ __launch_bounds__(256)
void dual_gemm(const float* __restrict__ X, const float* __restrict__ Wl,
               const float* __restrict__ Wr, float* __restrict__ Yl,
               float* __restrict__ Yr, int n)
{
    __shared__ float sW[K * 64 * 2];
    for (int i = threadIdx.x; i < K * 64; i += 256) {
        sW[i * 2]     = Wl[i];
        sW[i * 2 + 1] = Wr[i];
    }
    __syncthreads();

    const int lane = threadIdx.x & 63;
    const int wid  = threadIdx.x >> 6;
    const int gw   = blockIdx.x * 4 + wid;
    const int nw   = gridDim.x * 4;

    for (int row = gw; row < n; row += nw) {
        const float* __restrict__ xrow = X + (size_t)row * K;   // wave-uniform
        float accl = 0.f, accr = 0.f;
        #pragma unroll 16
        for (int k = 0; k < K; ++k) {
            float xk = xrow[k];
            float2 w = *reinterpret_cast<const float2*>(&sW[((size_t)k * 64 + lane) * 2]);
            accl += xk * w.x;
            accr += xk * w.y;
        }
        Yl[(size_t)row * 64 + lane] = accl;
        Yr[(size_t)row * 64 + lane] = accr;
    }
}

// out = X@Wo + bo  (K=64, OUTC=112)
__global__ __launch_bounds__(256)
void gemm_out(const float* __restrict__ X, const float* __restrict__ W,
              const float* __restrict__ bias, float* __restrict__ Y, int n)
{
    constexpr int K = 64, OUTC = 112;
    __shared__ float sW[K * OUTC];
    for (int i = threadIdx.x; i < K * OUTC; i += 256) sW[i] = W[i];
    __syncthreads();

    const int lane = threadIdx.x & 63;
    const int wid  = threadIdx.x >> 6;
    const int gw   = blockIdx.x * 4 + wid;
    const int nw   = gridDim.x * 4;

    for (int row = gw; row < n; row += nw) {
        const float* __restrict__ xrow = X + (size_t)row * K;   // wave-uniform
        float acc0 = 0.f, acc1 = 0.f;
        const int c1 = lane + 64;
        #pragma unroll 16
        for (int k = 0; k < K; ++k) {
            float xk = xrow[k];
            acc0 += xk * sW[k * OUTC + lane];
            if (c1 < OUTC) acc1 += xk * sW[k * OUTC + c1];
        }
        Y[(size_t)row * OUTC + lane] = acc0 + bias[lane];
        if (c1 < OUTC) Y[(size_t)row * OUTC + c1] = acc1 + bias[c1];
    }
}

// ---------------- elementwise: H = relu(B/deg + C + bias) ----------------
__global__ __launch_bounds__(256)
void mean_relu4(const float4* __restrict__ B, const float4* __restrict__ C,
                const float* __restrict__ bias, const int* __restrict__ degi,
                float4* __restrict__ H, long n4)
{
    for (long i = (long)blockIdx.x * blockDim.x + threadIdx.x; i < n4;
         i += (long)gridDim.x * blockDim.x) {
        long row = i >> 4;
        int colb = (int)(i & 15) * 4;
        float d = (float)degi[row];
        d = d > 1.f ? d : 1.f;
        float inv = 1.f / d;
        float4 b = B[i], c = C[i], r;
        r.x = b.x * inv + c.x + bias[colb + 0];
        r.y = b.y * inv + c.y + bias[colb + 1];
        r.z = b.z * inv + c.z + bias[colb + 2];
        r.w = b.w * inv + c.w + bias[colb + 3];
        r.x = r.x > 0.f ? r.x : 0.f;
        r.y = r.y > 0.f ? r.y : 0.f;
        r.z = r.z > 0.f ? r.z : 0.f;
        r.w = r.w > 0.f ? r.w : 0.f;
        H[i] = r;
    }
}

// ---------------- launch ----------------

extern "C" void kernel_launch(void* const* d_in, const int* in_sizes, int n_in,
                              void* d_out, int out_size, void* d_ws, size_t ws_size,
                              hipStream_t stream)
{
    const float* x   = (const float*)d_in[0];
    const int*   ei  = (const int*)d_in[1];
    const float* W1l = (const float*)d_in[2];
    const float* b1  = (const float*)d_in[3];
    const float* W1r = (const float*)d_in[4];
    const float* W2l = (const float*)d_in[5];
    const float* b2  = (const float*)d_in[6];
    const float* W2r = (const float*)d_in[7];
    const float* Wo  = (const float*)d_in[8];
    const float* bo  = (const float*)d_in[9];
    float* out = (float*)d_out;

    const int n = in_sizes[0] / 128;
    const int E = in_sizes[1] / 2;
    const int* srcI = ei;
    const int* dstI = ei + E;
    const int nchunk = (n + 1023) / 1024;

    float* A      = (float*)d_ws;                 // n*64
    float* B      = A + (size_t)n * 64;           // n*64
    float* C      = B + (size_t)n * 64;           // n*64
    int*   degi   = (int*)(C + (size_t)n * 64);   // n
    int*   rowptr = degi + n;                     // n+1
    int*   cursor = rowptr + n + 1;               // n
    int*   partial= cursor + n;                   // nchunk
    int*   csr    = partial + nchunk + 1;         // E

    // ---- CSR build (shared by both layers) ----
    hipMemsetAsync(degi, 0, (size_t)n * sizeof(int), stream);
    deg_int_kernel<<<1024, 256, 0, stream>>>(dstI, degi, E);
    scan_chunk<<<nchunk, 256, 0, stream>>>(degi, rowptr, partial, n);
    scan_partials<<<1, 64, 0, stream>>>(partial, nchunk);
    finalize_rowptr<<<(n + 256) / 256, 256, 0, stream>>>(rowptr, partial, cursor, n, E);
    csr_fill<<<2048, 256, 0, stream>>>(srcI, dstI, cursor, csr, E);

    // ---- layer 1 ----
    dual_gemm<128><<<2048, 256, 0, stream>>>(x, W1l, W1r, A, C, n);   // A=x@W1l, C=x@W1r
    pull_agg<<<4096, 256, 0, stream>>>(A, rowptr, csr, B, n);          // B=sum_neigh(A)
    mean_relu4<<<2048, 256, 0, stream>>>((const float4*)B, (const float4*)C, b1, degi,
                                         (float4*)A, (long)n * 16);    // A=h1

    // ---- layer 2 ----
    dual_gemm<64><<<2048, 256, 0, stream>>>(A, W2l, W2r, B, C, n);     // B=h1@W2l, C=h1@W2r
    pull_agg<<<4096, 256, 0, stream>>>(B, rowptr, csr, A, n);          // A=sum_neigh(B)
    mean_relu4<<<2048, 256, 0, stream>>>((const float4*)A, (const float4*)C, b2, degi,
                                         (float4*)B, (long)n * 16);    // B=h2

    // ---- output projection ----
    gemm_out<<<2048, 256, 0, stream>>>(B, Wo, bo, out, n);
}

// Round 3
// 539.963 us; speedup vs baseline: 2.1167x; 1.2863x over previous
//
#include <hip/hip_runtime.h>

// ---------------- CSR build ----------------

__global__ __launch_bounds__(256)
void deg_int_kernel(const int* __restrict__ dstIdx, int* __restrict__ degi, int E)
{
    for (long i = (long)blockIdx.x * blockDim.x + threadIdx.x; i < E;
         i += (long)gridDim.x * blockDim.x)
        atomicAdd(&degi[dstIdx[i]], 1);
}

__global__ __launch_bounds__(256)
void scan_chunk(const int* __restrict__ degi, int* __restrict__ rowptr,
                int* __restrict__ partial, int n)
{
    __shared__ int s[256];
    const int b = blockIdx.x, t = threadIdx.x;
    const int base = b * 1024 + t * 4;
    int v[4], sum = 0;
    #pragma unroll
    for (int j = 0; j < 4; ++j) {
        int idx = base + j;
        v[j] = (idx < n) ? degi[idx] : 0;
        sum += v[j];
    }
    s[t] = sum;
    __syncthreads();
    #pragma unroll
    for (int off = 1; off < 256; off <<= 1) {
        int x = (t >= off) ? s[t - off] : 0;
        __syncthreads();
        s[t] += x;
        __syncthreads();
    }
    int run = s[t] - sum;
    if (t == 255) partial[b] = s[255];
    #pragma unroll
    for (int j = 0; j < 4; ++j) {
        int idx = base + j;
        if (idx < n) { rowptr[idx] = run; run += v[j]; }
    }
}

__global__ void scan_partials(int* partial, int nchunk)
{
    if (blockIdx.x == 0 && threadIdx.x == 0) {
        int acc = 0;
        for (int i = 0; i < nchunk; ++i) { int p = partial[i]; partial[i] = acc; acc += p; }
    }
}

__global__ __launch_bounds__(256)
void finalize_rowptr(int* __restrict__ rowptr, const int* __restrict__ partial,
                     int* __restrict__ cursor, int n, int E)
{
    int i = blockIdx.x * blockDim.x + threadIdx.x;
    if (i < n) {
        int v = rowptr[i] + partial[i >> 10];
        rowptr[i] = v;
        cursor[i] = v;
    }
    if (i == n) rowptr[n] = E;
}

__global__ __launch_bounds__(256)
void csr_fill(const int* __restrict__ srcIdx, const int* __restrict__ dstIdx,
              int* __restrict__ cursor, int* __restrict__ csr, int E)
{
    for (long i = (long)blockIdx.x * blockDim.x + threadIdx.x; i < E;
         i += (long)gridDim.x * blockDim.x) {
        int p = atomicAdd(&cursor[dstIdx[i]], 1);
        csr[p] = srcIdx[i];
    }
}

// ---- pull + fused epilogue: H = relu(sum_neigh(feat)/max(deg,1) + C + bias) ----
__global__ __launch_bounds__(256)
void pull_agg_ep(const float* __restrict__ feat, const int* __restrict__ rowptr,
                 const int* __restrict__ csr, const float* __restrict__ C,
                 const float* __restrict__ bias, float* __restrict__ H, int n)
{
    const int lane = threadIdx.x & 63;
    const int wid  = threadIdx.x >> 6;
    const long w   = (long)blockIdx.x * 4 + wid;
    const long nw  = (long)gridDim.x * 4;
    const float bv = bias[lane];
    for (long row = w; row < n; row += nw) {
        const int s = rowptr[row], e = rowptr[row + 1];
        float acc = 0.f;
        int i = s;
        for (; i + 8 <= e; i += 8) {
            int i0 = csr[i],     i1 = csr[i + 1], i2 = csr[i + 2], i3 = csr[i + 3];
            int i4 = csr[i + 4], i5 = csr[i + 5], i6 = csr[i + 6], i7 = csr[i + 7];
            float v0 = feat[(size_t)i0 * 64 + lane];
            float v1 = feat[(size_t)i1 * 64 + lane];
            float v2 = feat[(size_t)i2 * 64 + lane];
            float v3 = feat[(size_t)i3 * 64 + lane];
            float v4 = feat[(size_t)i4 * 64 + lane];
            float v5 = feat[(size_t)i5 * 64 + lane];
            float v6 = feat[(size_t)i6 * 64 + lane];
            float v7 = feat[(size_t)i7 * 64 + lane];
            acc += v0 + v1 + v2 + v3 + v4 + v5 + v6 + v7;
        }
        for (; i < e; ++i) acc += feat[(size_t)csr[i] * 64 + lane];
        float d = (float)(e - s);
        d = d > 1.f ? d : 1.f;
        float v = acc / d + C[(size_t)row * 64 + lane] + bv;
        H[(size_t)row * 64 + lane] = v > 0.f ? v : 0.f;
    }
}

// ---------------- GEMMs ----------------
// Yl = X@Wl, Yr = X@Wr. 8 rows per wave; weight pairs packed so one
// ds_read_b128 (lane i -> bytes 16i, conflict-free) yields 2 k-steps.
// x comes in via wave-uniform s_load_dwordx4 (SMEM pipe).
template<int K>
__global__ __launch_bounds__(256)
void dual_gemm(const float* __restrict__ X, const float* __restrict__ Wl,
               const float* __restrict__ Wr, float* __restrict__ Yl,
               float* __restrict__ Yr, int n)
{
    __shared__ float sW[K * 128];   // [k/2][lane][4] = {Wl[k],Wr[k],Wl[k+1],Wr[k+1]}
    for (int i = threadIdx.x; i < K * 64; i += 256) {
        int k = i >> 6, c = i & 63;
        int base = (k >> 1) * 256 + c * 4 + (k & 1) * 2;
        sW[base]     = Wl[i];
        sW[base + 1] = Wr[i];
    }
    __syncthreads();

    const int lane = threadIdx.x & 63;
    const int wid  = __builtin_amdgcn_readfirstlane(threadIdx.x >> 6);
    constexpr int R = 8;
    const long gstep = (long)gridDim.x * 4 * R;

    for (long r0 = ((long)blockIdx.x * 4 + wid) * R; r0 < n; r0 += gstep) {
        float accl[R], accr[R];
        #pragma unroll
        for (int r = 0; r < R; ++r) { accl[r] = 0.f; accr[r] = 0.f; }

        #pragma unroll 2
        for (int k = 0; k < K; k += 4) {
            float4 xs[R];
            #pragma unroll
            for (int r = 0; r < R; ++r) {
                long row = r0 + r; if (row >= n) row = n - 1;   // clamp (uniform)
                xs[r] = *reinterpret_cast<const float4*>(X + row * K + k);
            }
            float4 wa = *reinterpret_cast<const float4*>(&sW[(k >> 1) * 256 + lane * 4]);
            float4 wb = *reinterpret_cast<const float4*>(&sW[(k >> 1) * 256 + 256 + lane * 4]);
            #pragma unroll
            for (int r = 0; r < R; ++r) {
                accl[r] += xs[r].x * wa.x;  accr[r] += xs[r].x * wa.y;
                accl[r] += xs[r].y * wa.z;  accr[r] += xs[r].y * wa.w;
                accl[r] += xs[r].z * wb.x;  accr[r] += xs[r].z * wb.y;
                accl[r] += xs[r].w * wb.z;  accr[r] += xs[r].w * wb.w;
            }
        }
        #pragma unroll
        for (int r = 0; r < R; ++r) {
            long row = r0 + r;
            if (row < n) {
                Yl[row * 64 + lane] = accl[r];
                Yr[row * 64 + lane] = accr[r];
            }
        }
    }
}

// out = X@Wo + bo  (K=64, OUTC=112), 8 rows per wave
__global__ __launch_bounds__(256)
void gemm_out(const float* __restrict__ X, const float* __restrict__ W,
              const float* __restrict__ bias, float* __restrict__ Y, int n)
{
    constexpr int K = 64, OUTC = 112, R = 8;
    __shared__ float sW[K * OUTC];
    for (int i = threadIdx.x; i < K * OUTC; i += 256) sW[i] = W[i];
    __syncthreads();

    const int lane = threadIdx.x & 63;
    const int wid  = __builtin_amdgcn_readfirstlane(threadIdx.x >> 6);
    const int c1   = lane + 64;
    const long gstep = (long)gridDim.x * 4 * R;

    for (long r0 = ((long)blockIdx.x * 4 + wid) * R; r0 < n; r0 += gstep) {
        float acc0[R], acc1[R];
        #pragma unroll
        for (int r = 0; r < R; ++r) { acc0[r] = 0.f; acc1[r] = 0.f; }

        #pragma unroll 2
        for (int k = 0; k < K; k += 4) {
            float4 xs[R];
            #pragma unroll
            for (int r = 0; r < R; ++r) {
                long row = r0 + r; if (row >= n) row = n - 1;
                xs[r] = *reinterpret_cast<const float4*>(X + row * K + k);
            }
            #pragma unroll
            for (int ku = 0; ku < 4; ++ku) {
                float w0 = sW[(k + ku) * OUTC + lane];
                float w1 = (c1 < OUTC) ? sW[(k + ku) * OUTC + c1] : 0.f;
                float xv;
                #pragma unroll
                for (int r = 0; r < R; ++r) {
                    xv = (ku == 0) ? xs[r].x : (ku == 1) ? xs[r].y : (ku == 2) ? xs[r].z : xs[r].w;
                    acc0[r] += xv * w0;
                    acc1[r] += xv * w1;
                }
            }
        }
        #pragma unroll
        for (int r = 0; r < R; ++r) {
            long row = r0 + r;
            if (row < n) {
                Y[row * OUTC + lane] = acc0[r] + bias[lane];
                if (c1 < OUTC) Y[row * OUTC + c1] = acc1[r] + bias[c1];
            }
        }
    }
}

// ---------------- launch ----------------

extern "C" void kernel_launch(void* const* d_in, const int* in_sizes, int n_in,
                              void* d_out, int out_size, void* d_ws, size_t ws_size,
                              hipStream_t stream)
{
    const float* x   = (const float*)d_in[0];
    const int*   ei  = (const int*)d_in[1];
    const float* W1l = (const float*)d_in[2];
    const float* b1  = (const float*)d_in[3];
    const float* W1r = (const float*)d_in[4];
    const float* W2l = (const float*)d_in[5];
    const float* b2  = (const float*)d_in[6];
    const float* W2r = (const float*)d_in[7];
    const float* Wo  = (const float*)d_in[8];
    const float* bo  = (const float*)d_in[9];
    float* out = (float*)d_out;

    const int n = in_sizes[0] / 128;
    const int E = in_sizes[1] / 2;
    const int* srcI = ei;
    const int* dstI = ei + E;
    const int nchunk = (n + 1023) / 1024;

    float* A      = (float*)d_ws;                 // n*64
    float* C      = A + (size_t)n * 64;           // n*64
    float* H      = C + (size_t)n * 64;           // n*64
    int*   degi   = (int*)(H + (size_t)n * 64);   // n
    int*   rowptr = degi + n;                     // n+1
    int*   cursor = rowptr + n + 1;               // n
    int*   partial= cursor + n;                   // nchunk
    int*   csr    = partial + nchunk + 1;         // E

    // ---- CSR build (shared by both layers) ----
    hipMemsetAsync(degi, 0, (size_t)n * sizeof(int), stream);
    deg_int_kernel<<<1024, 256, 0, stream>>>(dstI, degi, E);
    scan_chunk<<<nchunk, 256, 0, stream>>>(degi, rowptr, partial, n);
    scan_partials<<<1, 64, 0, stream>>>(partial, nchunk);
    finalize_rowptr<<<(n + 256) / 256, 256, 0, stream>>>(rowptr, partial, cursor, n, E);
    csr_fill<<<2048, 256, 0, stream>>>(srcI, dstI, cursor, csr, E);

    // ---- layer 1 ----
    dual_gemm<128><<<1024, 256, 0, stream>>>(x, W1l, W1r, A, C, n);    // A=x@W1l, C=x@W1r
    pull_agg_ep<<<4096, 256, 0, stream>>>(A, rowptr, csr, C, b1, H, n); // H=h1

    // ---- layer 2 ----
    dual_gemm<64><<<1024, 256, 0, stream>>>(H, W2l, W2r, A, C, n);     // A=h1@W2l, C=h1@W2r
    pull_agg_ep<<<4096, 256, 0, stream>>>(A, rowptr, csr, C, b2, H, n); // H=h2

    // ---- output projection ----
    gemm_out<<<1024, 256, 0, stream>>>(H, Wo, bo, out, n);
}

// Round 4
// 483.467 us; speedup vs baseline: 2.3640x; 1.1169x over previous
//
#include <hip/hip_runtime.h>

// ---------------- weight packing ----------------
// P1[k*128 + 2c + {0,1}] = {W1l[k][c], W1r[k][c]}   k<128, c<64
// P2[k*128 + 2c + {0,1}] = {W2l[k][c], W2r[k][c]}   k<64,  c<64
// Po[k*128 + c]          = c<112 ? Wo[k][c] : 0     k<64,  c<128
__global__ __launch_bounds__(256)
void pack_weights(const float* __restrict__ W1l, const float* __restrict__ W1r,
                  const float* __restrict__ W2l, const float* __restrict__ W2r,
                  const float* __restrict__ Wo,
                  float* __restrict__ P1, float* __restrict__ P2, float* __restrict__ Po)
{
    int t0 = blockIdx.x * 256 + threadIdx.x;
    int step = gridDim.x * 256;
    for (int i = t0; i < 128 * 64; i += step) {
        int k = i >> 6, c = i & 63;
        P1[k * 128 + 2 * c]     = W1l[i];
        P1[k * 128 + 2 * c + 1] = W1r[i];
    }
    for (int i = t0; i < 64 * 64; i += step) {
        int k = i >> 6, c = i & 63;
        P2[k * 128 + 2 * c]     = W2l[i];
        P2[k * 128 + 2 * c + 1] = W2r[i];
    }
    for (int i = t0; i < 64 * 128; i += step) {
        int k = i >> 7, c = i & 127;
        Po[i] = (c < 112) ? Wo[k * 112 + c] : 0.f;
    }
}

// ---------------- CSR build ----------------

// histogram with line-padded counters, 8 edges/thread batched
__global__ __launch_bounds__(256)
void deg_hist(const int* __restrict__ dstIdx, int* __restrict__ hist, int pad, int E)
{
    long base = ((long)blockIdx.x * 256 + threadIdx.x) * 8;
    if (base + 8 <= E) {
        #pragma unroll
        for (int j = 0; j < 8; ++j)
            atomicAdd(&hist[(size_t)dstIdx[base + j] * pad], 1);
    } else {
        for (long i = base; i < E; ++i)
            atomicAdd(&hist[(size_t)dstIdx[i] * pad], 1);
    }
}

__global__ __launch_bounds__(256)
void scan_chunk(const int* __restrict__ hist, int pad, int* __restrict__ rowptr,
                int* __restrict__ partial, int n)
{
    __shared__ int s[256];
    const int b = blockIdx.x, t = threadIdx.x;
    const int base = b * 1024 + t * 4;
    int v[4], sum = 0;
    #pragma unroll
    for (int j = 0; j < 4; ++j) {
        int idx = base + j;
        v[j] = (idx < n) ? hist[(size_t)idx * pad] : 0;
        sum += v[j];
    }
    s[t] = sum;
    __syncthreads();
    #pragma unroll
    for (int off = 1; off < 256; off <<= 1) {
        int x = (t >= off) ? s[t - off] : 0;
        __syncthreads();
        s[t] += x;
        __syncthreads();
    }
    int run = s[t] - sum;
    if (t == 255) partial[b] = s[255];
    #pragma unroll
    for (int j = 0; j < 4; ++j) {
        int idx = base + j;
        if (idx < n) { rowptr[idx] = run; run += v[j]; }
    }
}

// exclusive scan of up to 128 partials with one wave
__global__ void scan_partials(int* partial, int nchunk)
{
    int t = threadIdx.x;
    if (nchunk > 128) {                      // safety fallback
        if (t == 0) {
            int acc = 0;
            for (int i = 0; i < nchunk; ++i) { int p = partial[i]; partial[i] = acc; acc += p; }
        }
        return;
    }
    int a = (t < nchunk) ? partial[t] : 0;
    int b = (t + 64 < nchunk) ? partial[t + 64] : 0;
    int a0 = a, b0 = b;
    #pragma unroll
    for (int off = 1; off < 64; off <<= 1) {
        int u = __shfl_up(a, off, 64);
        if (t >= off) a += u;
    }
    int atot = __shfl(a, 63, 64);
    #pragma unroll
    for (int off = 1; off < 64; off <<= 1) {
        int u = __shfl_up(b, off, 64);
        if (t >= off) b += u;
    }
    if (t < nchunk) partial[t] = a - a0;
    if (t + 64 < nchunk) partial[t + 64] = atot + b - b0;
}

__global__ __launch_bounds__(256)
void finalize_rowptr(int* __restrict__ rowptr, const int* __restrict__ partial,
                     int* __restrict__ cursor, int pad, int n, int E)
{
    int i = blockIdx.x * blockDim.x + threadIdx.x;
    if (i < n) {
        int v = rowptr[i] + partial[i >> 10];
        rowptr[i] = v;
        cursor[(size_t)i * pad] = v;
    }
    if (i == n) rowptr[n] = E;
}

// fill with padded cursors, 8 edges/thread: 8 atomics in flight, then 8 stores
__global__ __launch_bounds__(256)
void csr_fill(const int* __restrict__ srcIdx, const int* __restrict__ dstIdx,
              int* __restrict__ cursor, int pad, int* __restrict__ csr, int E)
{
    long base = ((long)blockIdx.x * 256 + threadIdx.x) * 8;
    if (base + 8 <= E) {
        int d[8], s[8], p[8];
        #pragma unroll
        for (int j = 0; j < 8; ++j) { d[j] = dstIdx[base + j]; s[j] = srcIdx[base + j]; }
        #pragma unroll
        for (int j = 0; j < 8; ++j) p[j] = atomicAdd(&cursor[(size_t)d[j] * pad], 1);
        #pragma unroll
        for (int j = 0; j < 8; ++j) csr[p[j]] = s[j];
    } else {
        for (long i = base; i < E; ++i) {
            int p = atomicAdd(&cursor[(size_t)dstIdx[i] * pad], 1);
            csr[p] = srcIdx[i];
        }
    }
}

// ---- pull + fused epilogue: H = relu(sum_neigh(feat)/max(deg,1) + C + bias) ----
__global__ __launch_bounds__(256)
void pull_agg_ep(const float* __restrict__ feat, const int* __restrict__ rowptr,
                 const int* __restrict__ csr, const float* __restrict__ C,
                 const float* __restrict__ bias, float* __restrict__ H, int n)
{
    const int lane = threadIdx.x & 63;
    const int wid  = threadIdx.x >> 6;
    const long w   = (long)blockIdx.x * 4 + wid;
    const long nw  = (long)gridDim.x * 4;
    const float bv = bias[lane];
    for (long row = w; row < n; row += nw) {
        const int s = rowptr[row], e = rowptr[row + 1];
        float acc = 0.f;
        int i = s;
        for (; i + 8 <= e; i += 8) {
            int i0 = csr[i],     i1 = csr[i + 1], i2 = csr[i + 2], i3 = csr[i + 3];
            int i4 = csr[i + 4], i5 = csr[i + 5], i6 = csr[i + 6], i7 = csr[i + 7];
            float v0 = feat[(size_t)i0 * 64 + lane];
            float v1 = feat[(size_t)i1 * 64 + lane];
            float v2 = feat[(size_t)i2 * 64 + lane];
            float v3 = feat[(size_t)i3 * 64 + lane];
            float v4 = feat[(size_t)i4 * 64 + lane];
            float v5 = feat[(size_t)i5 * 64 + lane];
            float v6 = feat[(size_t)i6 * 64 + lane];
            float v7 = feat[(size_t)i7 * 64 + lane];
            acc += v0 + v1 + v2 + v3 + v4 + v5 + v6 + v7;
        }
        for (; i < e; ++i) acc += feat[(size_t)csr[i] * 64 + lane];
        float d = (float)(e - s);
        d = d > 1.f ? d : 1.f;
        float v = acc / d + C[(size_t)row * 64 + lane] + bv;
        H[(size_t)row * 64 + lane] = v > 0.f ? v : 0.f;
    }
}

// ---------------- GEMMs (no LDS: coalesced global weight loads) ----------------

// Yl = X@Wl, Yr = X@Wr. 8 rows/wave; x via wave-uniform s_load; weights via
// coalesced float2 loads from packed P (L1/L2-resident, shared by all waves).
template<int K>
__global__ __launch_bounds__(256)
void dual_gemm(const float* __restrict__ X, const float* __restrict__ P,
               float* __restrict__ Yl, float* __restrict__ Yr, int n)
{
    const int lane = threadIdx.x & 63;
    const int wid  = __builtin_amdgcn_readfirstlane(threadIdx.x >> 6);
    constexpr int R = 8;
    long r0 = ((long)blockIdx.x * 4 + wid) * R;
    if (r0 >= n) return;

    const float* xp[R];
    #pragma unroll
    for (int r = 0; r < R; ++r) {
        long row = r0 + r; if (row >= n) row = n - 1;
        xp[r] = X + row * K;
    }

    float accl[R], accr[R];
    #pragma unroll
    for (int r = 0; r < R; ++r) { accl[r] = 0.f; accr[r] = 0.f; }

    #pragma unroll 2
    for (int k = 0; k < K; k += 4) {
        float2 wv[4];
        #pragma unroll
        for (int ku = 0; ku < 4; ++ku)
            wv[ku] = *reinterpret_cast<const float2*>(P + (size_t)(k + ku) * 128 + lane * 2);
        #pragma unroll
        for (int r = 0; r < R; ++r) {
            float4 xv = *reinterpret_cast<const float4*>(xp[r] + k);
            accl[r] += xv.x * wv[0].x;  accr[r] += xv.x * wv[0].y;
            accl[r] += xv.y * wv[1].x;  accr[r] += xv.y * wv[1].y;
            accl[r] += xv.z * wv[2].x;  accr[r] += xv.z * wv[2].y;
            accl[r] += xv.w * wv[3].x;  accr[r] += xv.w * wv[3].y;
        }
    }
    #pragma unroll
    for (int r = 0; r < R; ++r) {
        long row = r0 + r;
        if (row < n) {
            Yl[row * 64 + lane] = accl[r];
            Yr[row * 64 + lane] = accr[r];
        }
    }
}

// out = X@Wo + bo  (K=64, OUTC=112, Po padded to 128 cols)
__global__ __launch_bounds__(256)
void gemm_out(const float* __restrict__ X, const float* __restrict__ Po,
              const float* __restrict__ bias, float* __restrict__ Y, int n)
{
    constexpr int K = 64, R = 8;
    const int lane = threadIdx.x & 63;
    const int wid  = __builtin_amdgcn_readfirstlane(threadIdx.x >> 6);
    long r0 = ((long)blockIdx.x * 4 + wid) * R;
    if (r0 >= n) return;

    const float* xp[R];
    #pragma unroll
    for (int r = 0; r < R; ++r) {
        long row = r0 + r; if (row >= n) row = n - 1;
        xp[r] = X + row * K;
    }

    float acc0[R], acc1[R];
    #pragma unroll
    for (int r = 0; r < R; ++r) { acc0[r] = 0.f; acc1[r] = 0.f; }

    #pragma unroll 2
    for (int k = 0; k < K; k += 4) {
        float w0[4], w1[4];
        #pragma unroll
        for (int ku = 0; ku < 4; ++ku) {
            w0[ku] = Po[(size_t)(k + ku) * 128 + lane];
            w1[ku] = Po[(size_t)(k + ku) * 128 + 64 + lane];
        }
        #pragma unroll
        for (int r = 0; r < R; ++r) {
            float4 xv = *reinterpret_cast<const float4*>(xp[r] + k);
            acc0[r] += xv.x * w0[0];  acc1[r] += xv.x * w1[0];
            acc0[r] += xv.y * w0[1];  acc1[r] += xv.y * w1[1];
            acc0[r] += xv.z * w0[2];  acc1[r] += xv.z * w1[2];
            acc0[r] += xv.w * w0[3];  acc1[r] += xv.w * w1[3];
        }
    }
    const float b0 = bias[lane];
    const float b1 = (lane < 48) ? bias[64 + lane] : 0.f;
    #pragma unroll
    for (int r = 0; r < R; ++r) {
        long row = r0 + r;
        if (row < n) {
            Y[row * 112 + lane] = acc0[r] + b0;
            if (lane < 48) Y[row * 112 + 64 + lane] = acc1[r] + b1;
        }
    }
}

// ---------------- launch ----------------

extern "C" void kernel_launch(void* const* d_in, const int* in_sizes, int n_in,
                              void* d_out, int out_size, void* d_ws, size_t ws_size,
                              hipStream_t stream)
{
    const float* x   = (const float*)d_in[0];
    const int*   ei  = (const int*)d_in[1];
    const float* W1l = (const float*)d_in[2];
    const float* b1  = (const float*)d_in[3];
    const float* W1r = (const float*)d_in[4];
    const float* W2l = (const float*)d_in[5];
    const float* b2  = (const float*)d_in[6];
    const float* W2r = (const float*)d_in[7];
    const float* Wo  = (const float*)d_in[8];
    const float* bo  = (const float*)d_in[9];
    float* out = (float*)d_out;

    const int n = in_sizes[0] / 128;
    const int E = in_sizes[1] / 2;
    const int* srcI = ei;
    const int* dstI = ei + E;
    const int nchunk = (n + 1023) / 1024;

    const size_t nn64 = (size_t)n * 64;
    float* A      = (float*)d_ws;                 // n*64
    float* C      = A + nn64;                     // n*64
    float* H      = C + nn64;                     // n*64
    int*   rowptr = (int*)(H + nn64);             // n+1
    int*   partial= rowptr + n + 1;               // 128 (nchunk<=128 expected)
    int*   csr    = partial + 128;                // E
    float* P1     = (float*)(csr + E);            // 128*128
    float* P2     = P1 + 128 * 128;               // 64*128
    float* Po     = P2 + 64 * 128;                // 64*128
    int*   hist   = (int*)(Po + 64 * 128);        // n*pad  (hist, then cursor)

    int pad = 16;
    size_t need16 = ((char*)(hist + (size_t)n * 16)) - (char*)d_ws;
    if (ws_size < need16) pad = 1;

    // ---- weight pack + CSR build ----
    pack_weights<<<64, 256, 0, stream>>>(W1l, W1r, W2l, W2r, Wo, P1, P2, Po);
    hipMemsetAsync(hist, 0, (size_t)n * pad * sizeof(int), stream);
    deg_hist<<<(int)((E + 2047) / 2048), 256, 0, stream>>>(dstI, hist, pad, E);
    scan_chunk<<<nchunk, 256, 0, stream>>>(hist, pad, rowptr, partial, n);
    scan_partials<<<1, 64, 0, stream>>>(partial, nchunk);
    finalize_rowptr<<<(n + 256) / 256, 256, 0, stream>>>(rowptr, partial, hist, pad, n, E);
    csr_fill<<<(int)((E + 2047) / 2048), 256, 0, stream>>>(srcI, dstI, hist, pad, csr, E);

    const int gblk = (int)((n + 31) / 32);   // 4 waves x 8 rows per block

    // ---- layer 1 ----
    dual_gemm<128><<<gblk, 256, 0, stream>>>(x, P1, A, C, n);            // A=x@W1l, C=x@W1r
    pull_agg_ep<<<4096, 256, 0, stream>>>(A, rowptr, csr, C, b1, H, n);  // H=h1

    // ---- layer 2 ----
    dual_gemm<64><<<gblk, 256, 0, stream>>>(H, P2, A, C, n);             // A=h1@W2l, C=h1@W2r
    pull_agg_ep<<<4096, 256, 0, stream>>>(A, rowptr, csr, C, b2, H, n);  // H=h2

    // ---- output projection ----
    gemm_out<<<gblk, 256, 0, stream>>>(H, Po, bo, out, n);
}

// Round 5
// 368.663 us; speedup vs baseline: 3.1002x; 1.3114x over previous
//
#include <hip/hip_runtime.h>

// Bucketing: 512 nodes/bucket. packed edge = (src << 9) | (dst & 511).
// Requires n <= 2^23 (src fits in 23 bits). n = 100000 here.

// ---------------- weight packing ----------------
__global__ __launch_bounds__(256)
void pack_weights(const float* __restrict__ W1l, const float* __restrict__ W1r,
                  const float* __restrict__ W2l, const float* __restrict__ W2r,
                  const float* __restrict__ Wo,
                  float* __restrict__ P1, float* __restrict__ P2, float* __restrict__ Po)
{
    int t0 = blockIdx.x * 256 + threadIdx.x;
    int step = gridDim.x * 256;
    for (int i = t0; i < 128 * 64; i += step) {
        int k = i >> 6, c = i & 63;
        P1[k * 128 + 2 * c]     = W1l[i];
        P1[k * 128 + 2 * c + 1] = W1r[i];
    }
    for (int i = t0; i < 64 * 64; i += step) {
        int k = i >> 6, c = i & 63;
        P2[k * 128 + 2 * c]     = W2l[i];
        P2[k * 128 + 2 * c + 1] = W2r[i];
    }
    for (int i = t0; i < 64 * 128; i += step) {
        int k = i >> 7, c = i & 127;
        Po[i] = (c < 112) ? Wo[k * 112 + c] : 0.f;
    }
}

// ---------------- CSR build via bucket sort (LDS atomics only) ----------------

__global__ __launch_bounds__(256)
void bucket_count(const int* __restrict__ dst, int* __restrict__ gcount, int E, int B)
{
    __shared__ int lh[256];
    for (int i = threadIdx.x; i < B; i += 256) lh[i] = 0;
    __syncthreads();
    long base = (long)blockIdx.x * 4096;
    #pragma unroll
    for (int j = 0; j < 16; ++j) {
        long e = base + j * 256 + threadIdx.x;
        if (e < E) atomicAdd(&lh[dst[e] >> 9], 1);
    }
    __syncthreads();
    for (int i = threadIdx.x; i < B; i += 256) {
        int v = lh[i];
        if (v) atomicAdd(&gcount[i], v);
    }
}

// exclusive scan of B (<=256) bucket counts; one block
__global__ void bucket_scan(const int* __restrict__ gcount, int* __restrict__ gbase,
                            int* __restrict__ gcursor, int B, int E)
{
    __shared__ int s[256];
    int t = threadIdx.x;
    int v = (t < B) ? gcount[t] : 0;
    s[t] = v;
    __syncthreads();
    for (int off = 1; off < 256; off <<= 1) {
        int u = (t >= off) ? s[t - off] : 0;
        __syncthreads();
        s[t] += u;
        __syncthreads();
    }
    int ex = s[t] - v;
    if (t < B) { gbase[t] = ex; gcursor[t] = ex; }
    if (t == 0) gbase[B] = E;
}

__global__ __launch_bounds__(256)
void bucket_scatter(const int* __restrict__ src, const int* __restrict__ dst,
                    int* __restrict__ gcursor, int* __restrict__ packed, int E, int B)
{
    __shared__ int lh[256];
    __shared__ int lbase[256];
    for (int i = threadIdx.x; i < B; i += 256) lh[i] = 0;
    __syncthreads();
    long base = (long)blockIdx.x * 4096;
    int bkt[16], rnk[16], pk[16];
    #pragma unroll
    for (int j = 0; j < 16; ++j) {
        long e = base + j * 256 + threadIdx.x;
        if (e < E) {
            int d = dst[e], s = src[e];
            bkt[j] = d >> 9;
            pk[j]  = (s << 9) | (d & 511);
            rnk[j] = atomicAdd(&lh[bkt[j]], 1);
        } else bkt[j] = -1;
    }
    __syncthreads();
    for (int i = threadIdx.x; i < B; i += 256) {
        int v = lh[i];
        lbase[i] = v ? atomicAdd(&gcursor[i], v) : 0;
    }
    __syncthreads();
    #pragma unroll
    for (int j = 0; j < 16; ++j)
        if (bkt[j] >= 0) packed[lbase[bkt[j]] + rnk[j]] = pk[j];
}

// one block per bucket: per-node degree via LDS histogram
__global__ __launch_bounds__(256)
void bucket_deg(const int* __restrict__ packed, const int* __restrict__ gbase,
                int* __restrict__ degi, int n)
{
    __shared__ int h[512];
    int b = blockIdx.x;
    int nb = b * 512;
    int cnt = n - nb; if (cnt > 512) cnt = 512;
    for (int i = threadIdx.x; i < cnt; i += 256) h[i] = 0;
    __syncthreads();
    int s = gbase[b], e = gbase[b + 1];
    for (int i = s + threadIdx.x; i < e; i += 256)
        atomicAdd(&h[packed[i] & 511], 1);
    __syncthreads();
    for (int i = threadIdx.x; i < cnt; i += 256) degi[nb + i] = h[i];
}

__global__ __launch_bounds__(256)
void scan_chunk(const int* __restrict__ degi, int* __restrict__ rowptr,
                int* __restrict__ partial, int n)
{
    __shared__ int s[256];
    const int b = blockIdx.x, t = threadIdx.x;
    const int base = b * 1024 + t * 4;
    int v[4], sum = 0;
    #pragma unroll
    for (int j = 0; j < 4; ++j) {
        int idx = base + j;
        v[j] = (idx < n) ? degi[idx] : 0;
        sum += v[j];
    }
    s[t] = sum;
    __syncthreads();
    #pragma unroll
    for (int off = 1; off < 256; off <<= 1) {
        int x = (t >= off) ? s[t - off] : 0;
        __syncthreads();
        s[t] += x;
        __syncthreads();
    }
    int run = s[t] - sum;
    if (t == 255) partial[b] = s[255];
    #pragma unroll
    for (int j = 0; j < 4; ++j) {
        int idx = base + j;
        if (idx < n) { rowptr[idx] = run; run += v[j]; }
    }
}

__global__ void scan_partials(int* partial, int nchunk)
{
    int t = threadIdx.x;
    if (nchunk > 128) {
        if (t == 0) {
            int acc = 0;
            for (int i = 0; i < nchunk; ++i) { int p = partial[i]; partial[i] = acc; acc += p; }
        }
        return;
    }
    int a = (t < nchunk) ? partial[t] : 0;
    int b = (t + 64 < nchunk) ? partial[t + 64] : 0;
    int a0 = a, b0 = b;
    #pragma unroll
    for (int off = 1; off < 64; off <<= 1) {
        int u = __shfl_up(a, off, 64);
        if (t >= off) a += u;
    }
    int atot = __shfl(a, 63, 64);
    #pragma unroll
    for (int off = 1; off < 64; off <<= 1) {
        int u = __shfl_up(b, off, 64);
        if (t >= off) b += u;
    }
    if (t < nchunk) partial[t] = a - a0;
    if (t + 64 < nchunk) partial[t + 64] = atot + b - b0;
}

__global__ __launch_bounds__(256)
void finalize_rowptr(int* __restrict__ rowptr, const int* __restrict__ partial, int n, int E)
{
    int i = blockIdx.x * blockDim.x + threadIdx.x;
    if (i < n) rowptr[i] += partial[i >> 10];
    if (i == n) rowptr[n] = E;
}

// one block per bucket: LDS cursors seeded from rowptr, fill csr with src ids
__global__ __launch_bounds__(256)
void bucket_fill(const int* __restrict__ packed, const int* __restrict__ gbase,
                 const int* __restrict__ rowptr, int* __restrict__ csr, int n)
{
    __shared__ int cur[512];
    int b = blockIdx.x;
    int nb = b * 512;
    int cnt = n - nb; if (cnt > 512) cnt = 512;
    for (int i = threadIdx.x; i < cnt; i += 256) cur[i] = rowptr[nb + i];
    __syncthreads();
    int s = gbase[b], e = gbase[b + 1];
    for (int i = s + threadIdx.x; i < e; i += 256) {
        int p = packed[i];
        int pos = atomicAdd(&cur[p & 511], 1);
        csr[pos] = p >> 9;
    }
}

// ---- pull + fused epilogue: H = relu(sum_neigh(feat)/max(deg,1) + C + bias) ----
__global__ __launch_bounds__(256)
void pull_agg_ep(const float* __restrict__ feat, const int* __restrict__ rowptr,
                 const int* __restrict__ csr, const float* __restrict__ C,
                 const float* __restrict__ bias, float* __restrict__ H, int n)
{
    const int lane = threadIdx.x & 63;
    const int wid  = threadIdx.x >> 6;
    const long w   = (long)blockIdx.x * 4 + wid;
    const long nw  = (long)gridDim.x * 4;
    const float bv = bias[lane];
    for (long row = w; row < n; row += nw) {
        const int s = rowptr[row], e = rowptr[row + 1];
        float acc = 0.f;
        int i = s;
        for (; i + 8 <= e; i += 8) {
            int i0 = csr[i],     i1 = csr[i + 1], i2 = csr[i + 2], i3 = csr[i + 3];
            int i4 = csr[i + 4], i5 = csr[i + 5], i6 = csr[i + 6], i7 = csr[i + 7];
            float v0 = feat[(size_t)i0 * 64 + lane];
            float v1 = feat[(size_t)i1 * 64 + lane];
            float v2 = feat[(size_t)i2 * 64 + lane];
            float v3 = feat[(size_t)i3 * 64 + lane];
            float v4 = feat[(size_t)i4 * 64 + lane];
            float v5 = feat[(size_t)i5 * 64 + lane];
            float v6 = feat[(size_t)i6 * 64 + lane];
            float v7 = feat[(size_t)i7 * 64 + lane];
            acc += v0 + v1 + v2 + v3 + v4 + v5 + v6 + v7;
        }
        for (; i < e; ++i) acc += feat[(size_t)csr[i] * 64 + lane];
        float d = (float)(e - s);
        d = d > 1.f ? d : 1.f;
        float v = acc / d + C[(size_t)row * 64 + lane] + bv;
        H[(size_t)row * 64 + lane] = v > 0.f ? v : 0.f;
    }
}

// ---------------- GEMMs (no LDS: coalesced global weight loads) ----------------

template<int K>
__global__ __launch_bounds__(256)
void dual_gemm(const float* __restrict__ X, const float* __restrict__ P,
               float* __restrict__ Yl, float* __restrict__ Yr, int n)
{
    const int lane = threadIdx.x & 63;
    const int wid  = __builtin_amdgcn_readfirstlane(threadIdx.x >> 6);
    constexpr int R = 8;
    long r0 = ((long)blockIdx.x * 4 + wid) * R;
    if (r0 >= n) return;

    const float* xp[R];
    #pragma unroll
    for (int r = 0; r < R; ++r) {
        long row = r0 + r; if (row >= n) row = n - 1;
        xp[r] = X + row * K;
    }

    float accl[R], accr[R];
    #pragma unroll
    for (int r = 0; r < R; ++r) { accl[r] = 0.f; accr[r] = 0.f; }

    #pragma unroll 2
    for (int k = 0; k < K; k += 4) {
        float2 wv[4];
        #pragma unroll
        for (int ku = 0; ku < 4; ++ku)
            wv[ku] = *reinterpret_cast<const float2*>(P + (size_t)(k + ku) * 128 + lane * 2);
        #pragma unroll
        for (int r = 0; r < R; ++r) {
            float4 xv = *reinterpret_cast<const float4*>(xp[r] + k);
            accl[r] += xv.x * wv[0].x;  accr[r] += xv.x * wv[0].y;
            accl[r] += xv.y * wv[1].x;  accr[r] += xv.y * wv[1].y;
            accl[r] += xv.z * wv[2].x;  accr[r] += xv.z * wv[2].y;
            accl[r] += xv.w * wv[3].x;  accr[r] += xv.w * wv[3].y;
        }
    }
    #pragma unroll
    for (int r = 0; r < R; ++r) {
        long row = r0 + r;
        if (row < n) {
            Yl[row * 64 + lane] = accl[r];
            Yr[row * 64 + lane] = accr[r];
        }
    }
}

__global__ __launch_bounds__(256)
void gemm_out(const float* __restrict__ X, const float* __restrict__ Po,
              const float* __restrict__ bias, float* __restrict__ Y, int n)
{
    constexpr int K = 64, R = 8;
    const int lane = threadIdx.x & 63;
    const int wid  = __builtin_amdgcn_readfirstlane(threadIdx.x >> 6);
    long r0 = ((long)blockIdx.x * 4 + wid) * R;
    if (r0 >= n) return;

    const float* xp[R];
    #pragma unroll
    for (int r = 0; r < R; ++r) {
        long row = r0 + r; if (row >= n) row = n - 1;
        xp[r] = X + row * K;
    }

    float acc0[R], acc1[R];
    #pragma unroll
    for (int r = 0; r < R; ++r) { acc0[r] = 0.f; acc1[r] = 0.f; }

    #pragma unroll 2
    for (int k = 0; k < K; k += 4) {
        float w0[4], w1[4];
        #pragma unroll
        for (int ku = 0; ku < 4; ++ku) {
            w0[ku] = Po[(size_t)(k + ku) * 128 + lane];
            w1[ku] = Po[(size_t)(k + ku) * 128 + 64 + lane];
        }
        #pragma unroll
        for (int r = 0; r < R; ++r) {
            float4 xv = *reinterpret_cast<const float4*>(xp[r] + k);
            acc0[r] += xv.x * w0[0];  acc1[r] += xv.x * w1[0];
            acc0[r] += xv.y * w0[1];  acc1[r] += xv.y * w1[1];
            acc0[r] += xv.z * w0[2];  acc1[r] += xv.z * w1[2];
            acc0[r] += xv.w * w0[3];  acc1[r] += xv.w * w1[3];
        }
    }
    const float b0 = bias[lane];
    const float b1 = (lane < 48) ? bias[64 + lane] : 0.f;
    #pragma unroll
    for (int r = 0; r < R; ++r) {
        long row = r0 + r;
        if (row < n) {
            Y[row * 112 + lane] = acc0[r] + b0;
            if (lane < 48) Y[row * 112 + 64 + lane] = acc1[r] + b1;
        }
    }
}

// ---------------- launch ----------------

extern "C" void kernel_launch(void* const* d_in, const int* in_sizes, int n_in,
                              void* d_out, int out_size, void* d_ws, size_t ws_size,
                              hipStream_t stream)
{
    const float* x   = (const float*)d_in[0];
    const int*   ei  = (const int*)d_in[1];
    const float* W1l = (const float*)d_in[2];
    const float* b1  = (const float*)d_in[3];
    const float* W1r = (const float*)d_in[4];
    const float* W2l = (const float*)d_in[5];
    const float* b2  = (const float*)d_in[6];
    const float* W2r = (const float*)d_in[7];
    const float* Wo  = (const float*)d_in[8];
    const float* bo  = (const float*)d_in[9];
    float* out = (float*)d_out;

    const int n = in_sizes[0] / 128;
    const int E = in_sizes[1] / 2;
    const int* srcI = ei;
    const int* dstI = ei + E;
    const int nchunk = (n + 1023) / 1024;
    const int nbkt   = (n + 511) >> 9;

    const size_t nn64 = (size_t)n * 64;
    float* A      = (float*)d_ws;                 // n*64
    float* C      = A + nn64;                     // n*64
    float* H      = C + nn64;                     // n*64
    int*   rowptr = (int*)(H + nn64);             // n+1
    int*   partial= rowptr + n + 1;               // 128
    int*   csr    = partial + 128;                // E
    float* P1     = (float*)(csr + E);            // 128*128
    float* P2     = P1 + 128 * 128;               // 64*128
    float* Po     = P2 + 64 * 128;                // 64*128
    int*   gcount = (int*)(Po + 64 * 128);        // nbkt
    int*   gbase  = gcount + nbkt;                // nbkt+1
    int*   gcursor= gbase + nbkt + 1;             // nbkt
    int*   degi   = gcursor + nbkt;               // n
    int*   packed = (int*)A;                      // E (aliases A: CSR-build phase only)

    // ---- weight pack + CSR build (no global scattered atomics) ----
    pack_weights<<<64, 256, 0, stream>>>(W1l, W1r, W2l, W2r, Wo, P1, P2, Po);
    hipMemsetAsync(gcount, 0, (size_t)nbkt * sizeof(int), stream);
    const int gE = (int)((E + 4095) / 4096);
    bucket_count<<<gE, 256, 0, stream>>>(dstI, gcount, E, nbkt);
    bucket_scan<<<1, 256, 0, stream>>>(gcount, gbase, gcursor, nbkt, E);
    bucket_scatter<<<gE, 256, 0, stream>>>(srcI, dstI, gcursor, packed, E, nbkt);
    bucket_deg<<<nbkt, 256, 0, stream>>>(packed, gbase, degi, n);
    scan_chunk<<<nchunk, 256, 0, stream>>>(degi, rowptr, partial, n);
    scan_partials<<<1, 64, 0, stream>>>(partial, nchunk);
    finalize_rowptr<<<(n + 256) / 256, 256, 0, stream>>>(rowptr, partial, n, E);
    bucket_fill<<<nbkt, 256, 0, stream>>>(packed, gbase, rowptr, csr, n);

    const int gblk = (int)((n + 31) / 32);

    // ---- layer 1 ----
    dual_gemm<128><<<gblk, 256, 0, stream>>>(x, P1, A, C, n);
    pull_agg_ep<<<4096, 256, 0, stream>>>(A, rowptr, csr, C, b1, H, n);

    // ---- layer 2 ----
    dual_gemm<64><<<gblk, 256, 0, stream>>>(H, P2, A, C, n);
    pull_agg_ep<<<4096, 256, 0, stream>>>(A, rowptr, csr, C, b2, H, n);

    // ---- output projection ----
    gemm_out<<<gblk, 256, 0, stream>>>(H, Po, bo, out, n);
}

// Round 6
// 368.242 us; speedup vs baseline: 3.1038x; 1.0011x over previous
//
#include <hip/hip_runtime.h>

typedef float f32x4 __attribute__((ext_vector_type(4)));
typedef short s16x8 __attribute__((ext_vector_type(8)));

// RNE fp32 -> bf16 (bit trick, valid for finite values)
__device__ __forceinline__ short f2bf(float f) {
    unsigned u = __builtin_bit_cast(unsigned, f);
    unsigned r = (u + 0x7FFFu + ((u >> 16) & 1u)) >> 16;
    return (short)r;
}
__device__ __forceinline__ float bf2f(short h) {
    unsigned u = ((unsigned)(unsigned short)h) << 16;
    return __builtin_bit_cast(float, u);
}

// ---------------- CSR build via bucket sort (LDS atomics only) ----------------
// 512 nodes/bucket. packed edge = (src << 9) | (dst & 511). Needs n <= 2^23.

__global__ __launch_bounds__(256)
void bucket_count(const int* __restrict__ dst, int* __restrict__ gcount, int E, int B)
{
    __shared__ int lh[256];
    for (int i = threadIdx.x; i < B; i += 256) lh[i] = 0;
    __syncthreads();
    long base = (long)blockIdx.x * 4096;
    #pragma unroll
    for (int j = 0; j < 16; ++j) {
        long e = base + j * 256 + threadIdx.x;
        if (e < E) atomicAdd(&lh[dst[e] >> 9], 1);
    }
    __syncthreads();
    for (int i = threadIdx.x; i < B; i += 256) {
        int v = lh[i];
        if (v) atomicAdd(&gcount[i], v);
    }
}

__global__ void bucket_scan(const int* __restrict__ gcount, int* __restrict__ gbase,
                            int* __restrict__ gcursor, int B, int E)
{
    __shared__ int s[256];
    int t = threadIdx.x;
    int v = (t < B) ? gcount[t] : 0;
    s[t] = v;
    __syncthreads();
    for (int off = 1; off < 256; off <<= 1) {
        int u = (t >= off) ? s[t - off] : 0;
        __syncthreads();
        s[t] += u;
        __syncthreads();
    }
    int ex = s[t] - v;
    if (t < B) { gbase[t] = ex; gcursor[t] = ex; }
    if (t == 0) gbase[B] = E;
}

__global__ __launch_bounds__(256)
void bucket_scatter(const int* __restrict__ src, const int* __restrict__ dst,
                    int* __restrict__ gcursor, int* __restrict__ packed, int E, int B)
{
    __shared__ int lh[256];
    __shared__ int lbase[256];
    for (int i = threadIdx.x; i < B; i += 256) lh[i] = 0;
    __syncthreads();
    long base = (long)blockIdx.x * 4096;
    int bkt[16], rnk[16], pk[16];
    #pragma unroll
    for (int j = 0; j < 16; ++j) {
        long e = base + j * 256 + threadIdx.x;
        if (e < E) {
            int d = dst[e], s = src[e];
            bkt[j] = d >> 9;
            pk[j]  = (s << 9) | (d & 511);
            rnk[j] = atomicAdd(&lh[bkt[j]], 1);
        } else bkt[j] = -1;
    }
    __syncthreads();
    for (int i = threadIdx.x; i < B; i += 256) {
        int v = lh[i];
        lbase[i] = v ? atomicAdd(&gcursor[i], v) : 0;
    }
    __syncthreads();
    #pragma unroll
    for (int j = 0; j < 16; ++j)
        if (bkt[j] >= 0) packed[lbase[bkt[j]] + rnk[j]] = pk[j];
}

__global__ __launch_bounds__(256)
void bucket_deg(const int* __restrict__ packed, const int* __restrict__ gbase,
                int* __restrict__ degi, int n)
{
    __shared__ int h[512];
    int b = blockIdx.x;
    int nb = b * 512;
    int cnt = n - nb; if (cnt > 512) cnt = 512;
    for (int i = threadIdx.x; i < cnt; i += 256) h[i] = 0;
    __syncthreads();
    int s = gbase[b], e = gbase[b + 1];
    for (int i = s + threadIdx.x; i < e; i += 256)
        atomicAdd(&h[packed[i] & 511], 1);
    __syncthreads();
    for (int i = threadIdx.x; i < cnt; i += 256) degi[nb + i] = h[i];
}

__global__ __launch_bounds__(256)
void scan_chunk(const int* __restrict__ degi, int* __restrict__ rowptr,
                int* __restrict__ partial, int n)
{
    __shared__ int s[256];
    const int b = blockIdx.x, t = threadIdx.x;
    const int base = b * 1024 + t * 4;
    int v[4], sum = 0;
    #pragma unroll
    for (int j = 0; j < 4; ++j) {
        int idx = base + j;
        v[j] = (idx < n) ? degi[idx] : 0;
        sum += v[j];
    }
    s[t] = sum;
    __syncthreads();
    #pragma unroll
    for (int off = 1; off < 256; off <<= 1) {
        int x = (t >= off) ? s[t - off] : 0;
        __syncthreads();
        s[t] += x;
        __syncthreads();
    }
    int run = s[t] - sum;
    if (t == 255) partial[b] = s[255];
    #pragma unroll
    for (int j = 0; j < 4; ++j) {
        int idx = base + j;
        if (idx < n) { rowptr[idx] = run; run += v[j]; }
    }
}

__global__ void scan_partials(int* partial, int nchunk)
{
    int t = threadIdx.x;
    if (nchunk > 128) {
        if (t == 0) {
            int acc = 0;
            for (int i = 0; i < nchunk; ++i) { int p = partial[i]; partial[i] = acc; acc += p; }
        }
        return;
    }
    int a = (t < nchunk) ? partial[t] : 0;
    int b = (t + 64 < nchunk) ? partial[t + 64] : 0;
    int a0 = a, b0 = b;
    #pragma unroll
    for (int off = 1; off < 64; off <<= 1) {
        int u = __shfl_up(a, off, 64);
        if (t >= off) a += u;
    }
    int atot = __shfl(a, 63, 64);
    #pragma unroll
    for (int off = 1; off < 64; off <<= 1) {
        int u = __shfl_up(b, off, 64);
        if (t >= off) b += u;
    }
    if (t < nchunk) partial[t] = a - a0;
    if (t + 64 < nchunk) partial[t + 64] = atot + b - b0;
}

__global__ __launch_bounds__(256)
void finalize_rowptr(int* __restrict__ rowptr, const int* __restrict__ partial, int n, int E)
{
    int i = blockIdx.x * blockDim.x + threadIdx.x;
    if (i < n) rowptr[i] += partial[i >> 10];
    if (i == n) rowptr[n] = E;
}

__global__ __launch_bounds__(256)
void bucket_fill(const int* __restrict__ packed, const int* __restrict__ gbase,
                 const int* __restrict__ rowptr, int* __restrict__ csr, int n)
{
    __shared__ int cur[512];
    int b = blockIdx.x;
    int nb = b * 512;
    int cnt = n - nb; if (cnt > 512) cnt = 512;
    for (int i = threadIdx.x; i < cnt; i += 256) cur[i] = rowptr[nb + i];
    __syncthreads();
    int s = gbase[b], e = gbase[b + 1];
    for (int i = s + threadIdx.x; i < e; i += 256) {
        int p = packed[i];
        int pos = atomicAdd(&cur[p & 511], 1);
        csr[pos] = p >> 9;
    }
}

// ---- pull + fused epilogue: H = relu(sum_neigh(feat)/max(deg,1) + C + bias) ----
__global__ __launch_bounds__(256)
void pull_agg_ep(const float* __restrict__ feat, const int* __restrict__ rowptr,
                 const int* __restrict__ csr, const float* __restrict__ C,
                 const float* __restrict__ bias, float* __restrict__ H, int n)
{
    const int lane = threadIdx.x & 63;
    const int wid  = threadIdx.x >> 6;
    const long w   = (long)blockIdx.x * 4 + wid;
    const long nw  = (long)gridDim.x * 4;
    const float bv = bias[lane];
    for (long row = w; row < n; row += nw) {
        const int s = rowptr[row], e = rowptr[row + 1];
        float acc = 0.f;
        int i = s;
        for (; i + 8 <= e; i += 8) {
            int i0 = csr[i],     i1 = csr[i + 1], i2 = csr[i + 2], i3 = csr[i + 3];
            int i4 = csr[i + 4], i5 = csr[i + 5], i6 = csr[i + 6], i7 = csr[i + 7];
            float v0 = feat[(size_t)i0 * 64 + lane];
            float v1 = feat[(size_t)i1 * 64 + lane];
            float v2 = feat[(size_t)i2 * 64 + lane];
            float v3 = feat[(size_t)i3 * 64 + lane];
            float v4 = feat[(size_t)i4 * 64 + lane];
            float v5 = feat[(size_t)i5 * 64 + lane];
            float v6 = feat[(size_t)i6 * 64 + lane];
            float v7 = feat[(size_t)i7 * 64 + lane];
            acc += v0 + v1 + v2 + v3 + v4 + v5 + v6 + v7;
        }
        for (; i < e; ++i) acc += feat[(size_t)csr[i] * 64 + lane];
        float d = (float)(e - s);
        d = d > 1.f ? d : 1.f;
        float v = acc / d + C[(size_t)row * 64 + lane] + bv;
        H[(size_t)row * 64 + lane] = v > 0.f ? v : 0.f;
    }
}

// ---------------- MFMA GEMMs (bf16 hi/lo split, near-fp32 precision) ----------------
// Yl = X@Wl, Yr = X@Wr. Wave = one 16-row M-tile x all 64 cols of both mats.
// W staged in LDS transposed as bf16 hi/lo: sH/sL[cc * KP + k], cc = mat*64+col.
// x*w ~= xh*wh + xl*wh + xh*wl (3 MFMAs; dropped term ~2^-17 relative).
template<int K>
__global__ __launch_bounds__(512)
void dual_gemm_mfma(const float* __restrict__ X, const float* __restrict__ Wl,
                    const float* __restrict__ Wr, float* __restrict__ Yl,
                    float* __restrict__ Yr, int n)
{
    constexpr int KP  = K + 8;     // padded row stride in shorts (16B-aligned, 2-way banks)
    constexpr int NKT = K / 32;
    __shared__ short sH[128 * KP];
    __shared__ short sL[128 * KP];

    for (int i = threadIdx.x; i < K * 64; i += 512) {
        int c = i & 63, k = i >> 6;
        float wl = Wl[i], wr = Wr[i];
        short hl = f2bf(wl), hr = f2bf(wr);
        sH[c * KP + k]        = hl;
        sH[(64 + c) * KP + k] = hr;
        sL[c * KP + k]        = f2bf(wl - bf2f(hl));
        sL[(64 + c) * KP + k] = f2bf(wr - bf2f(hr));
    }
    __syncthreads();

    const int lane  = threadIdx.x & 63;
    const int wid   = threadIdx.x >> 6;
    const int crow  = lane & 15;            // col within 16-tile / A-row within tile
    const int koff  = (lane >> 4) << 3;     // k-offset of this lane's 8-chunk
    const long ntile = ((long)n + 15) >> 4;

    for (long t = (long)blockIdx.x * 8 + wid; t < ntile; t += (long)gridDim.x * 8) {
        const long rbase = t << 4;
        long arow = rbase + crow;
        if (arow >= n) arow = n - 1;
        const float* xr = X + arow * K + koff;

        s16x8 Ah[NKT], Al[NKT];
        #pragma unroll
        for (int kt = 0; kt < NKT; ++kt) {
            f32x4 a0 = *(const f32x4*)(xr + kt * 32);
            f32x4 a1 = *(const f32x4*)(xr + kt * 32 + 4);
            s16x8 h, l;
            #pragma unroll
            for (int j = 0; j < 4; ++j) {
                float v = a0[j];
                short hb = f2bf(v);
                h[j] = hb; l[j] = f2bf(v - bf2f(hb));
                float v2 = a1[j];
                short hb2 = f2bf(v2);
                h[4 + j] = hb2; l[4 + j] = f2bf(v2 - bf2f(hb2));
            }
            Ah[kt] = h; Al[kt] = l;
        }

        f32x4 acc[2][4];
        #pragma unroll
        for (int m = 0; m < 2; ++m)
            #pragma unroll
            for (int ct = 0; ct < 4; ++ct)
                acc[m][ct] = (f32x4)(0.f);

        #pragma unroll
        for (int kt = 0; kt < NKT; ++kt) {
            #pragma unroll
            for (int m = 0; m < 2; ++m) {
                #pragma unroll
                for (int ct = 0; ct < 4; ++ct) {
                    const int cc = m * 64 + ct * 16 + crow;
                    const s16x8 bh = *(const s16x8*)&sH[cc * KP + kt * 32 + koff];
                    const s16x8 bl = *(const s16x8*)&sL[cc * KP + kt * 32 + koff];
                    acc[m][ct] = __builtin_amdgcn_mfma_f32_16x16x32_bf16(Ah[kt], bh, acc[m][ct], 0, 0, 0);
                    acc[m][ct] = __builtin_amdgcn_mfma_f32_16x16x32_bf16(Al[kt], bh, acc[m][ct], 0, 0, 0);
                    acc[m][ct] = __builtin_amdgcn_mfma_f32_16x16x32_bf16(Ah[kt], bl, acc[m][ct], 0, 0, 0);
                }
            }
        }

        const int rsub = (lane >> 4) << 2;   // C/D: row = (lane>>4)*4 + i
        #pragma unroll
        for (int ct = 0; ct < 4; ++ct) {
            #pragma unroll
            for (int i = 0; i < 4; ++i) {
                long r = rbase + rsub + i;
                if (r < n) {
                    Yl[r * 64 + ct * 16 + crow] = acc[0][ct][i];
                    Yr[r * 64 + ct * 16 + crow] = acc[1][ct][i];
                }
            }
        }
    }
}

// out = X@Wo + bo. K=64, OUTC=112 (7 col-tiles).
__global__ __launch_bounds__(512)
void gemm_out_mfma(const float* __restrict__ X, const float* __restrict__ Wo,
                   const float* __restrict__ bo, float* __restrict__ Y, int n)
{
    constexpr int K = 64, KP = 72, NCT = 7;
    __shared__ short sH[112 * KP];
    __shared__ short sL[112 * KP];

    for (int i = threadIdx.x; i < K * 112; i += 512) {
        int c = i % 112, k = i / 112;
        float w = Wo[i];
        short hb = f2bf(w);
        sH[c * KP + k] = hb;
        sL[c * KP + k] = f2bf(w - bf2f(hb));
    }
    __syncthreads();

    const int lane  = threadIdx.x & 63;
    const int wid   = threadIdx.x >> 6;
    const int crow  = lane & 15;
    const int koff  = (lane >> 4) << 3;
    const long ntile = ((long)n + 15) >> 4;

    float bv[NCT];
    #pragma unroll
    for (int ct = 0; ct < NCT; ++ct) bv[ct] = bo[ct * 16 + crow];

    for (long t = (long)blockIdx.x * 8 + wid; t < ntile; t += (long)gridDim.x * 8) {
        const long rbase = t << 4;
        long arow = rbase + crow;
        if (arow >= n) arow = n - 1;
        const float* xr = X + arow * K + koff;

        s16x8 Ah[2], Al[2];
        #pragma unroll
        for (int kt = 0; kt < 2; ++kt) {
            f32x4 a0 = *(const f32x4*)(xr + kt * 32);
            f32x4 a1 = *(const f32x4*)(xr + kt * 32 + 4);
            s16x8 h, l;
            #pragma unroll
            for (int j = 0; j < 4; ++j) {
                float v = a0[j];
                short hb = f2bf(v);
                h[j] = hb; l[j] = f2bf(v - bf2f(hb));
                float v2 = a1[j];
                short hb2 = f2bf(v2);
                h[4 + j] = hb2; l[4 + j] = f2bf(v2 - bf2f(hb2));
            }
            Ah[kt] = h; Al[kt] = l;
        }

        f32x4 acc[NCT];
        #pragma unroll
        for (int ct = 0; ct < NCT; ++ct) acc[ct] = (f32x4)(0.f);

        #pragma unroll
        for (int kt = 0; kt < 2; ++kt) {
            #pragma unroll
            for (int ct = 0; ct < NCT; ++ct) {
                const int cc = ct * 16 + crow;
                const s16x8 bh = *(const s16x8*)&sH[cc * KP + kt * 32 + koff];
                const s16x8 bl = *(const s16x8*)&sL[cc * KP + kt * 32 + koff];
                acc[ct] = __builtin_amdgcn_mfma_f32_16x16x32_bf16(Ah[kt], bh, acc[ct], 0, 0, 0);
                acc[ct] = __builtin_amdgcn_mfma_f32_16x16x32_bf16(Al[kt], bh, acc[ct], 0, 0, 0);
                acc[ct] = __builtin_amdgcn_mfma_f32_16x16x32_bf16(Ah[kt], bl, acc[ct], 0, 0, 0);
            }
        }

        const int rsub = (lane >> 4) << 2;
        #pragma unroll
        for (int ct = 0; ct < NCT; ++ct) {
            #pragma unroll
            for (int i = 0; i < 4; ++i) {
                long r = rbase + rsub + i;
                if (r < n) Y[r * 112 + ct * 16 + crow] = acc[ct][i] + bv[ct];
            }
        }
    }
}

// ---------------- launch ----------------

extern "C" void kernel_launch(void* const* d_in, const int* in_sizes, int n_in,
                              void* d_out, int out_size, void* d_ws, size_t ws_size,
                              hipStream_t stream)
{
    const float* x   = (const float*)d_in[0];
    const int*   ei  = (const int*)d_in[1];
    const float* W1l = (const float*)d_in[2];
    const float* b1  = (const float*)d_in[3];
    const float* W1r = (const float*)d_in[4];
    const float* W2l = (const float*)d_in[5];
    const float* b2  = (const float*)d_in[6];
    const float* W2r = (const float*)d_in[7];
    const float* Wo  = (const float*)d_in[8];
    const float* bo  = (const float*)d_in[9];
    float* out = (float*)d_out;

    const int n = in_sizes[0] / 128;
    const int E = in_sizes[1] / 2;
    const int* srcI = ei;
    const int* dstI = ei + E;
    const int nchunk = (n + 1023) / 1024;
    const int nbkt   = (n + 511) >> 9;

    const size_t nn64 = (size_t)n * 64;
    float* A      = (float*)d_ws;                 // n*64
    float* C      = A + nn64;                     // n*64
    float* H      = C + nn64;                     // n*64
    int*   rowptr = (int*)(H + nn64);             // n+1
    int*   partial= rowptr + n + 1;               // 128
    int*   csr    = partial + 128;                // E
    int*   gcount = csr + E;                      // nbkt
    int*   gbase  = gcount + nbkt;                // nbkt+1
    int*   gcursor= gbase + nbkt + 1;             // nbkt
    int*   degi   = gcursor + nbkt;               // n
    int*   packed = (int*)A;                      // E (aliases A: CSR-build phase only)

    // ---- CSR build (no global scattered atomics) ----
    hipMemsetAsync(gcount, 0, (size_t)nbkt * sizeof(int), stream);
    const int gE = (int)((E + 4095) / 4096);
    bucket_count<<<gE, 256, 0, stream>>>(dstI, gcount, E, nbkt);
    bucket_scan<<<1, 256, 0, stream>>>(gcount, gbase, gcursor, nbkt, E);
    bucket_scatter<<<gE, 256, 0, stream>>>(srcI, dstI, gcursor, packed, E, nbkt);
    bucket_deg<<<nbkt, 256, 0, stream>>>(packed, gbase, degi, n);
    scan_chunk<<<nchunk, 256, 0, stream>>>(degi, rowptr, partial, n);
    scan_partials<<<1, 64, 0, stream>>>(partial, nchunk);
    finalize_rowptr<<<(n + 256) / 256, 256, 0, stream>>>(rowptr, partial, n, E);
    bucket_fill<<<nbkt, 256, 0, stream>>>(packed, gbase, rowptr, csr, n);

    const long ntile = ((long)n + 15) >> 4;
    const int gmf = (int)((ntile + 7) / 8);       // 8 tiles (waves) per block

    // ---- layer 1 ----
    dual_gemm_mfma<128><<<gmf, 512, 0, stream>>>(x, W1l, W1r, A, C, n);
    pull_agg_ep<<<4096, 256, 0, stream>>>(A, rowptr, csr, C, b1, H, n);

    // ---- layer 2 ----
    dual_gemm_mfma<64><<<gmf, 512, 0, stream>>>(H, W2l, W2r, A, C, n);
    pull_agg_ep<<<4096, 256, 0, stream>>>(A, rowptr, csr, C, b2, H, n);

    // ---- output projection ----
    gemm_out_mfma<<<gmf, 512, 0, stream>>>(H, Wo, bo, out, n);
}

// Round 7
// 305.293 us; speedup vs baseline: 3.7437x; 1.2062x over previous
//
#include <hip/hip_runtime.h>

typedef float f32x4 __attribute__((ext_vector_type(4)));
typedef short s16x8 __attribute__((ext_vector_type(8)));

// RNE fp32 -> bf16 (bit trick, valid for finite values)
__device__ __forceinline__ short f2bf(float f) {
    unsigned u = __builtin_bit_cast(unsigned, f);
    unsigned r = (u + 0x7FFFu + ((u >> 16) & 1u)) >> 16;
    return (short)r;
}
__device__ __forceinline__ float bf2f(short h) {
    unsigned u = ((unsigned)(unsigned short)h) << 16;
    return __builtin_bit_cast(float, u);
}

// ---------------- weight fragment packing (one-time, tiny) ----------------
// MFMA operand-A fragment for W (K x C row-major), transposed role:
//   frag element j of lane: W[k0 + j][c],  k0 = kt*32 + (lane>>4)*8,  c = ct*16 + (lane&15)
// PH/PL store hi/lo bf16 splits, 8 shorts (16B) per (frag, lane) entry.
// dual1: f=((m*4+ct)*4+kt)  m<2,ct<4,kt<4  -> 2048 entries
// dual2: f=((m*4+ct)*2+kt)  m<2,ct<4,kt<2  -> 1024 entries
// out:   f=(ct*2+kt)        ct<7,kt<2      ->  896 entries
__global__ __launch_bounds__(256)
void pack_frags(const float* __restrict__ W1l, const float* __restrict__ W1r,
                const float* __restrict__ W2l, const float* __restrict__ W2r,
                const float* __restrict__ Wo,
                short* __restrict__ PH1, short* __restrict__ PL1,
                short* __restrict__ PH2, short* __restrict__ PL2,
                short* __restrict__ PHo, short* __restrict__ PLo)
{
    const int tot = 2048 + 1024 + 896;
    for (int e = blockIdx.x * 256 + threadIdx.x; e < tot; e += gridDim.x * 256) {
        int lane, f, k0, c, stride;
        const float* W;
        short *PH, *PL;
        int idx;
        if (e < 2048) {
            idx = e; lane = e & 63; f = e >> 6;
            int kt = f & 3, ct = (f >> 2) & 3, m = f >> 4;
            W = m ? W1r : W1l; PH = PH1; PL = PL1;
            k0 = kt * 32 + ((lane >> 4) << 3);
            c  = ct * 16 + (lane & 15);
            stride = 64;
        } else if (e < 3072) {
            int e2 = e - 2048;
            idx = e2; lane = e2 & 63; f = e2 >> 6;
            int kt = f & 1, ct = (f >> 1) & 3, m = f >> 3;
            W = m ? W2r : W2l; PH = PH2; PL = PL2;
            k0 = kt * 32 + ((lane >> 4) << 3);
            c  = ct * 16 + (lane & 15);
            stride = 64;
        } else {
            int eo = e - 3072;
            idx = eo; lane = eo & 63; f = eo >> 6;
            int kt = f & 1, ct = f >> 1;
            W = Wo; PH = PHo; PL = PLo;
            k0 = kt * 32 + ((lane >> 4) << 3);
            c  = ct * 16 + (lane & 15);
            stride = 112;
        }
        short h[8], l[8];
        #pragma unroll
        for (int j = 0; j < 8; ++j) {
            float v = W[(size_t)(k0 + j) * stride + c];
            short hb = f2bf(v);
            h[j] = hb;
            l[j] = f2bf(v - bf2f(hb));
        }
        #pragma unroll
        for (int j = 0; j < 8; ++j) { PH[idx * 8 + j] = h[j]; PL[idx * 8 + j] = l[j]; }
    }
}

// ---------------- CSR build via bucket sort (LDS atomics only) ----------------
// 512 nodes/bucket. packed edge = (src << 9) | (dst & 511). Needs n <= 2^23.

__global__ __launch_bounds__(256)
void bucket_count(const int* __restrict__ dst, int* __restrict__ gcount, int E, int B)
{
    __shared__ int lh[256];
    for (int i = threadIdx.x; i < B; i += 256) lh[i] = 0;
    __syncthreads();
    long base = (long)blockIdx.x * 4096;
    #pragma unroll
    for (int j = 0; j < 16; ++j) {
        long e = base + j * 256 + threadIdx.x;
        if (e < E) atomicAdd(&lh[dst[e] >> 9], 1);
    }
    __syncthreads();
    for (int i = threadIdx.x; i < B; i += 256) {
        int v = lh[i];
        if (v) atomicAdd(&gcount[i], v);
    }
}

__global__ void bucket_scan(const int* __restrict__ gcount, int* __restrict__ gbase,
                            int* __restrict__ gcursor, int B, int E)
{
    __shared__ int s[256];
    int t = threadIdx.x;
    int v = (t < B) ? gcount[t] : 0;
    s[t] = v;
    __syncthreads();
    for (int off = 1; off < 256; off <<= 1) {
        int u = (t >= off) ? s[t - off] : 0;
        __syncthreads();
        s[t] += u;
        __syncthreads();
    }
    int ex = s[t] - v;
    if (t < B) { gbase[t] = ex; gcursor[t] = ex; }
    if (t == 0) gbase[B] = E;
}

__global__ __launch_bounds__(256)
void bucket_scatter(const int* __restrict__ src, const int* __restrict__ dst,
                    int* __restrict__ gcursor, int* __restrict__ packed, int E, int B)
{
    __shared__ int lh[256];
    __shared__ int lbase[256];
    for (int i = threadIdx.x; i < B; i += 256) lh[i] = 0;
    __syncthreads();
    long base = (long)blockIdx.x * 4096;
    int bkt[16], rnk[16], pk[16];
    #pragma unroll
    for (int j = 0; j < 16; ++j) {
        long e = base + j * 256 + threadIdx.x;
        if (e < E) {
            int d = dst[e], s = src[e];
            bkt[j] = d >> 9;
            pk[j]  = (s << 9) | (d & 511);
            rnk[j] = atomicAdd(&lh[bkt[j]], 1);
        } else bkt[j] = -1;
    }
    __syncthreads();
    for (int i = threadIdx.x; i < B; i += 256) {
        int v = lh[i];
        lbase[i] = v ? atomicAdd(&gcursor[i], v) : 0;
    }
    __syncthreads();
    #pragma unroll
    for (int j = 0; j < 16; ++j)
        if (bkt[j] >= 0) packed[lbase[bkt[j]] + rnk[j]] = pk[j];
}

__global__ __launch_bounds__(256)
void bucket_deg(const int* __restrict__ packed, const int* __restrict__ gbase,
                int* __restrict__ degi, int n)
{
    __shared__ int h[512];
    int b = blockIdx.x;
    int nb = b * 512;
    int cnt = n - nb; if (cnt > 512) cnt = 512;
    for (int i = threadIdx.x; i < cnt; i += 256) h[i] = 0;
    __syncthreads();
    int s = gbase[b], e = gbase[b + 1];
    for (int i = s + threadIdx.x; i < e; i += 256)
        atomicAdd(&h[packed[i] & 511], 1);
    __syncthreads();
    for (int i = threadIdx.x; i < cnt; i += 256) degi[nb + i] = h[i];
}

__global__ __launch_bounds__(256)
void scan_chunk(const int* __restrict__ degi, int* __restrict__ rowptr,
                int* __restrict__ partial, int n)
{
    __shared__ int s[256];
    const int b = blockIdx.x, t = threadIdx.x;
    const int base = b * 1024 + t * 4;
    int v[4], sum = 0;
    #pragma unroll
    for (int j = 0; j < 4; ++j) {
        int idx = base + j;
        v[j] = (idx < n) ? degi[idx] : 0;
        sum += v[j];
    }
    s[t] = sum;
    __syncthreads();
    #pragma unroll
    for (int off = 1; off < 256; off <<= 1) {
        int x = (t >= off) ? s[t - off] : 0;
        __syncthreads();
        s[t] += x;
        __syncthreads();
    }
    int run = s[t] - sum;
    if (t == 255) partial[b] = s[255];
    #pragma unroll
    for (int j = 0; j < 4; ++j) {
        int idx = base + j;
        if (idx < n) { rowptr[idx] = run; run += v[j]; }
    }
}

__global__ void scan_partials(int* partial, int nchunk)
{
    int t = threadIdx.x;
    if (nchunk > 128) {
        if (t == 0) {
            int acc = 0;
            for (int i = 0; i < nchunk; ++i) { int p = partial[i]; partial[i] = acc; acc += p; }
        }
        return;
    }
    int a = (t < nchunk) ? partial[t] : 0;
    int b = (t + 64 < nchunk) ? partial[t + 64] : 0;
    int a0 = a, b0 = b;
    #pragma unroll
    for (int off = 1; off < 64; off <<= 1) {
        int u = __shfl_up(a, off, 64);
        if (t >= off) a += u;
    }
    int atot = __shfl(a, 63, 64);
    #pragma unroll
    for (int off = 1; off < 64; off <<= 1) {
        int u = __shfl_up(b, off, 64);
        if (t >= off) b += u;
    }
    if (t < nchunk) partial[t] = a - a0;
    if (t + 64 < nchunk) partial[t + 64] = atot + b - b0;
}

__global__ __launch_bounds__(256)
void finalize_rowptr(int* __restrict__ rowptr, const int* __restrict__ partial, int n, int E)
{
    int i = blockIdx.x * blockDim.x + threadIdx.x;
    if (i < n) rowptr[i] += partial[i >> 10];
    if (i == n) rowptr[n] = E;
}

__global__ __launch_bounds__(256)
void bucket_fill(const int* __restrict__ packed, const int* __restrict__ gbase,
                 const int* __restrict__ rowptr, int* __restrict__ csr, int n)
{
    __shared__ int cur[512];
    int b = blockIdx.x;
    int nb = b * 512;
    int cnt = n - nb; if (cnt > 512) cnt = 512;
    for (int i = threadIdx.x; i < cnt; i += 256) cur[i] = rowptr[nb + i];
    __syncthreads();
    int s = gbase[b], e = gbase[b + 1];
    for (int i = s + threadIdx.x; i < e; i += 256) {
        int p = packed[i];
        int pos = atomicAdd(&cur[p & 511], 1);
        csr[pos] = p >> 9;
    }
}

// ---- pull + fused epilogue: H = relu(sum_neigh(feat)/max(deg,1) + C + bias) ----
__global__ __launch_bounds__(256)
void pull_agg_ep(const float* __restrict__ feat, const int* __restrict__ rowptr,
                 const int* __restrict__ csr, const float* __restrict__ C,
                 const float* __restrict__ bias, float* __restrict__ H, int n)
{
    const int lane = threadIdx.x & 63;
    const int wid  = threadIdx.x >> 6;
    const long w   = (long)blockIdx.x * 4 + wid;
    const long nw  = (long)gridDim.x * 4;
    const float bv = bias[lane];
    for (long row = w; row < n; row += nw) {
        const int s = rowptr[row], e = rowptr[row + 1];
        float acc = 0.f;
        int i = s;
        for (; i + 8 <= e; i += 8) {
            int i0 = csr[i],     i1 = csr[i + 1], i2 = csr[i + 2], i3 = csr[i + 3];
            int i4 = csr[i + 4], i5 = csr[i + 5], i6 = csr[i + 6], i7 = csr[i + 7];
            float v0 = feat[(size_t)i0 * 64 + lane];
            float v1 = feat[(size_t)i1 * 64 + lane];
            float v2 = feat[(size_t)i2 * 64 + lane];
            float v3 = feat[(size_t)i3 * 64 + lane];
            float v4 = feat[(size_t)i4 * 64 + lane];
            float v5 = feat[(size_t)i5 * 64 + lane];
            float v6 = feat[(size_t)i6 * 64 + lane];
            float v7 = feat[(size_t)i7 * 64 + lane];
            acc += v0 + v1 + v2 + v3 + v4 + v5 + v6 + v7;
        }
        for (; i < e; ++i) acc += feat[(size_t)csr[i] * 64 + lane];
        float d = (float)(e - s);
        d = d > 1.f ? d : 1.f;
        float v = acc / d + C[(size_t)row * 64 + lane] + bv;
        H[(size_t)row * 64 + lane] = v > 0.f ? v : 0.f;
    }
}

// ---------------- MFMA GEMMs, transposed-D, fragment-packed weights ----------------
// D = W^T_frag (A) x X_frag (B): lane holds output row r = rbase+(lane&15),
// cols c = ct*16 + (lane>>4)*4 + reg  -> f32x4 accumulators in output space.
// Epilogue: per-wave LDS transpose -> 4 fully-contiguous 1KB store instructions.
// 3-term bf16 split: W*X ~= Wh*Xh + Wl*Xh + Wh*Xl.

template<int K>
__global__ __launch_bounds__(512)
void dual_gemm_mfma(const float* __restrict__ X, const short* __restrict__ PH,
                    const short* __restrict__ PL, float* __restrict__ Yl,
                    float* __restrict__ Yr, int n)
{
    constexpr int NKT = K / 32;
    __shared__ float sT[8][16 * 72];     // 36 KB; 72-float row pitch (16B aligned)
    const int lane = threadIdx.x & 63;
    const int wid  = threadIdx.x >> 6;
    const long ntile = ((long)n + 15) >> 4;
    long t = (long)blockIdx.x * 8 + wid;
    if (t >= ntile) return;
    const long rbase = t << 4;
    long arow = rbase + (lane & 15);
    if (arow >= n) arow = n - 1;
    const int koff = (lane >> 4) << 3;
    const float* xr = X + arow * K + koff;

    // X fragments (B operand), hi/lo split in-register
    s16x8 Bh[NKT], Bl[NKT];
    #pragma unroll
    for (int kt = 0; kt < NKT; ++kt) {
        f32x4 a0 = *(const f32x4*)(xr + kt * 32);
        f32x4 a1 = *(const f32x4*)(xr + kt * 32 + 4);
        s16x8 h, l;
        #pragma unroll
        for (int j = 0; j < 4; ++j) {
            float v = a0[j]; short hb = f2bf(v);
            h[j] = hb; l[j] = f2bf(v - bf2f(hb));
            float v2 = a1[j]; short hb2 = f2bf(v2);
            h[4 + j] = hb2; l[4 + j] = f2bf(v2 - bf2f(hb2));
        }
        Bh[kt] = h; Bl[kt] = l;
    }

    f32x4 acc[2][4];
    #pragma unroll
    for (int m = 0; m < 2; ++m)
        #pragma unroll
        for (int ct = 0; ct < 4; ++ct) acc[m][ct] = (f32x4)(0.f);

    #pragma unroll
    for (int m = 0; m < 2; ++m)
    #pragma unroll
    for (int ct = 0; ct < 4; ++ct)
    #pragma unroll
    for (int kt = 0; kt < NKT; ++kt) {
        const int fidx = ((((m << 2) | ct) * NKT) + kt) * 64 + lane;
        s16x8 Ah = *(const s16x8*)(PH + (size_t)fidx * 8);
        s16x8 Al = *(const s16x8*)(PL + (size_t)fidx * 8);
        acc[m][ct] = __builtin_amdgcn_mfma_f32_16x16x32_bf16(Ah, Bh[kt], acc[m][ct], 0, 0, 0);
        acc[m][ct] = __builtin_amdgcn_mfma_f32_16x16x32_bf16(Al, Bh[kt], acc[m][ct], 0, 0, 0);
        acc[m][ct] = __builtin_amdgcn_mfma_f32_16x16x32_bf16(Ah, Bl[kt], acc[m][ct], 0, 0, 0);
    }

    const int wrow = lane & 15, q4 = (lane >> 4) << 2;
    #pragma unroll
    for (int m = 0; m < 2; ++m) {
        float* __restrict__ Y = m ? Yr : Yl;
        #pragma unroll
        for (int ct = 0; ct < 4; ++ct)
            *(f32x4*)&sT[wid][wrow * 72 + ct * 16 + q4] = acc[m][ct];
        asm volatile("s_waitcnt lgkmcnt(0)" ::: "memory");
        if (rbase + 16 <= (long)n) {
            #pragma unroll
            for (int s = 0; s < 4; ++s) {
                int f = s * 64 + lane;
                f32x4 v = *(const f32x4*)&sT[wid][(f >> 4) * 72 + ((f & 15) << 2)];
                *(f32x4*)&Y[rbase * 64 + f * 4] = v;
            }
        } else {
            #pragma unroll
            for (int s = 0; s < 4; ++s) {
                int f = s * 64 + lane;
                long gbase_ = rbase * 64 + f * 4;
                f32x4 v = *(const f32x4*)&sT[wid][(f >> 4) * 72 + ((f & 15) << 2)];
                #pragma unroll
                for (int jj = 0; jj < 4; ++jj)
                    if (gbase_ + jj < (long)n * 64) Y[gbase_ + jj] = v[jj];
            }
        }
        asm volatile("s_waitcnt lgkmcnt(0)" ::: "memory");   // reads drained before m=1 rewrites
    }
}

// out = X@Wo + bo. K=64, OUTC=112 (7 col-tiles). Same structure.
__global__ __launch_bounds__(512)
void gemm_out_mfma(const float* __restrict__ X, const short* __restrict__ PH,
                   const short* __restrict__ PL, const float* __restrict__ bo,
                   float* __restrict__ Y, int n)
{
    constexpr int NCT = 7;
    __shared__ float sT[8][16 * 120];    // 60 KB; 120-float row pitch
    const int lane = threadIdx.x & 63;
    const int wid  = threadIdx.x >> 6;
    const long ntile = ((long)n + 15) >> 4;
    long t = (long)blockIdx.x * 8 + wid;
    if (t >= ntile) return;
    const long rbase = t << 4;
    long arow = rbase + (lane & 15);
    if (arow >= n) arow = n - 1;
    const int koff = (lane >> 4) << 3;
    const float* xr = X + arow * 64 + koff;

    s16x8 Bh[2], Bl[2];
    #pragma unroll
    for (int kt = 0; kt < 2; ++kt) {
        f32x4 a0 = *(const f32x4*)(xr + kt * 32);
        f32x4 a1 = *(const f32x4*)(xr + kt * 32 + 4);
        s16x8 h, l;
        #pragma unroll
        for (int j = 0; j < 4; ++j) {
            float v = a0[j]; short hb = f2bf(v);
            h[j] = hb; l[j] = f2bf(v - bf2f(hb));
            float v2 = a1[j]; short hb2 = f2bf(v2);
            h[4 + j] = hb2; l[4 + j] = f2bf(v2 - bf2f(hb2));
        }
        Bh[kt] = h; Bl[kt] = l;
    }

    f32x4 acc[NCT];
    #pragma unroll
    for (int ct = 0; ct < NCT; ++ct) acc[ct] = (f32x4)(0.f);

    #pragma unroll
    for (int ct = 0; ct < NCT; ++ct)
    #pragma unroll
    for (int kt = 0; kt < 2; ++kt) {
        const int fidx = (ct * 2 + kt) * 64 + lane;
        s16x8 Ah = *(const s16x8*)(PH + (size_t)fidx * 8);
        s16x8 Al = *(const s16x8*)(PL + (size_t)fidx * 8);
        acc[ct] = __builtin_amdgcn_mfma_f32_16x16x32_bf16(Ah, Bh[kt], acc[ct], 0, 0, 0);
        acc[ct] = __builtin_amdgcn_mfma_f32_16x16x32_bf16(Al, Bh[kt], acc[ct], 0, 0, 0);
        acc[ct] = __builtin_amdgcn_mfma_f32_16x16x32_bf16(Ah, Bl[kt], acc[ct], 0, 0, 0);
    }

    const int wrow = lane & 15, q4 = (lane >> 4) << 2;
    #pragma unroll
    for (int ct = 0; ct < NCT; ++ct)
        *(f32x4*)&sT[wid][wrow * 120 + ct * 16 + q4] = acc[ct];
    asm volatile("s_waitcnt lgkmcnt(0)" ::: "memory");

    if (rbase + 16 <= (long)n) {
        #pragma unroll
        for (int s = 0; s < 7; ++s) {
            int f = s * 64 + lane;                   // 448 f32x4 chunks per tile
            int row = f / 28, ch = f % 28;
            f32x4 v = *(const f32x4*)&sT[wid][row * 120 + ch * 4];
            f32x4 bv = *(const f32x4*)&bo[ch * 4];
            v.x += bv.x; v.y += bv.y; v.z += bv.z; v.w += bv.w;
            *(f32x4*)&Y[rbase * 112 + f * 4] = v;
        }
    } else {
        #pragma unroll
        for (int s = 0; s < 7; ++s) {
            int f = s * 64 + lane;
            int row = f / 28, ch = f % 28;
            f32x4 v = *(const f32x4*)&sT[wid][row * 120 + ch * 4];
            #pragma unroll
            for (int jj = 0; jj < 4; ++jj) {
                long g = rbase * 112 + f * 4 + jj;
                if (g < (long)n * 112) Y[g] = v[jj] + bo[ch * 4 + jj];
            }
        }
    }
}

// ---------------- launch ----------------

extern "C" void kernel_launch(void* const* d_in, const int* in_sizes, int n_in,
                              void* d_out, int out_size, void* d_ws, size_t ws_size,
                              hipStream_t stream)
{
    const float* x   = (const float*)d_in[0];
    const int*   ei  = (const int*)d_in[1];
    const float* W1l = (const float*)d_in[2];
    const float* b1  = (const float*)d_in[3];
    const float* W1r = (const float*)d_in[4];
    const float* W2l = (const float*)d_in[5];
    const float* b2  = (const float*)d_in[6];
    const float* W2r = (const float*)d_in[7];
    const float* Wo  = (const float*)d_in[8];
    const float* bo  = (const float*)d_in[9];
    float* out = (float*)d_out;

    const int n = in_sizes[0] / 128;
    const int E = in_sizes[1] / 2;
    const int* srcI = ei;
    const int* dstI = ei + E;
    const int nchunk = (n + 1023) / 1024;
    const int nbkt   = (n + 511) >> 9;

    const size_t nn64 = (size_t)n * 64;
    float* A      = (float*)d_ws;                 // n*64
    float* C      = A + nn64;                     // n*64
    float* H      = C + nn64;                     // n*64
    int*   rowptr = (int*)(H + nn64);             // n+1
    int*   partial= rowptr + n + 1;               // 128
    int*   csr    = partial + 128;                // E
    int*   gcount = csr + E;                      // nbkt
    int*   gbase  = gcount + nbkt;                // nbkt+1
    int*   gcursor= gbase + nbkt + 1;             // nbkt
    int*   degi   = gcursor + nbkt;               // n
    short* PH1    = (short*)(degi + n);           // 16384
    short* PL1    = PH1 + 16384;                  // 16384
    short* PH2    = PL1 + 16384;                  // 8192
    short* PL2    = PH2 + 8192;                   // 8192
    short* PHo    = PL2 + 8192;                   // 7168
    short* PLo    = PHo + 7168;                   // 7168
    int*   packed = (int*)A;                      // E (aliases A: CSR-build phase only)

    // ---- weight fragment pack + CSR build (no global scattered atomics) ----
    pack_frags<<<16, 256, 0, stream>>>(W1l, W1r, W2l, W2r, Wo, PH1, PL1, PH2, PL2, PHo, PLo);
    hipMemsetAsync(gcount, 0, (size_t)nbkt * sizeof(int), stream);
    const int gE = (int)((E + 4095) / 4096);
    bucket_count<<<gE, 256, 0, stream>>>(dstI, gcount, E, nbkt);
    bucket_scan<<<1, 256, 0, stream>>>(gcount, gbase, gcursor, nbkt, E);
    bucket_scatter<<<gE, 256, 0, stream>>>(srcI, dstI, gcursor, packed, E, nbkt);
    bucket_deg<<<nbkt, 256, 0, stream>>>(packed, gbase, degi, n);
    scan_chunk<<<nchunk, 256, 0, stream>>>(degi, rowptr, partial, n);
    scan_partials<<<1, 64, 0, stream>>>(partial, nchunk);
    finalize_rowptr<<<(n + 256) / 256, 256, 0, stream>>>(rowptr, partial, n, E);
    bucket_fill<<<nbkt, 256, 0, stream>>>(packed, gbase, rowptr, csr, n);

    const long ntile = ((long)n + 15) >> 4;
    const int gmf = (int)((ntile + 7) / 8);       // 8 tiles (waves) per block

    // ---- layer 1 ----
    dual_gemm_mfma<128><<<gmf, 512, 0, stream>>>(x, PH1, PL1, A, C, n);
    pull_agg_ep<<<4096, 256, 0, stream>>>(A, rowptr, csr, C, b1, H, n);

    // ---- layer 2 ----
    dual_gemm_mfma<64><<<gmf, 512, 0, stream>>>(H, PH2, PL2, A, C, n);
    pull_agg_ep<<<4096, 256, 0, stream>>>(A, rowptr, csr, C, b2, H, n);

    // ---- output projection ----
    gemm_out_mfma<<<gmf, 512, 0, stream>>>(H, PHo, PLo, bo, out, n);
}

// Round 8
// 277.354 us; speedup vs baseline: 4.1209x; 1.1007x over previous
//
#include <hip/hip_runtime.h>

typedef float f32x4 __attribute__((ext_vector_type(4)));
typedef short s16x8 __attribute__((ext_vector_type(8)));
typedef short s16x4 __attribute__((ext_vector_type(4)));

// RNE fp32 -> bf16 (bit trick, valid for finite values)
__device__ __forceinline__ unsigned short f2bf(float f) {
    unsigned u = __builtin_bit_cast(unsigned, f);
    unsigned r = (u + 0x7FFFu + ((u >> 16) & 1u)) >> 16;
    return (unsigned short)r;
}
__device__ __forceinline__ float bf2f(unsigned short h) {
    unsigned u = ((unsigned)h) << 16;
    return __builtin_bit_cast(float, u);
}

// ---------------- weight fragment packing (one-time, tiny) ----------------
// MFMA operand-A fragment for W (K x C row-major), transposed role:
//   frag element j of lane: W[k0 + j][c],  k0 = kt*32 + (lane>>4)*8,  c = ct*16 + (lane&15)
// dual1: f=((m*4+ct)*4+kt)  m<2,ct<4,kt<4  -> 2048 entries
// dual2: f=((m*4+ct)*2+kt)  m<2,ct<4,kt<2  -> 1024 entries
// out:   f=(ct*2+kt)        ct<7,kt<2      ->  896 entries
__global__ __launch_bounds__(256)
void pack_frags(const float* __restrict__ W1l, const float* __restrict__ W1r,
                const float* __restrict__ W2l, const float* __restrict__ W2r,
                const float* __restrict__ Wo,
                short* __restrict__ PH1, short* __restrict__ PL1,
                short* __restrict__ PH2, short* __restrict__ PL2,
                short* __restrict__ PHo, short* __restrict__ PLo)
{
    const int tot = 2048 + 1024 + 896;
    for (int e = blockIdx.x * 256 + threadIdx.x; e < tot; e += gridDim.x * 256) {
        int lane, f, k0, c, stride;
        const float* W;
        short *PH, *PL;
        int idx;
        if (e < 2048) {
            idx = e; lane = e & 63; f = e >> 6;
            int kt = f & 3, ct = (f >> 2) & 3, m = f >> 4;
            W = m ? W1r : W1l; PH = PH1; PL = PL1;
            k0 = kt * 32 + ((lane >> 4) << 3);
            c  = ct * 16 + (lane & 15);
            stride = 64;
        } else if (e < 3072) {
            int e2 = e - 2048;
            idx = e2; lane = e2 & 63; f = e2 >> 6;
            int kt = f & 1, ct = (f >> 1) & 3, m = f >> 3;
            W = m ? W2r : W2l; PH = PH2; PL = PL2;
            k0 = kt * 32 + ((lane >> 4) << 3);
            c  = ct * 16 + (lane & 15);
            stride = 64;
        } else {
            int eo = e - 3072;
            idx = eo; lane = eo & 63; f = eo >> 6;
            int kt = f & 1, ct = f >> 1;
            W = Wo; PH = PHo; PL = PLo;
            k0 = kt * 32 + ((lane >> 4) << 3);
            c  = ct * 16 + (lane & 15);
            stride = 112;
        }
        short h[8], l[8];
        #pragma unroll
        for (int j = 0; j < 8; ++j) {
            float v = W[(size_t)(k0 + j) * stride + c];
            unsigned short hb = f2bf(v);
            h[j] = (short)hb;
            l[j] = (short)f2bf(v - bf2f(hb));
        }
        #pragma unroll
        for (int j = 0; j < 8; ++j) { PH[idx * 8 + j] = h[j]; PL[idx * 8 + j] = l[j]; }
    }
}

// ---------------- CSR build via bucket sort (LDS atomics only) ----------------
// 512 nodes/bucket. packed edge = (src << 9) | (dst & 511). Needs n <= 2^23.

__global__ __launch_bounds__(256)
void bucket_count(const int* __restrict__ dst, int* __restrict__ gcount, int E, int B)
{
    __shared__ int lh[256];
    for (int i = threadIdx.x; i < B; i += 256) lh[i] = 0;
    __syncthreads();
    long base = (long)blockIdx.x * 4096;
    #pragma unroll
    for (int j = 0; j < 16; ++j) {
        long e = base + j * 256 + threadIdx.x;
        if (e < E) atomicAdd(&lh[dst[e] >> 9], 1);
    }
    __syncthreads();
    for (int i = threadIdx.x; i < B; i += 256) {
        int v = lh[i];
        if (v) atomicAdd(&gcount[i], v);
    }
}

__global__ void bucket_scan(const int* __restrict__ gcount, int* __restrict__ gbase,
                            int* __restrict__ gcursor, int B, int E)
{
    __shared__ int s[256];
    int t = threadIdx.x;
    int v = (t < B) ? gcount[t] : 0;
    s[t] = v;
    __syncthreads();
    for (int off = 1; off < 256; off <<= 1) {
        int u = (t >= off) ? s[t - off] : 0;
        __syncthreads();
        s[t] += u;
        __syncthreads();
    }
    int ex = s[t] - v;
    if (t < B) { gbase[t] = ex; gcursor[t] = ex; }
    if (t == 0) gbase[B] = E;
}

__global__ __launch_bounds__(256)
void bucket_scatter(const int* __restrict__ src, const int* __restrict__ dst,
                    int* __restrict__ gcursor, int* __restrict__ packed, int E, int B)
{
    __shared__ int lh[256];
    __shared__ int lbase[256];
    for (int i = threadIdx.x; i < B; i += 256) lh[i] = 0;
    __syncthreads();
    long base = (long)blockIdx.x * 4096;
    int bkt[16], rnk[16], pk[16];
    #pragma unroll
    for (int j = 0; j < 16; ++j) {
        long e = base + j * 256 + threadIdx.x;
        if (e < E) {
            int d = dst[e], s = src[e];
            bkt[j] = d >> 9;
            pk[j]  = (s << 9) | (d & 511);
            rnk[j] = atomicAdd(&lh[bkt[j]], 1);
        } else bkt[j] = -1;
    }
    __syncthreads();
    for (int i = threadIdx.x; i < B; i += 256) {
        int v = lh[i];
        lbase[i] = v ? atomicAdd(&gcursor[i], v) : 0;
    }
    __syncthreads();
    #pragma unroll
    for (int j = 0; j < 16; ++j)
        if (bkt[j] >= 0) packed[lbase[bkt[j]] + rnk[j]] = pk[j];
}

__global__ __launch_bounds__(256)
void bucket_deg(const int* __restrict__ packed, const int* __restrict__ gbase,
                int* __restrict__ degi, int n)
{
    __shared__ int h[512];
    int b = blockIdx.x;
    int nb = b * 512;
    int cnt = n - nb; if (cnt > 512) cnt = 512;
    for (int i = threadIdx.x; i < cnt; i += 256) h[i] = 0;
    __syncthreads();
    int s = gbase[b], e = gbase[b + 1];
    for (int i = s + threadIdx.x; i < e; i += 256)
        atomicAdd(&h[packed[i] & 511], 1);
    __syncthreads();
    for (int i = threadIdx.x; i < cnt; i += 256) degi[nb + i] = h[i];
}

__global__ __launch_bounds__(256)
void scan_chunk(const int* __restrict__ degi, int* __restrict__ rowptr,
                int* __restrict__ partial, int n)
{
    __shared__ int s[256];
    const int b = blockIdx.x, t = threadIdx.x;
    const int base = b * 1024 + t * 4;
    int v[4], sum = 0;
    #pragma unroll
    for (int j = 0; j < 4; ++j) {
        int idx = base + j;
        v[j] = (idx < n) ? degi[idx] : 0;
        sum += v[j];
    }
    s[t] = sum;
    __syncthreads();
    #pragma unroll
    for (int off = 1; off < 256; off <<= 1) {
        int x = (t >= off) ? s[t - off] : 0;
        __syncthreads();
        s[t] += x;
        __syncthreads();
    }
    int run = s[t] - sum;
    if (t == 255) partial[b] = s[255];
    #pragma unroll
    for (int j = 0; j < 4; ++j) {
        int idx = base + j;
        if (idx < n) { rowptr[idx] = run; run += v[j]; }
    }
}

__global__ void scan_partials(int* partial, int nchunk)
{
    int t = threadIdx.x;
    if (nchunk > 128) {
        if (t == 0) {
            int acc = 0;
            for (int i = 0; i < nchunk; ++i) { int p = partial[i]; partial[i] = acc; acc += p; }
        }
        return;
    }
    int a = (t < nchunk) ? partial[t] : 0;
    int b = (t + 64 < nchunk) ? partial[t + 64] : 0;
    int a0 = a, b0 = b;
    #pragma unroll
    for (int off = 1; off < 64; off <<= 1) {
        int u = __shfl_up(a, off, 64);
        if (t >= off) a += u;
    }
    int atot = __shfl(a, 63, 64);
    #pragma unroll
    for (int off = 1; off < 64; off <<= 1) {
        int u = __shfl_up(b, off, 64);
        if (t >= off) b += u;
    }
    if (t < nchunk) partial[t] = a - a0;
    if (t + 64 < nchunk) partial[t + 64] = atot + b - b0;
}

__global__ __launch_bounds__(256)
void finalize_rowptr(int* __restrict__ rowptr, const int* __restrict__ partial, int n, int E)
{
    int i = blockIdx.x * blockDim.x + threadIdx.x;
    if (i < n) rowptr[i] += partial[i >> 10];
    if (i == n) rowptr[n] = E;
}

__global__ __launch_bounds__(256)
void bucket_fill(const int* __restrict__ packed, const int* __restrict__ gbase,
                 const int* __restrict__ rowptr, int* __restrict__ csr, int n)
{
    __shared__ int cur[512];
    int b = blockIdx.x;
    int nb = b * 512;
    int cnt = n - nb; if (cnt > 512) cnt = 512;
    for (int i = threadIdx.x; i < cnt; i += 256) cur[i] = rowptr[nb + i];
    __syncthreads();
    int s = gbase[b], e = gbase[b + 1];
    for (int i = s + threadIdx.x; i < e; i += 256) {
        int p = packed[i];
        int pos = atomicAdd(&cur[p & 511], 1);
        csr[pos] = p >> 9;
    }
}

// ---- pull + fused epilogue (all-bf16 features):
//      H = relu(sum_neigh(feat)/max(deg,1) + C + bias) ----
__global__ __launch_bounds__(256)
void pull_agg_ep_b16(const unsigned short* __restrict__ feat, const int* __restrict__ rowptr,
                     const int* __restrict__ csr, const unsigned short* __restrict__ C,
                     const float* __restrict__ bias, unsigned short* __restrict__ H, int n)
{
    const int lane = threadIdx.x & 63;
    const int wid  = threadIdx.x >> 6;
    const long w   = (long)blockIdx.x * 4 + wid;
    const long nw  = (long)gridDim.x * 4;
    const float bv = bias[lane];
    for (long row = w; row < n; row += nw) {
        const int s = rowptr[row], e = rowptr[row + 1];
        float acc = 0.f;
        int i = s;
        for (; i + 8 <= e; i += 8) {
            int i0 = csr[i],     i1 = csr[i + 1], i2 = csr[i + 2], i3 = csr[i + 3];
            int i4 = csr[i + 4], i5 = csr[i + 5], i6 = csr[i + 6], i7 = csr[i + 7];
            unsigned short v0 = feat[(size_t)i0 * 64 + lane];
            unsigned short v1 = feat[(size_t)i1 * 64 + lane];
            unsigned short v2 = feat[(size_t)i2 * 64 + lane];
            unsigned short v3 = feat[(size_t)i3 * 64 + lane];
            unsigned short v4 = feat[(size_t)i4 * 64 + lane];
            unsigned short v5 = feat[(size_t)i5 * 64 + lane];
            unsigned short v6 = feat[(size_t)i6 * 64 + lane];
            unsigned short v7 = feat[(size_t)i7 * 64 + lane];
            acc += bf2f(v0) + bf2f(v1) + bf2f(v2) + bf2f(v3)
                 + bf2f(v4) + bf2f(v5) + bf2f(v6) + bf2f(v7);
        }
        for (; i < e; ++i) acc += bf2f(feat[(size_t)csr[i] * 64 + lane]);
        float d = (float)(e - s);
        d = d > 1.f ? d : 1.f;
        float v = acc / d + bf2f(C[(size_t)row * 64 + lane]) + bv;
        H[(size_t)row * 64 + lane] = f2bf(v > 0.f ? v : 0.f);
    }
}

// ---------------- MFMA GEMMs, transposed-D, fragment-packed weights ----------------
// D = W^T_frag (A) x X_frag (B): lane holds output row r = rbase+(lane&15),
// cols c = ct*16 + (lane>>4)*4 + reg.
// Epilogue: per-wave LDS transpose -> fully-contiguous wide stores.

// layer 1: f32 input (3-term hi/lo split), bf16 output
__global__ __launch_bounds__(512)
void dual_gemm_f32in(const float* __restrict__ X, const short* __restrict__ PH,
                     const short* __restrict__ PL, unsigned short* __restrict__ Yl,
                     unsigned short* __restrict__ Yr, int n)
{
    constexpr int K = 128, NKT = 4;
    __shared__ unsigned short sT[8][16 * 72];    // 18 KB
    const int lane = threadIdx.x & 63;
    const int wid  = threadIdx.x >> 6;
    const long ntile = ((long)n + 15) >> 4;
    long t = (long)blockIdx.x * 8 + wid;
    if (t >= ntile) return;
    const long rbase = t << 4;
    long arow = rbase + (lane & 15);
    if (arow >= n) arow = n - 1;
    const int koff = (lane >> 4) << 3;
    const float* xr = X + arow * K + koff;

    s16x8 Bh[NKT], Bl[NKT];
    #pragma unroll
    for (int kt = 0; kt < NKT; ++kt) {
        f32x4 a0 = *(const f32x4*)(xr + kt * 32);
        f32x4 a1 = *(const f32x4*)(xr + kt * 32 + 4);
        s16x8 h, l;
        #pragma unroll
        for (int j = 0; j < 4; ++j) {
            float v = a0[j]; unsigned short hb = f2bf(v);
            h[j] = (short)hb; l[j] = (short)f2bf(v - bf2f(hb));
            float v2 = a1[j]; unsigned short hb2 = f2bf(v2);
            h[4 + j] = (short)hb2; l[4 + j] = (short)f2bf(v2 - bf2f(hb2));
        }
        Bh[kt] = h; Bl[kt] = l;
    }

    f32x4 acc[2][4];
    #pragma unroll
    for (int m = 0; m < 2; ++m)
        #pragma unroll
        for (int ct = 0; ct < 4; ++ct) acc[m][ct] = (f32x4)(0.f);

    #pragma unroll
    for (int m = 0; m < 2; ++m)
    #pragma unroll
    for (int ct = 0; ct < 4; ++ct)
    #pragma unroll
    for (int kt = 0; kt < NKT; ++kt) {
        const int fidx = ((((m << 2) | ct) * NKT) + kt) * 64 + lane;
        s16x8 Ah = *(const s16x8*)(PH + (size_t)fidx * 8);
        s16x8 Al = *(const s16x8*)(PL + (size_t)fidx * 8);
        acc[m][ct] = __builtin_amdgcn_mfma_f32_16x16x32_bf16(Ah, Bh[kt], acc[m][ct], 0, 0, 0);
        acc[m][ct] = __builtin_amdgcn_mfma_f32_16x16x32_bf16(Al, Bh[kt], acc[m][ct], 0, 0, 0);
        acc[m][ct] = __builtin_amdgcn_mfma_f32_16x16x32_bf16(Ah, Bl[kt], acc[m][ct], 0, 0, 0);
    }

    const int wrow = lane & 15, q4 = (lane >> 4) << 2;
    #pragma unroll
    for (int m = 0; m < 2; ++m) {
        unsigned short* __restrict__ Y = m ? Yr : Yl;
        #pragma unroll
        for (int ct = 0; ct < 4; ++ct) {
            s16x4 pv;
            #pragma unroll
            for (int j = 0; j < 4; ++j) pv[j] = (short)f2bf(acc[m][ct][j]);
            *(s16x4*)&sT[wid][wrow * 72 + ct * 16 + q4] = pv;
        }
        asm volatile("s_waitcnt lgkmcnt(0)" ::: "memory");
        if (rbase + 16 <= (long)n) {
            #pragma unroll
            for (int s = 0; s < 2; ++s) {
                int f = s * 64 + lane;               // 128 chunks of 8 bf16
                s16x8 v = *(const s16x8*)&sT[wid][(f >> 3) * 72 + ((f & 7) << 3)];
                *(s16x8*)&Y[rbase * 64 + (size_t)f * 8] = v;
            }
        } else {
            #pragma unroll
            for (int s = 0; s < 2; ++s) {
                int f = s * 64 + lane;
                s16x8 v = *(const s16x8*)&sT[wid][(f >> 3) * 72 + ((f & 7) << 3)];
                long g = rbase * 64 + (size_t)f * 8;
                #pragma unroll
                for (int jj = 0; jj < 8; ++jj)
                    if (g + jj < (long)n * 64) Y[g + jj] = (unsigned short)v[jj];
            }
        }
        asm volatile("s_waitcnt lgkmcnt(0)" ::: "memory");
    }
}

// layer 2: bf16 input (2-term), bf16 output. K=64.
__global__ __launch_bounds__(512)
void dual_gemm_b16in(const unsigned short* __restrict__ X, const short* __restrict__ PH,
                     const short* __restrict__ PL, unsigned short* __restrict__ Yl,
                     unsigned short* __restrict__ Yr, int n)
{
    constexpr int NKT = 2;
    __shared__ unsigned short sT[8][16 * 72];
    const int lane = threadIdx.x & 63;
    const int wid  = threadIdx.x >> 6;
    const long ntile = ((long)n + 15) >> 4;
    long t = (long)blockIdx.x * 8 + wid;
    if (t >= ntile) return;
    const long rbase = t << 4;
    long arow = rbase + (lane & 15);
    if (arow >= n) arow = n - 1;
    const int koff = (lane >> 4) << 3;
    const unsigned short* xr = X + arow * 64 + koff;

    s16x8 Bv[NKT];
    #pragma unroll
    for (int kt = 0; kt < NKT; ++kt) Bv[kt] = *(const s16x8*)(xr + kt * 32);

    f32x4 acc[2][4];
    #pragma unroll
    for (int m = 0; m < 2; ++m)
        #pragma unroll
        for (int ct = 0; ct < 4; ++ct) acc[m][ct] = (f32x4)(0.f);

    #pragma unroll
    for (int m = 0; m < 2; ++m)
    #pragma unroll
    for (int ct = 0; ct < 4; ++ct)
    #pragma unroll
    for (int kt = 0; kt < NKT; ++kt) {
        const int fidx = ((((m << 2) | ct) * NKT) + kt) * 64 + lane;
        s16x8 Ah = *(const s16x8*)(PH + (size_t)fidx * 8);
        s16x8 Al = *(const s16x8*)(PL + (size_t)fidx * 8);
        acc[m][ct] = __builtin_amdgcn_mfma_f32_16x16x32_bf16(Ah, Bv[kt], acc[m][ct], 0, 0, 0);
        acc[m][ct] = __builtin_amdgcn_mfma_f32_16x16x32_bf16(Al, Bv[kt], acc[m][ct], 0, 0, 0);
    }

    const int wrow = lane & 15, q4 = (lane >> 4) << 2;
    #pragma unroll
    for (int m = 0; m < 2; ++m) {
        unsigned short* __restrict__ Y = m ? Yr : Yl;
        #pragma unroll
        for (int ct = 0; ct < 4; ++ct) {
            s16x4 pv;
            #pragma unroll
            for (int j = 0; j < 4; ++j) pv[j] = (short)f2bf(acc[m][ct][j]);
            *(s16x4*)&sT[wid][wrow * 72 + ct * 16 + q4] = pv;
        }
        asm volatile("s_waitcnt lgkmcnt(0)" ::: "memory");
        if (rbase + 16 <= (long)n) {
            #pragma unroll
            for (int s = 0; s < 2; ++s) {
                int f = s * 64 + lane;
                s16x8 v = *(const s16x8*)&sT[wid][(f >> 3) * 72 + ((f & 7) << 3)];
                *(s16x8*)&Y[rbase * 64 + (size_t)f * 8] = v;
            }
        } else {
            #pragma unroll
            for (int s = 0; s < 2; ++s) {
                int f = s * 64 + lane;
                s16x8 v = *(const s16x8*)&sT[wid][(f >> 3) * 72 + ((f & 7) << 3)];
                long g = rbase * 64 + (size_t)f * 8;
                #pragma unroll
                for (int jj = 0; jj < 8; ++jj)
                    if (g + jj < (long)n * 64) Y[g + jj] = (unsigned short)v[jj];
            }
        }
        asm volatile("s_waitcnt lgkmcnt(0)" ::: "memory");
    }
}

// out = H2@Wo + bo. bf16 input (2-term), f32 output, OUTC=112 (7 col-tiles).
__global__ __launch_bounds__(512)
void gemm_out_mfma(const unsigned short* __restrict__ X, const short* __restrict__ PH,
                   const short* __restrict__ PL, const float* __restrict__ bo,
                   float* __restrict__ Y, int n)
{
    constexpr int NCT = 7;
    __shared__ float sT[8][16 * 120];    // 60 KB
    const int lane = threadIdx.x & 63;
    const int wid  = threadIdx.x >> 6;
    const long ntile = ((long)n + 15) >> 4;
    long t = (long)blockIdx.x * 8 + wid;
    if (t >= ntile) return;
    const long rbase = t << 4;
    long arow = rbase + (lane & 15);
    if (arow >= n) arow = n - 1;
    const int koff = (lane >> 4) << 3;
    const unsigned short* xr = X + arow * 64 + koff;

    s16x8 Bv[2];
    #pragma unroll
    for (int kt = 0; kt < 2; ++kt) Bv[kt] = *(const s16x8*)(xr + kt * 32);

    f32x4 acc[NCT];
    #pragma unroll
    for (int ct = 0; ct < NCT; ++ct) acc[ct] = (f32x4)(0.f);

    #pragma unroll
    for (int ct = 0; ct < NCT; ++ct)
    #pragma unroll
    for (int kt = 0; kt < 2; ++kt) {
        const int fidx = (ct * 2 + kt) * 64 + lane;
        s16x8 Ah = *(const s16x8*)(PH + (size_t)fidx * 8);
        s16x8 Al = *(const s16x8*)(PL + (size_t)fidx * 8);
        acc[ct] = __builtin_amdgcn_mfma_f32_16x16x32_bf16(Ah, Bv[kt], acc[ct], 0, 0, 0);
        acc[ct] = __builtin_amdgcn_mfma_f32_16x16x32_bf16(Al, Bv[kt], acc[ct], 0, 0, 0);
    }

    const int wrow = lane & 15, q4 = (lane >> 4) << 2;
    #pragma unroll
    for (int ct = 0; ct < NCT; ++ct)
        *(f32x4*)&sT[wid][wrow * 120 + ct * 16 + q4] = acc[ct];
    asm volatile("s_waitcnt lgkmcnt(0)" ::: "memory");

    if (rbase + 16 <= (long)n) {
        #pragma unroll
        for (int s = 0; s < 7; ++s) {
            int f = s * 64 + lane;                   // 448 f32x4 chunks per tile
            int row = f / 28, ch = f % 28;
            f32x4 v = *(const f32x4*)&sT[wid][row * 120 + ch * 4];
            f32x4 bv = *(const f32x4*)&bo[ch * 4];
            v.x += bv.x; v.y += bv.y; v.z += bv.z; v.w += bv.w;
            *(f32x4*)&Y[rbase * 112 + (size_t)f * 4] = v;
        }
    } else {
        #pragma unroll
        for (int s = 0; s < 7; ++s) {
            int f = s * 64 + lane;
            int row = f / 28, ch = f % 28;
            f32x4 v = *(const f32x4*)&sT[wid][row * 120 + ch * 4];
            #pragma unroll
            for (int jj = 0; jj < 4; ++jj) {
                long g = rbase * 112 + (size_t)f * 4 + jj;
                if (g < (long)n * 112) Y[g] = v[jj] + bo[ch * 4 + jj];
            }
        }
    }
}

// ---------------- launch ----------------

extern "C" void kernel_launch(void* const* d_in, const int* in_sizes, int n_in,
                              void* d_out, int out_size, void* d_ws, size_t ws_size,
                              hipStream_t stream)
{
    const float* x   = (const float*)d_in[0];
    const int*   ei  = (const int*)d_in[1];
    const float* W1l = (const float*)d_in[2];
    const float* b1  = (const float*)d_in[3];
    const float* W1r = (const float*)d_in[4];
    const float* W2l = (const float*)d_in[5];
    const float* b2  = (const float*)d_in[6];
    const float* W2r = (const float*)d_in[7];
    const float* Wo  = (const float*)d_in[8];
    const float* bo  = (const float*)d_in[9];
    float* out = (float*)d_out;

    const int n = in_sizes[0] / 128;
    const int E = in_sizes[1] / 2;
    const int* srcI = ei;
    const int* dstI = ei + E;
    const int nchunk = (n + 1023) / 1024;
    const int nbkt   = (n + 511) >> 9;

    const size_t nn64 = (size_t)n * 64;
    unsigned short* A = (unsigned short*)d_ws;    // n*64 bf16
    unsigned short* C = A + nn64;                 // n*64 bf16
    unsigned short* H = C + nn64;                 // n*64 bf16
    int*   rowptr = (int*)(H + nn64);             // n+1
    int*   partial= rowptr + n + 1;               // 128
    int*   csr    = partial + 128;                // E
    int*   gcount = csr + E;                      // nbkt
    int*   gbase  = gcount + nbkt;                // nbkt+1
    int*   gcursor= gbase + nbkt + 1;             // nbkt
    int*   degi   = gcursor + nbkt;               // n
    short* PH1    = (short*)(degi + n);           // 16384
    short* PL1    = PH1 + 16384;                  // 16384
    short* PH2    = PL1 + 16384;                  // 8192
    short* PL2    = PH2 + 8192;                   // 8192
    short* PHo    = PL2 + 8192;                   // 7168
    short* PLo    = PHo + 7168;                   // 7168
    int*   packed = (int*)A;                      // E ints (aliases A: CSR-build phase only)

    // ---- weight fragment pack + CSR build (no global scattered atomics) ----
    pack_frags<<<16, 256, 0, stream>>>(W1l, W1r, W2l, W2r, Wo, PH1, PL1, PH2, PL2, PHo, PLo);
    hipMemsetAsync(gcount, 0, (size_t)nbkt * sizeof(int), stream);
    const int gE = (int)((E + 4095) / 4096);
    bucket_count<<<gE, 256, 0, stream>>>(dstI, gcount, E, nbkt);
    bucket_scan<<<1, 256, 0, stream>>>(gcount, gbase, gcursor, nbkt, E);
    bucket_scatter<<<gE, 256, 0, stream>>>(srcI, dstI, gcursor, packed, E, nbkt);
    bucket_deg<<<nbkt, 256, 0, stream>>>(packed, gbase, degi, n);
    scan_chunk<<<nchunk, 256, 0, stream>>>(degi, rowptr, partial, n);
    scan_partials<<<1, 64, 0, stream>>>(partial, nchunk);
    finalize_rowptr<<<(n + 256) / 256, 256, 0, stream>>>(rowptr, partial, n, E);
    bucket_fill<<<nbkt, 256, 0, stream>>>(packed, gbase, rowptr, csr, n);

    const long ntile = ((long)n + 15) >> 4;
    const int gmf = (int)((ntile + 7) / 8);       // 8 tiles (waves) per block

    // ---- layer 1 ----
    dual_gemm_f32in<<<gmf, 512, 0, stream>>>(x, PH1, PL1, A, C, n);          // A=x@W1l, C=x@W1r (bf16)
    pull_agg_ep_b16<<<4096, 256, 0, stream>>>(A, rowptr, csr, C, b1, H, n);  // H=h1 (bf16)

    // ---- layer 2 ----
    dual_gemm_b16in<<<gmf, 512, 0, stream>>>(H, PH2, PL2, A, C, n);          // A=h1@W2l, C=h1@W2r
    pull_agg_ep_b16<<<4096, 256, 0, stream>>>(A, rowptr, csr, C, b2, H, n);  // H=h2

    // ---- output projection ----
    gemm_out_mfma<<<gmf, 512, 0, stream>>>(H, PHo, PLo, bo, out, n);
}

// Round 9
// 245.907 us; speedup vs baseline: 4.6479x; 1.1279x over previous
//
#include <hip/hip_runtime.h>

typedef float f32x4 __attribute__((ext_vector_type(4)));
typedef short s16x8 __attribute__((ext_vector_type(8)));
typedef short s16x4 __attribute__((ext_vector_type(4)));

// RNE fp32 -> bf16 (bit trick, valid for finite values)
__device__ __forceinline__ unsigned short f2bf(float f) {
    unsigned u = __builtin_bit_cast(unsigned, f);
    unsigned r = (u + 0x7FFFu + ((u >> 16) & 1u)) >> 16;
    return (unsigned short)r;
}
__device__ __forceinline__ float bf2f(unsigned short h) {
    unsigned u = ((unsigned)h) << 16;
    return __builtin_bit_cast(float, u);
}
__device__ __forceinline__ float bflo(unsigned u) {        // low ushort as bf16
    return __builtin_bit_cast(float, u << 16);
}
__device__ __forceinline__ float bfhi(unsigned u) {        // high ushort as bf16
    return __builtin_bit_cast(float, u & 0xffff0000u);
}

// ---------------- weight fragment packing (one-time, tiny) ----------------
__global__ __launch_bounds__(256)
void pack_frags(const float* __restrict__ W1l, const float* __restrict__ W1r,
                const float* __restrict__ W2l, const float* __restrict__ W2r,
                const float* __restrict__ Wo,
                short* __restrict__ PH1, short* __restrict__ PL1,
                short* __restrict__ PH2, short* __restrict__ PL2,
                short* __restrict__ PHo, short* __restrict__ PLo)
{
    const int tot = 2048 + 1024 + 896;
    for (int e = blockIdx.x * 256 + threadIdx.x; e < tot; e += gridDim.x * 256) {
        int lane, f, k0, c, stride;
        const float* W;
        short *PH, *PL;
        int idx;
        if (e < 2048) {
            idx = e; lane = e & 63; f = e >> 6;
            int kt = f & 3, ct = (f >> 2) & 3, m = f >> 4;
            W = m ? W1r : W1l; PH = PH1; PL = PL1;
            k0 = kt * 32 + ((lane >> 4) << 3);
            c  = ct * 16 + (lane & 15);
            stride = 64;
        } else if (e < 3072) {
            int e2 = e - 2048;
            idx = e2; lane = e2 & 63; f = e2 >> 6;
            int kt = f & 1, ct = (f >> 1) & 3, m = f >> 3;
            W = m ? W2r : W2l; PH = PH2; PL = PL2;
            k0 = kt * 32 + ((lane >> 4) << 3);
            c  = ct * 16 + (lane & 15);
            stride = 64;
        } else {
            int eo = e - 3072;
            idx = eo; lane = eo & 63; f = eo >> 6;
            int kt = f & 1, ct = f >> 1;
            W = Wo; PH = PHo; PL = PLo;
            k0 = kt * 32 + ((lane >> 4) << 3);
            c  = ct * 16 + (lane & 15);
            stride = 112;
        }
        short h[8], l[8];
        #pragma unroll
        for (int j = 0; j < 8; ++j) {
            float v = W[(size_t)(k0 + j) * stride + c];
            unsigned short hb = f2bf(v);
            h[j] = (short)hb;
            l[j] = (short)f2bf(v - bf2f(hb));
        }
        #pragma unroll
        for (int j = 0; j < 8; ++j) { PH[idx * 8 + j] = h[j]; PL[idx * 8 + j] = l[j]; }
    }
}

// ---------------- CSR build via bucket sort (LDS atomics only) ----------------
// 512 nodes/bucket. packed edge = (src << 9) | (dst & 511). Needs n <= 2^23.

__global__ __launch_bounds__(256)
void bucket_count(const int* __restrict__ dst, int* __restrict__ gcount, int E, int B)
{
    __shared__ int lh[256];
    for (int i = threadIdx.x; i < B; i += 256) lh[i] = 0;
    __syncthreads();
    long base = (long)blockIdx.x * 4096;
    #pragma unroll
    for (int j = 0; j < 16; ++j) {
        long e = base + j * 256 + threadIdx.x;
        if (e < E) atomicAdd(&lh[dst[e] >> 9], 1);
    }
    __syncthreads();
    for (int i = threadIdx.x; i < B; i += 256) {
        int v = lh[i];
        if (v) atomicAdd(&gcount[i], v);
    }
}

__global__ void bucket_scan(const int* __restrict__ gcount, int* __restrict__ gbase,
                            int* __restrict__ gcursor, int B, int E)
{
    __shared__ int s[256];
    int t = threadIdx.x;
    int v = (t < B) ? gcount[t] : 0;
    s[t] = v;
    __syncthreads();
    for (int off = 1; off < 256; off <<= 1) {
        int u = (t >= off) ? s[t - off] : 0;
        __syncthreads();
        s[t] += u;
        __syncthreads();
    }
    int ex = s[t] - v;
    if (t < B) { gbase[t] = ex; gcursor[t] = ex; }
    if (t == 0) gbase[B] = E;
}

__global__ __launch_bounds__(256)
void bucket_scatter(const int* __restrict__ src, const int* __restrict__ dst,
                    int* __restrict__ gcursor, int* __restrict__ packed, int E, int B)
{
    __shared__ int lh[256];
    __shared__ int lbase[256];
    for (int i = threadIdx.x; i < B; i += 256) lh[i] = 0;
    __syncthreads();
    long base = (long)blockIdx.x * 4096;
    int bkt[16], rnk[16], pk[16];
    #pragma unroll
    for (int j = 0; j < 16; ++j) {
        long e = base + j * 256 + threadIdx.x;
        if (e < E) {
            int d = dst[e], s = src[e];
            bkt[j] = d >> 9;
            pk[j]  = (s << 9) | (d & 511);
            rnk[j] = atomicAdd(&lh[bkt[j]], 1);
        } else bkt[j] = -1;
    }
    __syncthreads();
    for (int i = threadIdx.x; i < B; i += 256) {
        int v = lh[i];
        lbase[i] = v ? atomicAdd(&gcursor[i], v) : 0;
    }
    __syncthreads();
    #pragma unroll
    for (int j = 0; j < 16; ++j)
        if (bkt[j] >= 0) packed[lbase[bkt[j]] + rnk[j]] = pk[j];
}

__global__ __launch_bounds__(256)
void bucket_deg(const int* __restrict__ packed, const int* __restrict__ gbase,
                int* __restrict__ degi, int n)
{
    __shared__ int h[512];
    int b = blockIdx.x;
    int nb = b * 512;
    int cnt = n - nb; if (cnt > 512) cnt = 512;
    for (int i = threadIdx.x; i < cnt; i += 256) h[i] = 0;
    __syncthreads();
    int s = gbase[b], e = gbase[b + 1];
    for (int i = s + threadIdx.x; i < e; i += 256)
        atomicAdd(&h[packed[i] & 511], 1);
    __syncthreads();
    for (int i = threadIdx.x; i < cnt; i += 256) degi[nb + i] = h[i];
}

__global__ __launch_bounds__(256)
void scan_chunk(const int* __restrict__ degi, int* __restrict__ rowptr,
                int* __restrict__ partial, int n)
{
    __shared__ int s[256];
    const int b = blockIdx.x, t = threadIdx.x;
    const int base = b * 1024 + t * 4;
    int v[4], sum = 0;
    #pragma unroll
    for (int j = 0; j < 4; ++j) {
        int idx = base + j;
        v[j] = (idx < n) ? degi[idx] : 0;
        sum += v[j];
    }
    s[t] = sum;
    __syncthreads();
    #pragma unroll
    for (int off = 1; off < 256; off <<= 1) {
        int x = (t >= off) ? s[t - off] : 0;
        __syncthreads();
        s[t] += x;
        __syncthreads();
    }
    int run = s[t] - sum;
    if (t == 255) partial[b] = s[255];
    #pragma unroll
    for (int j = 0; j < 4; ++j) {
        int idx = base + j;
        if (idx < n) { rowptr[idx] = run; run += v[j]; }
    }
}

__global__ void scan_partials(int* partial, int nchunk)
{
    int t = threadIdx.x;
    if (nchunk > 128) {
        if (t == 0) {
            int acc = 0;
            for (int i = 0; i < nchunk; ++i) { int p = partial[i]; partial[i] = acc; acc += p; }
        }
        return;
    }
    int a = (t < nchunk) ? partial[t] : 0;
    int b = (t + 64 < nchunk) ? partial[t + 64] : 0;
    int a0 = a, b0 = b;
    #pragma unroll
    for (int off = 1; off < 64; off <<= 1) {
        int u = __shfl_up(a, off, 64);
        if (t >= off) a += u;
    }
    int atot = __shfl(a, 63, 64);
    #pragma unroll
    for (int off = 1; off < 64; off <<= 1) {
        int u = __shfl_up(b, off, 64);
        if (t >= off) b += u;
    }
    if (t < nchunk) partial[t] = a - a0;
    if (t + 64 < nchunk) partial[t + 64] = atot + b - b0;
}

__global__ __launch_bounds__(256)
void finalize_rowptr(int* __restrict__ rowptr, const int* __restrict__ partial, int n, int E)
{
    int i = blockIdx.x * blockDim.x + threadIdx.x;
    if (i < n) rowptr[i] += partial[i >> 10];
    if (i == n) rowptr[n] = E;
}

// csr stores BYTE offsets of source feature rows: (src * 128)
__global__ __launch_bounds__(256)
void bucket_fill(const int* __restrict__ packed, const int* __restrict__ gbase,
                 const int* __restrict__ rowptr, int* __restrict__ csr, int n)
{
    __shared__ int cur[512];
    int b = blockIdx.x;
    int nb = b * 512;
    int cnt = n - nb; if (cnt > 512) cnt = 512;
    for (int i = threadIdx.x; i < cnt; i += 256) cur[i] = rowptr[nb + i];
    __syncthreads();
    int s = gbase[b], e = gbase[b + 1];
    for (int i = s + threadIdx.x; i < e; i += 256) {
        int p = packed[i];
        int pos = atomicAdd(&cur[p & 511], 1);
        csr[pos] = (p >> 9) << 7;            // byte offset of 128B bf16 row
    }
}

// ---- pull + fused epilogue (bf16 feats, 2 edges per load instruction):
//      H = relu(sum_neigh(feat)/max(deg,1) + C + bias)
// lanes 0-31 process even-listed edges, 32-63 odd-listed; lane covers feats
// [2c, 2c+1] (c = lane&31) via one dword gather. Final __shfl_xor(32) combine.
__global__ __launch_bounds__(256)
void pull_agg_ep2(const unsigned short* __restrict__ feat, const int* __restrict__ rowptr,
                  const int* __restrict__ csrB, const unsigned short* __restrict__ C,
                  const float* __restrict__ bias, unsigned short* __restrict__ H, int n)
{
    const int lane = threadIdx.x & 63;
    const int half = lane >> 5;
    const int c    = lane & 31;
    const int wid  = threadIdx.x >> 6;
    const char* fb = (const char*)feat;
    const int cb   = c << 2;                  // byte offset within row
    const float2 bv = *(const float2*)&bias[c * 2];

    const long w  = (long)blockIdx.x * 4 + wid;
    const long nw = (long)gridDim.x * 4;
    for (long row = w; row < n; row += nw) {
        const int s = rowptr[row], e = rowptr[row + 1];
        float a0 = 0.f, a1 = 0.f;
        int i = s;
        for (; i + 8 <= e; i += 8) {
            int offs[4];
            #pragma unroll
            for (int j = 0; j < 4; ++j) offs[j] = csrB[i + 2 * j + half];
            #pragma unroll
            for (int j = 0; j < 4; ++j) {
                unsigned u = *(const unsigned*)(fb + offs[j] + cb);
                a0 += bflo(u);
                a1 += bfhi(u);
            }
        }
        for (; i + 2 <= e; i += 2) {
            unsigned u = *(const unsigned*)(fb + csrB[i + half] + cb);
            a0 += bflo(u);
            a1 += bfhi(u);
        }
        if (i < e && half == 0) {
            unsigned u = *(const unsigned*)(fb + csrB[i] + cb);
            a0 += bflo(u);
            a1 += bfhi(u);
        }
        a0 += __shfl_xor(a0, 32, 64);
        a1 += __shfl_xor(a1, 32, 64);

        float d = (float)(e - s);
        d = d > 1.f ? d : 1.f;
        float inv = 1.f / d;
        unsigned cu = *(const unsigned*)&C[(size_t)row * 64 + c * 2];
        float v0 = a0 * inv + bflo(cu) + bv.x;
        float v1 = a1 * inv + bfhi(cu) + bv.y;
        v0 = v0 > 0.f ? v0 : 0.f;
        v1 = v1 > 0.f ? v1 : 0.f;
        if (half == 0) {
            unsigned pv = (unsigned)f2bf(v0) | ((unsigned)f2bf(v1) << 16);
            *(unsigned*)&H[(size_t)row * 64 + c * 2] = pv;
        }
    }
}

// ---------------- MFMA GEMMs, transposed-D, fragment-packed weights ----------------

// layer 1: f32 input (3-term hi/lo split), bf16 output
__global__ __launch_bounds__(512)
void dual_gemm_f32in(const float* __restrict__ X, const short* __restrict__ PH,
                     const short* __restrict__ PL, unsigned short* __restrict__ Yl,
                     unsigned short* __restrict__ Yr, int n)
{
    constexpr int K = 128, NKT = 4;
    __shared__ unsigned short sT[8][16 * 72];
    const int lane = threadIdx.x & 63;
    const int wid  = threadIdx.x >> 6;
    const long ntile = ((long)n + 15) >> 4;
    long t = (long)blockIdx.x * 8 + wid;
    if (t >= ntile) return;
    const long rbase = t << 4;
    long arow = rbase + (lane & 15);
    if (arow >= n) arow = n - 1;
    const int koff = (lane >> 4) << 3;
    const float* xr = X + arow * K + koff;

    s16x8 Bh[NKT], Bl[NKT];
    #pragma unroll
    for (int kt = 0; kt < NKT; ++kt) {
        f32x4 a0 = *(const f32x4*)(xr + kt * 32);
        f32x4 a1 = *(const f32x4*)(xr + kt * 32 + 4);
        s16x8 h, l;
        #pragma unroll
        for (int j = 0; j < 4; ++j) {
            float v = a0[j]; unsigned short hb = f2bf(v);
            h[j] = (short)hb; l[j] = (short)f2bf(v - bf2f(hb));
            float v2 = a1[j]; unsigned short hb2 = f2bf(v2);
            h[4 + j] = (short)hb2; l[4 + j] = (short)f2bf(v2 - bf2f(hb2));
        }
        Bh[kt] = h; Bl[kt] = l;
    }

    f32x4 acc[2][4];
    #pragma unroll
    for (int m = 0; m < 2; ++m)
        #pragma unroll
        for (int ct = 0; ct < 4; ++ct) acc[m][ct] = (f32x4)(0.f);

    #pragma unroll
    for (int m = 0; m < 2; ++m)
    #pragma unroll
    for (int ct = 0; ct < 4; ++ct)
    #pragma unroll
    for (int kt = 0; kt < NKT; ++kt) {
        const int fidx = ((((m << 2) | ct) * NKT) + kt) * 64 + lane;
        s16x8 Ah = *(const s16x8*)(PH + (size_t)fidx * 8);
        s16x8 Al = *(const s16x8*)(PL + (size_t)fidx * 8);
        acc[m][ct] = __builtin_amdgcn_mfma_f32_16x16x32_bf16(Ah, Bh[kt], acc[m][ct], 0, 0, 0);
        acc[m][ct] = __builtin_amdgcn_mfma_f32_16x16x32_bf16(Al, Bh[kt], acc[m][ct], 0, 0, 0);
        acc[m][ct] = __builtin_amdgcn_mfma_f32_16x16x32_bf16(Ah, Bl[kt], acc[m][ct], 0, 0, 0);
    }

    const int wrow = lane & 15, q4 = (lane >> 4) << 2;
    #pragma unroll
    for (int m = 0; m < 2; ++m) {
        unsigned short* __restrict__ Y = m ? Yr : Yl;
        #pragma unroll
        for (int ct = 0; ct < 4; ++ct) {
            s16x4 pv;
            #pragma unroll
            for (int j = 0; j < 4; ++j) pv[j] = (short)f2bf(acc[m][ct][j]);
            *(s16x4*)&sT[wid][wrow * 72 + ct * 16 + q4] = pv;
        }
        asm volatile("s_waitcnt lgkmcnt(0)" ::: "memory");
        if (rbase + 16 <= (long)n) {
            #pragma unroll
            for (int s = 0; s < 2; ++s) {
                int f = s * 64 + lane;
                s16x8 v = *(const s16x8*)&sT[wid][(f >> 3) * 72 + ((f & 7) << 3)];
                *(s16x8*)&Y[rbase * 64 + (size_t)f * 8] = v;
            }
        } else {
            #pragma unroll
            for (int s = 0; s < 2; ++s) {
                int f = s * 64 + lane;
                s16x8 v = *(const s16x8*)&sT[wid][(f >> 3) * 72 + ((f & 7) << 3)];
                long g = rbase * 64 + (size_t)f * 8;
                #pragma unroll
                for (int jj = 0; jj < 8; ++jj)
                    if (g + jj < (long)n * 64) Y[g + jj] = (unsigned short)v[jj];
            }
        }
        asm volatile("s_waitcnt lgkmcnt(0)" ::: "memory");
    }
}

// layer 2: bf16 input (2-term), bf16 output. K=64.
__global__ __launch_bounds__(512)
void dual_gemm_b16in(const unsigned short* __restrict__ X, const short* __restrict__ PH,
                     const short* __restrict__ PL, unsigned short* __restrict__ Yl,
                     unsigned short* __restrict__ Yr, int n)
{
    constexpr int NKT = 2;
    __shared__ unsigned short sT[8][16 * 72];
    const int lane = threadIdx.x & 63;
    const int wid  = threadIdx.x >> 6;
    const long ntile = ((long)n + 15) >> 4;
    long t = (long)blockIdx.x * 8 + wid;
    if (t >= ntile) return;
    const long rbase = t << 4;
    long arow = rbase + (lane & 15);
    if (arow >= n) arow = n - 1;
    const int koff = (lane >> 4) << 3;
    const unsigned short* xr = X + arow * 64 + koff;

    s16x8 Bv[NKT];
    #pragma unroll
    for (int kt = 0; kt < NKT; ++kt) Bv[kt] = *(const s16x8*)(xr + kt * 32);

    f32x4 acc[2][4];
    #pragma unroll
    for (int m = 0; m < 2; ++m)
        #pragma unroll
        for (int ct = 0; ct < 4; ++ct) acc[m][ct] = (f32x4)(0.f);

    #pragma unroll
    for (int m = 0; m < 2; ++m)
    #pragma unroll
    for (int ct = 0; ct < 4; ++ct)
    #pragma unroll
    for (int kt = 0; kt < NKT; ++kt) {
        const int fidx = ((((m << 2) | ct) * NKT) + kt) * 64 + lane;
        s16x8 Ah = *(const s16x8*)(PH + (size_t)fidx * 8);
        s16x8 Al = *(const s16x8*)(PL + (size_t)fidx * 8);
        acc[m][ct] = __builtin_amdgcn_mfma_f32_16x16x32_bf16(Ah, Bv[kt], acc[m][ct], 0, 0, 0);
        acc[m][ct] = __builtin_amdgcn_mfma_f32_16x16x32_bf16(Al, Bv[kt], acc[m][ct], 0, 0, 0);
    }

    const int wrow = lane & 15, q4 = (lane >> 4) << 2;
    #pragma unroll
    for (int m = 0; m < 2; ++m) {
        unsigned short* __restrict__ Y = m ? Yr : Yl;
        #pragma unroll
        for (int ct = 0; ct < 4; ++ct) {
            s16x4 pv;
            #pragma unroll
            for (int j = 0; j < 4; ++j) pv[j] = (short)f2bf(acc[m][ct][j]);
            *(s16x4*)&sT[wid][wrow * 72 + ct * 16 + q4] = pv;
        }
        asm volatile("s_waitcnt lgkmcnt(0)" ::: "memory");
        if (rbase + 16 <= (long)n) {
            #pragma unroll
            for (int s = 0; s < 2; ++s) {
                int f = s * 64 + lane;
                s16x8 v = *(const s16x8*)&sT[wid][(f >> 3) * 72 + ((f & 7) << 3)];
                *(s16x8*)&Y[rbase * 64 + (size_t)f * 8] = v;
            }
        } else {
            #pragma unroll
            for (int s = 0; s < 2; ++s) {
                int f = s * 64 + lane;
                s16x8 v = *(const s16x8*)&sT[wid][(f >> 3) * 72 + ((f & 7) << 3)];
                long g = rbase * 64 + (size_t)f * 8;
                #pragma unroll
                for (int jj = 0; jj < 8; ++jj)
                    if (g + jj < (long)n * 64) Y[g + jj] = (unsigned short)v[jj];
            }
        }
        asm volatile("s_waitcnt lgkmcnt(0)" ::: "memory");
    }
}

// out = H2@Wo + bo. bf16 input (2-term), f32 output, OUTC=112 (7 col-tiles).
__global__ __launch_bounds__(512)
void gemm_out_mfma(const unsigned short* __restrict__ X, const short* __restrict__ PH,
                   const short* __restrict__ PL, const float* __restrict__ bo,
                   float* __restrict__ Y, int n)
{
    constexpr int NCT = 7;
    __shared__ float sT[8][16 * 120];
    const int lane = threadIdx.x & 63;
    const int wid  = threadIdx.x >> 6;
    const long ntile = ((long)n + 15) >> 4;
    long t = (long)blockIdx.x * 8 + wid;
    if (t >= ntile) return;
    const long rbase = t << 4;
    long arow = rbase + (lane & 15);
    if (arow >= n) arow = n - 1;
    const int koff = (lane >> 4) << 3;
    const unsigned short* xr = X + arow * 64 + koff;

    s16x8 Bv[2];
    #pragma unroll
    for (int kt = 0; kt < 2; ++kt) Bv[kt] = *(const s16x8*)(xr + kt * 32);

    f32x4 acc[NCT];
    #pragma unroll
    for (int ct = 0; ct < NCT; ++ct) acc[ct] = (f32x4)(0.f);

    #pragma unroll
    for (int ct = 0; ct < NCT; ++ct)
    #pragma unroll
    for (int kt = 0; kt < 2; ++kt) {
        const int fidx = (ct * 2 + kt) * 64 + lane;
        s16x8 Ah = *(const s16x8*)(PH + (size_t)fidx * 8);
        s16x8 Al = *(const s16x8*)(PL + (size_t)fidx * 8);
        acc[ct] = __builtin_amdgcn_mfma_f32_16x16x32_bf16(Ah, Bv[kt], acc[ct], 0, 0, 0);
        acc[ct] = __builtin_amdgcn_mfma_f32_16x16x32_bf16(Al, Bv[kt], acc[ct], 0, 0, 0);
    }

    const int wrow = lane & 15, q4 = (lane >> 4) << 2;
    #pragma unroll
    for (int ct = 0; ct < NCT; ++ct)
        *(f32x4*)&sT[wid][wrow * 120 + ct * 16 + q4] = acc[ct];
    asm volatile("s_waitcnt lgkmcnt(0)" ::: "memory");

    if (rbase + 16 <= (long)n) {
        #pragma unroll
        for (int s = 0; s < 7; ++s) {
            int f = s * 64 + lane;
            int row = f / 28, ch = f % 28;
            f32x4 v = *(const f32x4*)&sT[wid][row * 120 + ch * 4];
            f32x4 bv = *(const f32x4*)&bo[ch * 4];
            v.x += bv.x; v.y += bv.y; v.z += bv.z; v.w += bv.w;
            *(f32x4*)&Y[rbase * 112 + (size_t)f * 4] = v;
        }
    } else {
        #pragma unroll
        for (int s = 0; s < 7; ++s) {
            int f = s * 64 + lane;
            int row = f / 28, ch = f % 28;
            f32x4 v = *(const f32x4*)&sT[wid][row * 120 + ch * 4];
            #pragma unroll
            for (int jj = 0; jj < 4; ++jj) {
                long g = rbase * 112 + (size_t)f * 4 + jj;
                if (g < (long)n * 112) Y[g] = v[jj] + bo[ch * 4 + jj];
            }
        }
    }
}

// ---------------- launch ----------------

extern "C" void kernel_launch(void* const* d_in, const int* in_sizes, int n_in,
                              void* d_out, int out_size, void* d_ws, size_t ws_size,
                              hipStream_t stream)
{
    const float* x   = (const float*)d_in[0];
    const int*   ei  = (const int*)d_in[1];
    const float* W1l = (const float*)d_in[2];
    const float* b1  = (const float*)d_in[3];
    const float* W1r = (const float*)d_in[4];
    const float* W2l = (const float*)d_in[5];
    const float* b2  = (const float*)d_in[6];
    const float* W2r = (const float*)d_in[7];
    const float* Wo  = (const float*)d_in[8];
    const float* bo  = (const float*)d_in[9];
    float* out = (float*)d_out;

    const int n = in_sizes[0] / 128;
    const int E = in_sizes[1] / 2;
    const int* srcI = ei;
    const int* dstI = ei + E;
    const int nchunk = (n + 1023) / 1024;
    const int nbkt   = (n + 511) >> 9;

    const size_t nn64 = (size_t)n * 64;
    unsigned short* A = (unsigned short*)d_ws;    // n*64 bf16
    unsigned short* C = A + nn64;                 // n*64 bf16
    unsigned short* H = C + nn64;                 // n*64 bf16
    int*   rowptr = (int*)(H + nn64);             // n+1
    int*   partial= rowptr + n + 1;               // 128
    int*   csr    = partial + 128;                // E   (byte offsets)
    int*   gcount = csr + E;                      // nbkt
    int*   gbase  = gcount + nbkt;                // nbkt+1
    int*   gcursor= gbase + nbkt + 1;             // nbkt
    int*   degi   = gcursor + nbkt;               // n
    short* PH1    = (short*)(degi + n);           // 16384
    short* PL1    = PH1 + 16384;                  // 16384
    short* PH2    = PL1 + 16384;                  // 8192
    short* PL2    = PH2 + 8192;                   // 8192
    short* PHo    = PL2 + 8192;                   // 7168
    short* PLo    = PHo + 7168;                   // 7168
    int*   packed = (int*)A;                      // E ints (aliases A: CSR-build phase only)

    // ---- weight fragment pack + CSR build (no global scattered atomics) ----
    pack_frags<<<16, 256, 0, stream>>>(W1l, W1r, W2l, W2r, Wo, PH1, PL1, PH2, PL2, PHo, PLo);
    hipMemsetAsync(gcount, 0, (size_t)nbkt * sizeof(int), stream);
    const int gE = (int)((E + 4095) / 4096);
    bucket_count<<<gE, 256, 0, stream>>>(dstI, gcount, E, nbkt);
    bucket_scan<<<1, 256, 0, stream>>>(gcount, gbase, gcursor, nbkt, E);
    bucket_scatter<<<gE, 256, 0, stream>>>(srcI, dstI, gcursor, packed, E, nbkt);
    bucket_deg<<<nbkt, 256, 0, stream>>>(packed, gbase, degi, n);
    scan_chunk<<<nchunk, 256, 0, stream>>>(degi, rowptr, partial, n);
    scan_partials<<<1, 64, 0, stream>>>(partial, nchunk);
    finalize_rowptr<<<(n + 256) / 256, 256, 0, stream>>>(rowptr, partial, n, E);
    bucket_fill<<<nbkt, 256, 0, stream>>>(packed, gbase, rowptr, csr, n);

    const long ntile = ((long)n + 15) >> 4;
    const int gmf = (int)((ntile + 7) / 8);       // 8 tiles (waves) per block

    // ---- layer 1 ----
    dual_gemm_f32in<<<gmf, 512, 0, stream>>>(x, PH1, PL1, A, C, n);           // A=x@W1l, C=x@W1r (bf16)
    pull_agg_ep2<<<4096, 256, 0, stream>>>(A, rowptr, csr, C, b1, H, n);      // H=h1 (bf16)

    // ---- layer 2 ----
    dual_gemm_b16in<<<gmf, 512, 0, stream>>>(H, PH2, PL2, A, C, n);           // A=h1@W2l, C=h1@W2r
    pull_agg_ep2<<<4096, 256, 0, stream>>>(A, rowptr, csr, C, b2, H, n);      // H=h2

    // ---- output projection ----
    gemm_out_mfma<<<gmf, 512, 0, stream>>>(H, PHo, PLo, bo, out, n);
}

// Round 10
// 241.554 us; speedup vs baseline: 4.7316x; 1.0180x over previous
//
#include <hip/hip_runtime.h>

typedef float f32x4 __attribute__((ext_vector_type(4)));
typedef short s16x8 __attribute__((ext_vector_type(8)));
typedef short s16x4 __attribute__((ext_vector_type(4)));

// RNE fp32 -> bf16 (bit trick, valid for finite values)
__device__ __forceinline__ unsigned short f2bf(float f) {
    unsigned u = __builtin_bit_cast(unsigned, f);
    unsigned r = (u + 0x7FFFu + ((u >> 16) & 1u)) >> 16;
    return (unsigned short)r;
}
__device__ __forceinline__ float bf2f(unsigned short h) {
    unsigned u = ((unsigned)h) << 16;
    return __builtin_bit_cast(float, u);
}
__device__ __forceinline__ float bflo(unsigned u) {
    return __builtin_bit_cast(float, u << 16);
}
__device__ __forceinline__ float bfhi(unsigned u) {
    return __builtin_bit_cast(float, u & 0xffff0000u);
}

// ---------------- weight fragment packing (one-time, tiny) ----------------
__global__ __launch_bounds__(256)
void pack_frags(const float* __restrict__ W1l, const float* __restrict__ W1r,
                const float* __restrict__ W2l, const float* __restrict__ W2r,
                const float* __restrict__ Wo,
                short* __restrict__ PH1, short* __restrict__ PL1,
                short* __restrict__ PH2, short* __restrict__ PL2,
                short* __restrict__ PHo, short* __restrict__ PLo)
{
    const int tot = 2048 + 1024 + 896;
    for (int e = blockIdx.x * 256 + threadIdx.x; e < tot; e += gridDim.x * 256) {
        int lane, f, k0, c, stride;
        const float* W;
        short *PH, *PL;
        int idx;
        if (e < 2048) {
            idx = e; lane = e & 63; f = e >> 6;
            int kt = f & 3, ct = (f >> 2) & 3, m = f >> 4;
            W = m ? W1r : W1l; PH = PH1; PL = PL1;
            k0 = kt * 32 + ((lane >> 4) << 3);
            c  = ct * 16 + (lane & 15);
            stride = 64;
        } else if (e < 3072) {
            int e2 = e - 2048;
            idx = e2; lane = e2 & 63; f = e2 >> 6;
            int kt = f & 1, ct = (f >> 1) & 3, m = f >> 3;
            W = m ? W2r : W2l; PH = PH2; PL = PL2;
            k0 = kt * 32 + ((lane >> 4) << 3);
            c  = ct * 16 + (lane & 15);
            stride = 64;
        } else {
            int eo = e - 3072;
            idx = eo; lane = eo & 63; f = eo >> 6;
            int kt = f & 1, ct = f >> 1;
            W = Wo; PH = PHo; PL = PLo;
            k0 = kt * 32 + ((lane >> 4) << 3);
            c  = ct * 16 + (lane & 15);
            stride = 112;
        }
        short h[8], l[8];
        #pragma unroll
        for (int j = 0; j < 8; ++j) {
            float v = W[(size_t)(k0 + j) * stride + c];
            unsigned short hb = f2bf(v);
            h[j] = (short)hb;
            l[j] = (short)f2bf(v - bf2f(hb));
        }
        #pragma unroll
        for (int j = 0; j < 8; ++j) { PH[idx * 8 + j] = h[j]; PL[idx * 8 + j] = l[j]; }
    }
}

// ---------------- CSR build via bucket sort (LDS atomics only) ----------------
// 512 nodes/bucket. packed edge = (src << 9) | (dst & 511). Needs n <= 2^23.

__global__ __launch_bounds__(256)
void bucket_count(const int* __restrict__ dst, int* __restrict__ gcount, int E, int B)
{
    __shared__ int lh[256];
    for (int i = threadIdx.x; i < B; i += 256) lh[i] = 0;
    __syncthreads();
    long base = (long)blockIdx.x * 4096;
    #pragma unroll
    for (int j = 0; j < 16; ++j) {
        long e = base + j * 256 + threadIdx.x;
        if (e < E) atomicAdd(&lh[dst[e] >> 9], 1);
    }
    __syncthreads();
    for (int i = threadIdx.x; i < B; i += 256) {
        int v = lh[i];
        if (v) atomicAdd(&gcount[i], v);
    }
}

__global__ void bucket_scan(const int* __restrict__ gcount, int* __restrict__ gbase,
                            int* __restrict__ gcursor, int B, int E)
{
    __shared__ int s[256];
    int t = threadIdx.x;
    int v = (t < B) ? gcount[t] : 0;
    s[t] = v;
    __syncthreads();
    for (int off = 1; off < 256; off <<= 1) {
        int u = (t >= off) ? s[t - off] : 0;
        __syncthreads();
        s[t] += u;
        __syncthreads();
    }
    int ex = s[t] - v;
    if (t < B) { gbase[t] = ex; gcursor[t] = ex; }
    if (t == 0) gbase[B] = E;
}

__global__ __launch_bounds__(256)
void bucket_scatter(const int* __restrict__ src, const int* __restrict__ dst,
                    int* __restrict__ gcursor, int* __restrict__ packed, int E, int B)
{
    __shared__ int lh[256];
    __shared__ int lbase[256];
    for (int i = threadIdx.x; i < B; i += 256) lh[i] = 0;
    __syncthreads();
    long base = (long)blockIdx.x * 4096;
    int bkt[16], rnk[16], pk[16];
    #pragma unroll
    for (int j = 0; j < 16; ++j) {
        long e = base + j * 256 + threadIdx.x;
        if (e < E) {
            int d = dst[e], s = src[e];
            bkt[j] = d >> 9;
            pk[j]  = (s << 9) | (d & 511);
            rnk[j] = atomicAdd(&lh[bkt[j]], 1);
        } else bkt[j] = -1;
    }
    __syncthreads();
    for (int i = threadIdx.x; i < B; i += 256) {
        int v = lh[i];
        lbase[i] = v ? atomicAdd(&gcursor[i], v) : 0;
    }
    __syncthreads();
    #pragma unroll
    for (int j = 0; j < 16; ++j)
        if (bkt[j] >= 0) packed[lbase[bkt[j]] + rnk[j]] = pk[j];
}

__global__ __launch_bounds__(256)
void bucket_deg(const int* __restrict__ packed, const int* __restrict__ gbase,
                int* __restrict__ degi, int n)
{
    __shared__ int h[512];
    int b = blockIdx.x;
    int nb = b * 512;
    int cnt = n - nb; if (cnt > 512) cnt = 512;
    for (int i = threadIdx.x; i < cnt; i += 256) h[i] = 0;
    __syncthreads();
    int s = gbase[b], e = gbase[b + 1];
    for (int i = s + threadIdx.x; i < e; i += 256)
        atomicAdd(&h[packed[i] & 511], 1);
    __syncthreads();
    for (int i = threadIdx.x; i < cnt; i += 256) degi[nb + i] = h[i];
}

__global__ __launch_bounds__(256)
void scan_chunk(const int* __restrict__ degi, int* __restrict__ rowptr,
                int* __restrict__ partial, int n)
{
    __shared__ int s[256];
    const int b = blockIdx.x, t = threadIdx.x;
    const int base = b * 1024 + t * 4;
    int v[4], sum = 0;
    #pragma unroll
    for (int j = 0; j < 4; ++j) {
        int idx = base + j;
        v[j] = (idx < n) ? degi[idx] : 0;
        sum += v[j];
    }
    s[t] = sum;
    __syncthreads();
    #pragma unroll
    for (int off = 1; off < 256; off <<= 1) {
        int x = (t >= off) ? s[t - off] : 0;
        __syncthreads();
        s[t] += x;
        __syncthreads();
    }
    int run = s[t] - sum;
    if (t == 255) partial[b] = s[255];
    #pragma unroll
    for (int j = 0; j < 4; ++j) {
        int idx = base + j;
        if (idx < n) { rowptr[idx] = run; run += v[j]; }
    }
}

__global__ void scan_partials(int* partial, int nchunk)
{
    int t = threadIdx.x;
    if (nchunk > 128) {
        if (t == 0) {
            int acc = 0;
            for (int i = 0; i < nchunk; ++i) { int p = partial[i]; partial[i] = acc; acc += p; }
        }
        return;
    }
    int a = (t < nchunk) ? partial[t] : 0;
    int b = (t + 64 < nchunk) ? partial[t + 64] : 0;
    int a0 = a, b0 = b;
    #pragma unroll
    for (int off = 1; off < 64; off <<= 1) {
        int u = __shfl_up(a, off, 64);
        if (t >= off) a += u;
    }
    int atot = __shfl(a, 63, 64);
    #pragma unroll
    for (int off = 1; off < 64; off <<= 1) {
        int u = __shfl_up(b, off, 64);
        if (t >= off) b += u;
    }
    if (t < nchunk) partial[t] = a - a0;
    if (t + 64 < nchunk) partial[t + 64] = atot + b - b0;
}

__global__ __launch_bounds__(256)
void finalize_rowptr(int* __restrict__ rowptr, const int* __restrict__ partial, int n, int E)
{
    int i = blockIdx.x * blockDim.x + threadIdx.x;
    if (i < n) rowptr[i] += partial[i >> 10];
    if (i == n) rowptr[n] = E;
}

// csr stores BYTE offsets of source feature rows: (src * 128)
__global__ __launch_bounds__(256)
void bucket_fill(const int* __restrict__ packed, const int* __restrict__ gbase,
                 const int* __restrict__ rowptr, int* __restrict__ csr, int n)
{
    __shared__ int cur[512];
    int b = blockIdx.x;
    int nb = b * 512;
    int cnt = n - nb; if (cnt > 512) cnt = 512;
    for (int i = threadIdx.x; i < cnt; i += 256) cur[i] = rowptr[nb + i];
    __syncthreads();
    int s = gbase[b], e = gbase[b + 1];
    for (int i = s + threadIdx.x; i < e; i += 256) {
        int p = packed[i];
        int pos = atomicAdd(&cur[p & 511], 1);
        csr[pos] = (p >> 9) << 7;            // byte offset of 128B bf16 row
    }
}

// ---- pull + fused epilogue, TWO independent rows per wave (latency interleave).
// lanes 0-31 even-listed edges, 32-63 odd; lane covers feats [2c,2c+1] per dword.
// Epilogue: after shfl_xor(32), half 0 finishes row A, half 1 row B ->
// one coalesced 256B C-load and H-store per wave.
__global__ __launch_bounds__(256)
void pull_agg_ep2x(const unsigned short* __restrict__ feat, const int* __restrict__ rowptr,
                   const int* __restrict__ csrB, const unsigned short* __restrict__ C,
                   const float* __restrict__ bias, unsigned short* __restrict__ H, int n)
{
    const int lane = threadIdx.x & 63;
    const int half = lane >> 5;
    const int c    = lane & 31;
    const int wid  = threadIdx.x >> 6;
    const char* fb = (const char*)feat;
    const int cb   = c << 2;
    const float2 bv = *(const float2*)&bias[c * 2];

    const long w  = (long)blockIdx.x * 4 + wid;
    const long nw = (long)gridDim.x * 4;
    for (long rp = w * 2; rp < n; rp += nw * 2) {
        int2 rr = *(const int2*)&rowptr[rp];            // rp even -> 8B aligned
        const int sA = rr.x, eA = rr.y;
        const int sB = eA;
        const int eB = (rp + 1 < n) ? rowptr[rp + 2] : eA;

        float a0A = 0.f, a1A = 0.f, a0B = 0.f, a1B = 0.f;
        int iA = sA, iB = sB;

        for (;;) {
            const bool doA = (iA + 8 <= eA);
            const bool doB = (iB + 8 <= eB);
            if (!(doA | doB)) break;
            int offsA[4], offsB[4];
            if (doA) {
                #pragma unroll
                for (int j = 0; j < 4; ++j) offsA[j] = csrB[iA + 2 * j + half];
            }
            if (doB) {
                #pragma unroll
                for (int j = 0; j < 4; ++j) offsB[j] = csrB[iB + 2 * j + half];
            }
            if (doA) {
                #pragma unroll
                for (int j = 0; j < 4; ++j) {
                    unsigned u = *(const unsigned*)(fb + offsA[j] + cb);
                    a0A += bflo(u);
                    a1A += bfhi(u);
                }
                iA += 8;
            }
            if (doB) {
                #pragma unroll
                for (int j = 0; j < 4; ++j) {
                    unsigned u = *(const unsigned*)(fb + offsB[j] + cb);
                    a0B += bflo(u);
                    a1B += bfhi(u);
                }
                iB += 8;
            }
        }
        // tails (2-edge steps, then odd single edge on half 0)
        for (; iA + 2 <= eA; iA += 2) {
            unsigned u = *(const unsigned*)(fb + csrB[iA + half] + cb);
            a0A += bflo(u); a1A += bfhi(u);
        }
        if (iA < eA && half == 0) {
            unsigned u = *(const unsigned*)(fb + csrB[iA] + cb);
            a0A += bflo(u); a1A += bfhi(u);
        }
        for (; iB + 2 <= eB; iB += 2) {
            unsigned u = *(const unsigned*)(fb + csrB[iB + half] + cb);
            a0B += bflo(u); a1B += bfhi(u);
        }
        if (iB < eB && half == 0) {
            unsigned u = *(const unsigned*)(fb + csrB[iB] + cb);
            a0B += bflo(u); a1B += bfhi(u);
        }

        a0A += __shfl_xor(a0A, 32, 64);
        a1A += __shfl_xor(a1A, 32, 64);
        a0B += __shfl_xor(a0B, 32, 64);
        a1B += __shfl_xor(a1B, 32, 64);

        const long r = rp + half;                 // half0 -> row A, half1 -> row B
        if (r < n) {
            const int s_ = half ? sB : sA;
            const int e_ = half ? eB : eA;
            float m0 = half ? a0B : a0A;
            float m1 = half ? a1B : a1A;
            float d = (float)(e_ - s_);
            d = d > 1.f ? d : 1.f;
            float inv = 1.f / d;
            unsigned cu = *(const unsigned*)&C[(size_t)r * 64 + c * 2];
            float v0 = m0 * inv + bflo(cu) + bv.x;
            float v1 = m1 * inv + bfhi(cu) + bv.y;
            v0 = v0 > 0.f ? v0 : 0.f;
            v1 = v1 > 0.f ? v1 : 0.f;
            unsigned pv = (unsigned)f2bf(v0) | ((unsigned)f2bf(v1) << 16);
            *(unsigned*)&H[(size_t)r * 64 + c * 2] = pv;
        }
    }
}

// ---------------- MFMA GEMMs, transposed-D, fragment-packed weights ----------------

// layer 1: f32 input (3-term hi/lo split), bf16 output
__global__ __launch_bounds__(512)
void dual_gemm_f32in(const float* __restrict__ X, const short* __restrict__ PH,
                     const short* __restrict__ PL, unsigned short* __restrict__ Yl,
                     unsigned short* __restrict__ Yr, int n)
{
    constexpr int K = 128, NKT = 4;
    __shared__ unsigned short sT[8][16 * 72];
    const int lane = threadIdx.x & 63;
    const int wid  = threadIdx.x >> 6;
    const long ntile = ((long)n + 15) >> 4;
    long t = (long)blockIdx.x * 8 + wid;
    if (t >= ntile) return;
    const long rbase = t << 4;
    long arow = rbase + (lane & 15);
    if (arow >= n) arow = n - 1;
    const int koff = (lane >> 4) << 3;
    const float* xr = X + arow * K + koff;

    s16x8 Bh[NKT], Bl[NKT];
    #pragma unroll
    for (int kt = 0; kt < NKT; ++kt) {
        f32x4 a0 = *(const f32x4*)(xr + kt * 32);
        f32x4 a1 = *(const f32x4*)(xr + kt * 32 + 4);
        s16x8 h, l;
        #pragma unroll
        for (int j = 0; j < 4; ++j) {
            float v = a0[j]; unsigned short hb = f2bf(v);
            h[j] = (short)hb; l[j] = (short)f2bf(v - bf2f(hb));
            float v2 = a1[j]; unsigned short hb2 = f2bf(v2);
            h[4 + j] = (short)hb2; l[4 + j] = (short)f2bf(v2 - bf2f(hb2));
        }
        Bh[kt] = h; Bl[kt] = l;
    }

    f32x4 acc[2][4];
    #pragma unroll
    for (int m = 0; m < 2; ++m)
        #pragma unroll
        for (int ct = 0; ct < 4; ++ct) acc[m][ct] = (f32x4)(0.f);

    #pragma unroll
    for (int m = 0; m < 2; ++m)
    #pragma unroll
    for (int ct = 0; ct < 4; ++ct)
    #pragma unroll
    for (int kt = 0; kt < NKT; ++kt) {
        const int fidx = ((((m << 2) | ct) * NKT) + kt) * 64 + lane;
        s16x8 Ah = *(const s16x8*)(PH + (size_t)fidx * 8);
        s16x8 Al = *(const s16x8*)(PL + (size_t)fidx * 8);
        acc[m][ct] = __builtin_amdgcn_mfma_f32_16x16x32_bf16(Ah, Bh[kt], acc[m][ct], 0, 0, 0);
        acc[m][ct] = __builtin_amdgcn_mfma_f32_16x16x32_bf16(Al, Bh[kt], acc[m][ct], 0, 0, 0);
        acc[m][ct] = __builtin_amdgcn_mfma_f32_16x16x32_bf16(Ah, Bl[kt], acc[m][ct], 0, 0, 0);
    }

    const int wrow = lane & 15, q4 = (lane >> 4) << 2;
    #pragma unroll
    for (int m = 0; m < 2; ++m) {
        unsigned short* __restrict__ Y = m ? Yr : Yl;
        #pragma unroll
        for (int ct = 0; ct < 4; ++ct) {
            s16x4 pv;
            #pragma unroll
            for (int j = 0; j < 4; ++j) pv[j] = (short)f2bf(acc[m][ct][j]);
            *(s16x4*)&sT[wid][wrow * 72 + ct * 16 + q4] = pv;
        }
        asm volatile("s_waitcnt lgkmcnt(0)" ::: "memory");
        if (rbase + 16 <= (long)n) {
            #pragma unroll
            for (int s = 0; s < 2; ++s) {
                int f = s * 64 + lane;
                s16x8 v = *(const s16x8*)&sT[wid][(f >> 3) * 72 + ((f & 7) << 3)];
                *(s16x8*)&Y[rbase * 64 + (size_t)f * 8] = v;
            }
        } else {
            #pragma unroll
            for (int s = 0; s < 2; ++s) {
                int f = s * 64 + lane;
                s16x8 v = *(const s16x8*)&sT[wid][(f >> 3) * 72 + ((f & 7) << 3)];
                long g = rbase * 64 + (size_t)f * 8;
                #pragma unroll
                for (int jj = 0; jj < 8; ++jj)
                    if (g + jj < (long)n * 64) Y[g + jj] = (unsigned short)v[jj];
            }
        }
        asm volatile("s_waitcnt lgkmcnt(0)" ::: "memory");
    }
}

// layer 2: bf16 input (2-term), bf16 output. K=64.
__global__ __launch_bounds__(512)
void dual_gemm_b16in(const unsigned short* __restrict__ X, const short* __restrict__ PH,
                     const short* __restrict__ PL, unsigned short* __restrict__ Yl,
                     unsigned short* __restrict__ Yr, int n)
{
    constexpr int NKT = 2;
    __shared__ unsigned short sT[8][16 * 72];
    const int lane = threadIdx.x & 63;
    const int wid  = threadIdx.x >> 6;
    const long ntile = ((long)n + 15) >> 4;
    long t = (long)blockIdx.x * 8 + wid;
    if (t >= ntile) return;
    const long rbase = t << 4;
    long arow = rbase + (lane & 15);
    if (arow >= n) arow = n - 1;
    const int koff = (lane >> 4) << 3;
    const unsigned short* xr = X + arow * 64 + koff;

    s16x8 Bv[NKT];
    #pragma unroll
    for (int kt = 0; kt < NKT; ++kt) Bv[kt] = *(const s16x8*)(xr + kt * 32);

    f32x4 acc[2][4];
    #pragma unroll
    for (int m = 0; m < 2; ++m)
        #pragma unroll
        for (int ct = 0; ct < 4; ++ct) acc[m][ct] = (f32x4)(0.f);

    #pragma unroll
    for (int m = 0; m < 2; ++m)
    #pragma unroll
    for (int ct = 0; ct < 4; ++ct)
    #pragma unroll
    for (int kt = 0; kt < NKT; ++kt) {
        const int fidx = ((((m << 2) | ct) * NKT) + kt) * 64 + lane;
        s16x8 Ah = *(const s16x8*)(PH + (size_t)fidx * 8);
        s16x8 Al = *(const s16x8*)(PL + (size_t)fidx * 8);
        acc[m][ct] = __builtin_amdgcn_mfma_f32_16x16x32_bf16(Ah, Bv[kt], acc[m][ct], 0, 0, 0);
        acc[m][ct] = __builtin_amdgcn_mfma_f32_16x16x32_bf16(Al, Bv[kt], acc[m][ct], 0, 0, 0);
    }

    const int wrow = lane & 15, q4 = (lane >> 4) << 2;
    #pragma unroll
    for (int m = 0; m < 2; ++m) {
        unsigned short* __restrict__ Y = m ? Yr : Yl;
        #pragma unroll
        for (int ct = 0; ct < 4; ++ct) {
            s16x4 pv;
            #pragma unroll
            for (int j = 0; j < 4; ++j) pv[j] = (short)f2bf(acc[m][ct][j]);
            *(s16x4*)&sT[wid][wrow * 72 + ct * 16 + q4] = pv;
        }
        asm volatile("s_waitcnt lgkmcnt(0)" ::: "memory");
        if (rbase + 16 <= (long)n) {
            #pragma unroll
            for (int s = 0; s < 2; ++s) {
                int f = s * 64 + lane;
                s16x8 v = *(const s16x8*)&sT[wid][(f >> 3) * 72 + ((f & 7) << 3)];
                *(s16x8*)&Y[rbase * 64 + (size_t)f * 8] = v;
            }
        } else {
            #pragma unroll
            for (int s = 0; s < 2; ++s) {
                int f = s * 64 + lane;
                s16x8 v = *(const s16x8*)&sT[wid][(f >> 3) * 72 + ((f & 7) << 3)];
                long g = rbase * 64 + (size_t)f * 8;
                #pragma unroll
                for (int jj = 0; jj < 8; ++jj)
                    if (g + jj < (long)n * 64) Y[g + jj] = (unsigned short)v[jj];
            }
        }
        asm volatile("s_waitcnt lgkmcnt(0)" ::: "memory");
    }
}

// out = H2@Wo + bo. bf16 input (2-term), f32 output, OUTC=112 (7 col-tiles).
__global__ __launch_bounds__(512)
void gemm_out_mfma(const unsigned short* __restrict__ X, const short* __restrict__ PH,
                   const short* __restrict__ PL, const float* __restrict__ bo,
                   float* __restrict__ Y, int n)
{
    constexpr int NCT = 7;
    __shared__ float sT[8][16 * 120];
    const int lane = threadIdx.x & 63;
    const int wid  = threadIdx.x >> 6;
    const long ntile = ((long)n + 15) >> 4;
    long t = (long)blockIdx.x * 8 + wid;
    if (t >= ntile) return;
    const long rbase = t << 4;
    long arow = rbase + (lane & 15);
    if (arow >= n) arow = n - 1;
    const int koff = (lane >> 4) << 3;
    const unsigned short* xr = X + arow * 64 + koff;

    s16x8 Bv[2];
    #pragma unroll
    for (int kt = 0; kt < 2; ++kt) Bv[kt] = *(const s16x8*)(xr + kt * 32);

    f32x4 acc[NCT];
    #pragma unroll
    for (int ct = 0; ct < NCT; ++ct) acc[ct] = (f32x4)(0.f);

    #pragma unroll
    for (int ct = 0; ct < NCT; ++ct)
    #pragma unroll
    for (int kt = 0; kt < 2; ++kt) {
        const int fidx = (ct * 2 + kt) * 64 + lane;
        s16x8 Ah = *(const s16x8*)(PH + (size_t)fidx * 8);
        s16x8 Al = *(const s16x8*)(PL + (size_t)fidx * 8);
        acc[ct] = __builtin_amdgcn_mfma_f32_16x16x32_bf16(Ah, Bv[kt], acc[ct], 0, 0, 0);
        acc[ct] = __builtin_amdgcn_mfma_f32_16x16x32_bf16(Al, Bv[kt], acc[ct], 0, 0, 0);
    }

    const int wrow = lane & 15, q4 = (lane >> 4) << 2;
    #pragma unroll
    for (int ct = 0; ct < NCT; ++ct)
        *(f32x4*)&sT[wid][wrow * 120 + ct * 16 + q4] = acc[ct];
    asm volatile("s_waitcnt lgkmcnt(0)" ::: "memory");

    if (rbase + 16 <= (long)n) {
        #pragma unroll
        for (int s = 0; s < 7; ++s) {
            int f = s * 64 + lane;
            int row = f / 28, ch = f % 28;
            f32x4 v = *(const f32x4*)&sT[wid][row * 120 + ch * 4];
            f32x4 bv = *(const f32x4*)&bo[ch * 4];
            v.x += bv.x; v.y += bv.y; v.z += bv.z; v.w += bv.w;
            *(f32x4*)&Y[rbase * 112 + (size_t)f * 4] = v;
        }
    } else {
        #pragma unroll
        for (int s = 0; s < 7; ++s) {
            int f = s * 64 + lane;
            int row = f / 28, ch = f % 28;
            f32x4 v = *(const f32x4*)&sT[wid][row * 120 + ch * 4];
            #pragma unroll
            for (int jj = 0; jj < 4; ++jj) {
                long g = rbase * 112 + (size_t)f * 4 + jj;
                if (g < (long)n * 112) Y[g] = v[jj] + bo[ch * 4 + jj];
            }
        }
    }
}

// ---------------- launch ----------------

extern "C" void kernel_launch(void* const* d_in, const int* in_sizes, int n_in,
                              void* d_out, int out_size, void* d_ws, size_t ws_size,
                              hipStream_t stream)
{
    const float* x   = (const float*)d_in[0];
    const int*   ei  = (const int*)d_in[1];
    const float* W1l = (const float*)d_in[2];
    const float* b1  = (const float*)d_in[3];
    const float* W1r = (const float*)d_in[4];
    const float* W2l = (const float*)d_in[5];
    const float* b2  = (const float*)d_in[6];
    const float* W2r = (const float*)d_in[7];
    const float* Wo  = (const float*)d_in[8];
    const float* bo  = (const float*)d_in[9];
    float* out = (float*)d_out;

    const int n = in_sizes[0] / 128;
    const int E = in_sizes[1] / 2;
    const int* srcI = ei;
    const int* dstI = ei + E;
    const int nchunk = (n + 1023) / 1024;
    const int nbkt   = (n + 511) >> 9;

    const size_t nn64 = (size_t)n * 64;
    unsigned short* A = (unsigned short*)d_ws;    // n*64 bf16
    unsigned short* C = A + nn64;                 // n*64 bf16
    unsigned short* H = C + nn64;                 // n*64 bf16
    int*   rowptr = (int*)(H + nn64);             // n+1
    int*   partial= rowptr + n + 1;               // 128
    int*   csr    = partial + 128;                // E   (byte offsets)
    int*   gcount = csr + E;                      // nbkt
    int*   gbase  = gcount + nbkt;                // nbkt+1
    int*   gcursor= gbase + nbkt + 1;             // nbkt
    int*   degi   = gcursor + nbkt;               // n
    short* PH1    = (short*)(degi + n);           // 16384
    short* PL1    = PH1 + 16384;                  // 16384
    short* PH2    = PL1 + 16384;                  // 8192
    short* PL2    = PH2 + 8192;                   // 8192
    short* PHo    = PL2 + 8192;                   // 7168
    short* PLo    = PHo + 7168;                   // 7168
    int*   packed = (int*)A;                      // E ints (aliases A: CSR-build phase only)

    // ---- weight fragment pack + CSR build (no global scattered atomics) ----
    pack_frags<<<16, 256, 0, stream>>>(W1l, W1r, W2l, W2r, Wo, PH1, PL1, PH2, PL2, PHo, PLo);
    hipMemsetAsync(gcount, 0, (size_t)nbkt * sizeof(int), stream);
    const int gE = (int)((E + 4095) / 4096);
    bucket_count<<<gE, 256, 0, stream>>>(dstI, gcount, E, nbkt);
    bucket_scan<<<1, 256, 0, stream>>>(gcount, gbase, gcursor, nbkt, E);
    bucket_scatter<<<gE, 256, 0, stream>>>(srcI, dstI, gcursor, packed, E, nbkt);
    bucket_deg<<<nbkt, 256, 0, stream>>>(packed, gbase, degi, n);
    scan_chunk<<<nchunk, 256, 0, stream>>>(degi, rowptr, partial, n);
    scan_partials<<<1, 64, 0, stream>>>(partial, nchunk);
    finalize_rowptr<<<(n + 256) / 256, 256, 0, stream>>>(rowptr, partial, n, E);
    bucket_fill<<<nbkt, 256, 0, stream>>>(packed, gbase, rowptr, csr, n);

    const long ntile = ((long)n + 15) >> 4;
    const int gmf = (int)((ntile + 7) / 8);       // 8 tiles (waves) per block

    // ---- layer 1 ----
    dual_gemm_f32in<<<gmf, 512, 0, stream>>>(x, PH1, PL1, A, C, n);           // A=x@W1l, C=x@W1r (bf16)
    pull_agg_ep2x<<<4096, 256, 0, stream>>>(A, rowptr, csr, C, b1, H, n);     // H=h1 (bf16)

    // ---- layer 2 ----
    dual_gemm_b16in<<<gmf, 512, 0, stream>>>(H, PH2, PL2, A, C, n);           // A=h1@W2l, C=h1@W2r
    pull_agg_ep2x<<<4096, 256, 0, stream>>>(A, rowptr, csr, C, b2, H, n);     // H=h2

    // ---- output projection ----
    gemm_out_mfma<<<gmf, 512, 0, stream>>>(H, PHo, PLo, bo, out, n);
}

// Round 11
// 212.399 us; speedup vs baseline: 5.3811x; 1.1373x over previous
//
#include <hip/hip_runtime.h>

typedef float f32x4 __attribute__((ext_vector_type(4)));
typedef short s16x8 __attribute__((ext_vector_type(8)));
typedef short s16x4 __attribute__((ext_vector_type(4)));

__device__ __forceinline__ unsigned short f2bf(float f) {
    unsigned u = __builtin_bit_cast(unsigned, f);
    unsigned r = (u + 0x7FFFu + ((u >> 16) & 1u)) >> 16;
    return (unsigned short)r;
}
__device__ __forceinline__ float bf2f(unsigned short h) {
    unsigned u = ((unsigned)h) << 16;
    return __builtin_bit_cast(float, u);
}
__device__ __forceinline__ float bflo(unsigned u) {
    return __builtin_bit_cast(float, u << 16);
}
__device__ __forceinline__ float bfhi(unsigned u) {
    return __builtin_bit_cast(float, u & 0xffff0000u);
}

// ---------------- weight fragment packing ----------------
__global__ __launch_bounds__(256)
void pack_frags(const float* __restrict__ W1l, const float* __restrict__ W1r,
                const float* __restrict__ W2l, const float* __restrict__ W2r,
                const float* __restrict__ Wo,
                short* __restrict__ PH1, short* __restrict__ PL1,
                short* __restrict__ PH2, short* __restrict__ PL2,
                short* __restrict__ PHo, short* __restrict__ PLo)
{
    const int tot = 2048 + 1024 + 896;
    for (int e = blockIdx.x * 256 + threadIdx.x; e < tot; e += gridDim.x * 256) {
        int lane, f, k0, c, stride;
        const float* W;
        short *PH, *PL;
        int idx;
        if (e < 2048) {
            idx = e; lane = e & 63; f = e >> 6;
            int kt = f & 3, ct = (f >> 2) & 3, m = f >> 4;
            W = m ? W1r : W1l; PH = PH1; PL = PL1;
            k0 = kt * 32 + ((lane >> 4) << 3);
            c  = ct * 16 + (lane & 15);
            stride = 64;
        } else if (e < 3072) {
            int e2 = e - 2048;
            idx = e2; lane = e2 & 63; f = e2 >> 6;
            int kt = f & 1, ct = (f >> 1) & 3, m = f >> 3;
            W = m ? W2r : W2l; PH = PH2; PL = PL2;
            k0 = kt * 32 + ((lane >> 4) << 3);
            c  = ct * 16 + (lane & 15);
            stride = 64;
        } else {
            int eo = e - 3072;
            idx = eo; lane = eo & 63; f = eo >> 6;
            int kt = f & 1, ct = f >> 1;
            W = Wo; PH = PHo; PL = PLo;
            k0 = kt * 32 + ((lane >> 4) << 3);
            c  = ct * 16 + (lane & 15);
            stride = 112;
        }
        short h[8], l[8];
        #pragma unroll
        for (int j = 0; j < 8; ++j) {
            float v = W[(size_t)(k0 + j) * stride + c];
            unsigned short hb = f2bf(v);
            h[j] = (short)hb;
            l[j] = (short)f2bf(v - bf2f(hb));
        }
        #pragma unroll
        for (int j = 0; j < 8; ++j) { PH[idx * 8 + j] = h[j]; PL[idx * 8 + j] = l[j]; }
    }
}

// ---------------- fused: GEMM1 (x @ {W1l,W1r}) + bucket_count ----------------
// blocks [0, gemmBlocks): MFMA dual GEMM, f32 input (3-term hi/lo), bf16 out.
// blocks [gemmBlocks, ...): per-block LDS histogram of dst buckets (8192 edges).
__global__ __launch_bounds__(512)
void fused_gemm1_count(const float* __restrict__ X, const short* __restrict__ PH,
                       const short* __restrict__ PL, unsigned short* __restrict__ Yl,
                       unsigned short* __restrict__ Yr, int n,
                       const int* __restrict__ dst, int* __restrict__ gcount,
                       int E, int B, int gemmBlocks)
{
    __shared__ unsigned short sT[8][16 * 72];   // GEMM branch
    __shared__ int lh[512];                     // count branch

    if ((int)blockIdx.x >= gemmBlocks) {
        // ---- bucket_count ----
        for (int i = threadIdx.x; i < B; i += 512) lh[i] = 0;
        __syncthreads();
        long base = (long)(blockIdx.x - gemmBlocks) * 8192;
        #pragma unroll
        for (int j = 0; j < 16; ++j) {
            long e = base + j * 512 + threadIdx.x;
            if (e < E) atomicAdd(&lh[dst[e] >> 9], 1);
        }
        __syncthreads();
        for (int i = threadIdx.x; i < B; i += 512) {
            int v = lh[i];
            if (v) atomicAdd(&gcount[i], v);
        }
        return;
    }

    // ---- GEMM1 ----
    constexpr int K = 128, NKT = 4;
    const int lane = threadIdx.x & 63;
    const int wid  = threadIdx.x >> 6;
    const long ntile = ((long)n + 15) >> 4;
    long t = (long)blockIdx.x * 8 + wid;
    if (t >= ntile) return;
    const long rbase = t << 4;
    long arow = rbase + (lane & 15);
    if (arow >= n) arow = n - 1;
    const int koff = (lane >> 4) << 3;
    const float* xr = X + arow * K + koff;

    s16x8 Bh[NKT], Bl[NKT];
    #pragma unroll
    for (int kt = 0; kt < NKT; ++kt) {
        f32x4 a0 = *(const f32x4*)(xr + kt * 32);
        f32x4 a1 = *(const f32x4*)(xr + kt * 32 + 4);
        s16x8 h, l;
        #pragma unroll
        for (int j = 0; j < 4; ++j) {
            float v = a0[j]; unsigned short hb = f2bf(v);
            h[j] = (short)hb; l[j] = (short)f2bf(v - bf2f(hb));
            float v2 = a1[j]; unsigned short hb2 = f2bf(v2);
            h[4 + j] = (short)hb2; l[4 + j] = (short)f2bf(v2 - bf2f(hb2));
        }
        Bh[kt] = h; Bl[kt] = l;
    }

    f32x4 acc[2][4];
    #pragma unroll
    for (int m = 0; m < 2; ++m)
        #pragma unroll
        for (int ct = 0; ct < 4; ++ct) acc[m][ct] = (f32x4)(0.f);

    #pragma unroll
    for (int m = 0; m < 2; ++m)
    #pragma unroll
    for (int ct = 0; ct < 4; ++ct)
    #pragma unroll
    for (int kt = 0; kt < NKT; ++kt) {
        const int fidx = ((((m << 2) | ct) * NKT) + kt) * 64 + lane;
        s16x8 Ah = *(const s16x8*)(PH + (size_t)fidx * 8);
        s16x8 Al = *(const s16x8*)(PL + (size_t)fidx * 8);
        acc[m][ct] = __builtin_amdgcn_mfma_f32_16x16x32_bf16(Ah, Bh[kt], acc[m][ct], 0, 0, 0);
        acc[m][ct] = __builtin_amdgcn_mfma_f32_16x16x32_bf16(Al, Bh[kt], acc[m][ct], 0, 0, 0);
        acc[m][ct] = __builtin_amdgcn_mfma_f32_16x16x32_bf16(Ah, Bl[kt], acc[m][ct], 0, 0, 0);
    }

    const int wrow = lane & 15, q4 = (lane >> 4) << 2;
    #pragma unroll
    for (int m = 0; m < 2; ++m) {
        unsigned short* __restrict__ Y = m ? Yr : Yl;
        #pragma unroll
        for (int ct = 0; ct < 4; ++ct) {
            s16x4 pv;
            #pragma unroll
            for (int j = 0; j < 4; ++j) pv[j] = (short)f2bf(acc[m][ct][j]);
            *(s16x4*)&sT[wid][wrow * 72 + ct * 16 + q4] = pv;
        }
        asm volatile("s_waitcnt lgkmcnt(0)" ::: "memory");
        if (rbase + 16 <= (long)n) {
            #pragma unroll
            for (int s = 0; s < 2; ++s) {
                int f = s * 64 + lane;
                s16x8 v = *(const s16x8*)&sT[wid][(f >> 3) * 72 + ((f & 7) << 3)];
                *(s16x8*)&Y[rbase * 64 + (size_t)f * 8] = v;
            }
        } else {
            #pragma unroll
            for (int s = 0; s < 2; ++s) {
                int f = s * 64 + lane;
                s16x8 v = *(const s16x8*)&sT[wid][(f >> 3) * 72 + ((f & 7) << 3)];
                long g = rbase * 64 + (size_t)f * 8;
                #pragma unroll
                for (int jj = 0; jj < 8; ++jj)
                    if (g + jj < (long)n * 64) Y[g + jj] = (unsigned short)v[jj];
            }
        }
        asm volatile("s_waitcnt lgkmcnt(0)" ::: "memory");
    }
}

// ---------------- CSR build (bucket sort, padded lists) ----------------

__global__ void bucket_scan(const int* __restrict__ gcount, int* __restrict__ gbase,
                            int* __restrict__ gcursor, int B, int E)
{
    __shared__ int s[256];
    int t = threadIdx.x;
    int v = (t < B) ? gcount[t] : 0;
    s[t] = v;
    __syncthreads();
    for (int off = 1; off < 256; off <<= 1) {
        int u = (t >= off) ? s[t - off] : 0;
        __syncthreads();
        s[t] += u;
        __syncthreads();
    }
    int ex = s[t] - v;
    if (t < B) { gbase[t] = ex; gcursor[t] = ex; }
    if (t == 0) gbase[B] = E;
}

__global__ __launch_bounds__(256)
void bucket_scatter(const int* __restrict__ src, const int* __restrict__ dst,
                    int* __restrict__ gcursor, int* __restrict__ packed, int E, int B)
{
    __shared__ int lh[256];
    __shared__ int lbase[256];
    for (int i = threadIdx.x; i < B; i += 256) lh[i] = 0;
    __syncthreads();
    long base = (long)blockIdx.x * 4096;
    int bkt[16], rnk[16], pk[16];
    #pragma unroll
    for (int j = 0; j < 16; ++j) {
        long e = base + j * 256 + threadIdx.x;
        if (e < E) {
            int d = dst[e], s = src[e];
            bkt[j] = d >> 9;
            pk[j]  = (s << 9) | (d & 511);
            rnk[j] = atomicAdd(&lh[bkt[j]], 1);
        } else bkt[j] = -1;
    }
    __syncthreads();
    for (int i = threadIdx.x; i < B; i += 256) {
        int v = lh[i];
        lbase[i] = v ? atomicAdd(&gcursor[i], v) : 0;
    }
    __syncthreads();
    #pragma unroll
    for (int j = 0; j < 16; ++j)
        if (bkt[j] >= 0) packed[lbase[bkt[j]] + rnk[j]] = pk[j];
}

__global__ __launch_bounds__(256)
void bucket_hist(const int* __restrict__ packed, const int* __restrict__ gbase,
                 int* __restrict__ degi, int n)
{
    __shared__ int h[512];
    int b = blockIdx.x, nb = b << 9;
    int cnt = n - nb; if (cnt > 512) cnt = 512;
    for (int i = threadIdx.x; i < 512; i += 256) h[i] = 0;
    __syncthreads();
    int s = gbase[b], e = gbase[b + 1];
    for (int i = s + threadIdx.x; i < e; i += 256)
        atomicAdd(&h[packed[i] & 511], 1);
    __syncthreads();
    for (int i = threadIdx.x; i < cnt; i += 256) degi[nb + i] = h[i];
}

// scan of PADDED degrees: pad(d) = (d+7)&~7
__global__ __launch_bounds__(256)
void scan_chunk(const int* __restrict__ degi, int* __restrict__ rowptrP,
                int* __restrict__ partial, int n)
{
    __shared__ int s[256];
    const int b = blockIdx.x, t = threadIdx.x;
    const int base = b * 1024 + t * 4;
    int v[4], sum = 0;
    #pragma unroll
    for (int j = 0; j < 4; ++j) {
        int idx = base + j;
        v[j] = (idx < n) ? ((degi[idx] + 7) & ~7) : 0;
        sum += v[j];
    }
    s[t] = sum;
    __syncthreads();
    #pragma unroll
    for (int off = 1; off < 256; off <<= 1) {
        int x = (t >= off) ? s[t - off] : 0;
        __syncthreads();
        s[t] += x;
        __syncthreads();
    }
    int run = s[t] - sum;
    if (t == 255) partial[b] = s[255];
    #pragma unroll
    for (int j = 0; j < 4; ++j) {
        int idx = base + j;
        if (idx < n) { rowptrP[idx] = run; run += v[j]; }
    }
}

__global__ void scan_partials(int* partial, int nchunk)
{
    int t = threadIdx.x;
    if (nchunk > 128) {
        if (t == 0) {
            int acc = 0;
            for (int i = 0; i < nchunk; ++i) { int p = partial[i]; partial[i] = acc; acc += p; }
            partial[128] = acc;
        }
        return;
    }
    int a = (t < nchunk) ? partial[t] : 0;
    int b = (t + 64 < nchunk) ? partial[t + 64] : 0;
    int a0 = a, b0 = b;
    #pragma unroll
    for (int off = 1; off < 64; off <<= 1) {
        int u = __shfl_up(a, off, 64);
        if (t >= off) a += u;
    }
    int atot = __shfl(a, 63, 64);
    #pragma unroll
    for (int off = 1; off < 64; off <<= 1) {
        int u = __shfl_up(b, off, 64);
        if (t >= off) b += u;
    }
    int btot = __shfl(b, 63, 64);
    if (t < nchunk) partial[t] = a - a0;
    if (t + 64 < nchunk) partial[t + 64] = atot + b - b0;
    if (t == 0) partial[128] = atot + btot;
}

// add chunk prefixes; write rowptrP[n]; zero the dummy feat row (A row n)
__global__ __launch_bounds__(256)
void finalize_rowptr(int* __restrict__ rowptrP, const int* __restrict__ partial,
                     unsigned* __restrict__ Adummy, int n)
{
    int i = blockIdx.x * blockDim.x + threadIdx.x;
    if (i < n) rowptrP[i] += partial[i >> 10];
    if (i == n) rowptrP[n] = partial[128];
    if (i < 32) Adummy[i] = 0u;
}

// fill csr (byte offsets) + dummy-pad each list to its padded length
__global__ __launch_bounds__(256)
void bucket_fill(const int* __restrict__ packed, const int* __restrict__ gbase,
                 const int* __restrict__ rowptrP, int* __restrict__ csr,
                 int n, int dummyOff)
{
    __shared__ int cur[512];
    int b = blockIdx.x, nb = b << 9;
    int cnt = n - nb; if (cnt > 512) cnt = 512;
    for (int i = threadIdx.x; i < cnt; i += 256) cur[i] = rowptrP[nb + i];
    __syncthreads();
    int s = gbase[b], e = gbase[b + 1];
    for (int i = s + threadIdx.x; i < e; i += 256) {
        int p = packed[i];
        int pos = atomicAdd(&cur[p & 511], 1);
        csr[pos] = (p >> 9) << 7;
    }
    __syncthreads();
    for (int i = threadIdx.x; i < cnt; i += 256) {
        int end = rowptrP[nb + i + 1];
        for (int p = cur[i]; p < end; ++p) csr[p] = dummyOff;
    }
}

// ---- pull + fused epilogue, padded lists, pipelined offsets, 2 rows/wave ----
// half0 handles edges [i,i+4), half1 [i+4,i+8) -> one aligned int4 offset load.
__global__ __launch_bounds__(256)
void pull_agg_pad(const unsigned short* __restrict__ feat, const int* __restrict__ rowptrP,
                  const int* __restrict__ degi, const int* __restrict__ csrB,
                  const unsigned short* __restrict__ C, const float* __restrict__ bias,
                  unsigned short* __restrict__ H, int n)
{
    const int lane = threadIdx.x & 63;
    const int half = lane >> 5;
    const int c    = lane & 31;
    const int wid  = threadIdx.x >> 6;
    const char* fb = (const char*)feat;
    const int cb   = c << 2;
    const float2 bv = *(const float2*)&bias[c * 2];

    const long w  = (long)blockIdx.x * 4 + wid;
    const long nw = (long)gridDim.x * 4;
    for (long rp = w * 2; rp < n; rp += nw * 2) {
        int2 rr = *(const int2*)&rowptrP[rp];
        int eB = (rp + 1 < n) ? rowptrP[rp + 2] : rr.y;

        // hoisted epilogue loads (independent of gather loop)
        const long r = rp + half;
        int dg = 1; unsigned cu = 0;
        if (r < n) {
            dg = degi[r];
            cu = *(const unsigned*)&C[(size_t)r * 64 + (c << 1)];
        }

        int iA = rr.x + (half << 2);
        int iB = rr.y + (half << 2);
        const int endA = rr.y, endB = eB;
        bool dA = iA < endA, dB = iB < endB;
        int4 oA = (int4)(0), oB = (int4)(0);
        if (dA) oA = *(const int4*)&csrB[iA];
        if (dB) oB = *(const int4*)&csrB[iB];

        float a0A = 0.f, a1A = 0.f, a0B = 0.f, a1B = 0.f;
        while (dA | dB) {
            unsigned uA0, uA1, uA2, uA3, uB0, uB1, uB2, uB3;
            if (dA) {
                uA0 = *(const unsigned*)(fb + oA.x + cb);
                uA1 = *(const unsigned*)(fb + oA.y + cb);
                uA2 = *(const unsigned*)(fb + oA.z + cb);
                uA3 = *(const unsigned*)(fb + oA.w + cb);
            }
            if (dB) {
                uB0 = *(const unsigned*)(fb + oB.x + cb);
                uB1 = *(const unsigned*)(fb + oB.y + cb);
                uB2 = *(const unsigned*)(fb + oB.z + cb);
                uB3 = *(const unsigned*)(fb + oB.w + cb);
            }
            int niA = iA + 8, niB = iB + 8;
            bool ndA = niA < endA, ndB = niB < endB;
            int4 tA = oA, tB = oB;
            if (ndA) tA = *(const int4*)&csrB[niA];     // prefetch next offsets
            if (ndB) tB = *(const int4*)&csrB[niB];
            if (dA) {
                a0A += bflo(uA0); a1A += bfhi(uA0);
                a0A += bflo(uA1); a1A += bfhi(uA1);
                a0A += bflo(uA2); a1A += bfhi(uA2);
                a0A += bflo(uA3); a1A += bfhi(uA3);
            }
            if (dB) {
                a0B += bflo(uB0); a1B += bfhi(uB0);
                a0B += bflo(uB1); a1B += bfhi(uB1);
                a0B += bflo(uB2); a1B += bfhi(uB2);
                a0B += bflo(uB3); a1B += bfhi(uB3);
            }
            oA = tA; oB = tB; iA = niA; iB = niB; dA = ndA; dB = ndB;
        }

        a0A += __shfl_xor(a0A, 32, 64);
        a1A += __shfl_xor(a1A, 32, 64);
        a0B += __shfl_xor(a0B, 32, 64);
        a1B += __shfl_xor(a1B, 32, 64);

        if (r < n) {
            float m0 = half ? a0B : a0A;
            float m1 = half ? a1B : a1A;
            float d = (float)dg;
            d = d > 1.f ? d : 1.f;
            float inv = 1.f / d;
            float v0 = m0 * inv + bflo(cu) + bv.x;
            float v1 = m1 * inv + bfhi(cu) + bv.y;
            v0 = v0 > 0.f ? v0 : 0.f;
            v1 = v1 > 0.f ? v1 : 0.f;
            unsigned pv = (unsigned)f2bf(v0) | ((unsigned)f2bf(v1) << 16);
            *(unsigned*)&H[(size_t)r * 64 + (c << 1)] = pv;
        }
    }
}

// ---------------- layer-2 GEMM + output GEMM (unchanged) ----------------

__global__ __launch_bounds__(512)
void dual_gemm_b16in(const unsigned short* __restrict__ X, const short* __restrict__ PH,
                     const short* __restrict__ PL, unsigned short* __restrict__ Yl,
                     unsigned short* __restrict__ Yr, int n)
{
    constexpr int NKT = 2;
    __shared__ unsigned short sT[8][16 * 72];
    const int lane = threadIdx.x & 63;
    const int wid  = threadIdx.x >> 6;
    const long ntile = ((long)n + 15) >> 4;
    long t = (long)blockIdx.x * 8 + wid;
    if (t >= ntile) return;
    const long rbase = t << 4;
    long arow = rbase + (lane & 15);
    if (arow >= n) arow = n - 1;
    const int koff = (lane >> 4) << 3;
    const unsigned short* xr = X + arow * 64 + koff;

    s16x8 Bv[NKT];
    #pragma unroll
    for (int kt = 0; kt < NKT; ++kt) Bv[kt] = *(const s16x8*)(xr + kt * 32);

    f32x4 acc[2][4];
    #pragma unroll
    for (int m = 0; m < 2; ++m)
        #pragma unroll
        for (int ct = 0; ct < 4; ++ct) acc[m][ct] = (f32x4)(0.f);

    #pragma unroll
    for (int m = 0; m < 2; ++m)
    #pragma unroll
    for (int ct = 0; ct < 4; ++ct)
    #pragma unroll
    for (int kt = 0; kt < NKT; ++kt) {
        const int fidx = ((((m << 2) | ct) * NKT) + kt) * 64 + lane;
        s16x8 Ah = *(const s16x8*)(PH + (size_t)fidx * 8);
        s16x8 Al = *(const s16x8*)(PL + (size_t)fidx * 8);
        acc[m][ct] = __builtin_amdgcn_mfma_f32_16x16x32_bf16(Ah, Bv[kt], acc[m][ct], 0, 0, 0);
        acc[m][ct] = __builtin_amdgcn_mfma_f32_16x16x32_bf16(Al, Bv[kt], acc[m][ct], 0, 0, 0);
    }

    const int wrow = lane & 15, q4 = (lane >> 4) << 2;
    #pragma unroll
    for (int m = 0; m < 2; ++m) {
        unsigned short* __restrict__ Y = m ? Yr : Yl;
        #pragma unroll
        for (int ct = 0; ct < 4; ++ct) {
            s16x4 pv;
            #pragma unroll
            for (int j = 0; j < 4; ++j) pv[j] = (short)f2bf(acc[m][ct][j]);
            *(s16x4*)&sT[wid][wrow * 72 + ct * 16 + q4] = pv;
        }
        asm volatile("s_waitcnt lgkmcnt(0)" ::: "memory");
        if (rbase + 16 <= (long)n) {
            #pragma unroll
            for (int s = 0; s < 2; ++s) {
                int f = s * 64 + lane;
                s16x8 v = *(const s16x8*)&sT[wid][(f >> 3) * 72 + ((f & 7) << 3)];
                *(s16x8*)&Y[rbase * 64 + (size_t)f * 8] = v;
            }
        } else {
            #pragma unroll
            for (int s = 0; s < 2; ++s) {
                int f = s * 64 + lane;
                s16x8 v = *(const s16x8*)&sT[wid][(f >> 3) * 72 + ((f & 7) << 3)];
                long g = rbase * 64 + (size_t)f * 8;
                #pragma unroll
                for (int jj = 0; jj < 8; ++jj)
                    if (g + jj < (long)n * 64) Y[g + jj] = (unsigned short)v[jj];
            }
        }
        asm volatile("s_waitcnt lgkmcnt(0)" ::: "memory");
    }
}

__global__ __launch_bounds__(512)
void gemm_out_mfma(const unsigned short* __restrict__ X, const short* __restrict__ PH,
                   const short* __restrict__ PL, const float* __restrict__ bo,
                   float* __restrict__ Y, int n)
{
    constexpr int NCT = 7;
    __shared__ float sT[8][16 * 120];
    const int lane = threadIdx.x & 63;
    const int wid  = threadIdx.x >> 6;
    const long ntile = ((long)n + 15) >> 4;
    long t = (long)blockIdx.x * 8 + wid;
    if (t >= ntile) return;
    const long rbase = t << 4;
    long arow = rbase + (lane & 15);
    if (arow >= n) arow = n - 1;
    const int koff = (lane >> 4) << 3;
    const unsigned short* xr = X + arow * 64 + koff;

    s16x8 Bv[2];
    #pragma unroll
    for (int kt = 0; kt < 2; ++kt) Bv[kt] = *(const s16x8*)(xr + kt * 32);

    f32x4 acc[NCT];
    #pragma unroll
    for (int ct = 0; ct < NCT; ++ct) acc[ct] = (f32x4)(0.f);

    #pragma unroll
    for (int ct = 0; ct < NCT; ++ct)
    #pragma unroll
    for (int kt = 0; kt < 2; ++kt) {
        const int fidx = (ct * 2 + kt) * 64 + lane;
        s16x8 Ah = *(const s16x8*)(PH + (size_t)fidx * 8);
        s16x8 Al = *(const s16x8*)(PL + (size_t)fidx * 8);
        acc[ct] = __builtin_amdgcn_mfma_f32_16x16x32_bf16(Ah, Bv[kt], acc[ct], 0, 0, 0);
        acc[ct] = __builtin_amdgcn_mfma_f32_16x16x32_bf16(Al, Bv[kt], acc[ct], 0, 0, 0);
    }

    const int wrow = lane & 15, q4 = (lane >> 4) << 2;
    #pragma unroll
    for (int ct = 0; ct < NCT; ++ct)
        *(f32x4*)&sT[wid][wrow * 120 + ct * 16 + q4] = acc[ct];
    asm volatile("s_waitcnt lgkmcnt(0)" ::: "memory");

    if (rbase + 16 <= (long)n) {
        #pragma unroll
        for (int s = 0; s < 7; ++s) {
            int f = s * 64 + lane;
            int row = f / 28, ch = f % 28;
            f32x4 v = *(const f32x4*)&sT[wid][row * 120 + ch * 4];
            f32x4 bv = *(const f32x4*)&bo[ch * 4];
            v.x += bv.x; v.y += bv.y; v.z += bv.z; v.w += bv.w;
            *(f32x4*)&Y[rbase * 112 + (size_t)f * 4] = v;
        }
    } else {
        #pragma unroll
        for (int s = 0; s < 7; ++s) {
            int f = s * 64 + lane;
            int row = f / 28, ch = f % 28;
            f32x4 v = *(const f32x4*)&sT[wid][row * 120 + ch * 4];
            #pragma unroll
            for (int jj = 0; jj < 4; ++jj) {
                long g = rbase * 112 + (size_t)f * 4 + jj;
                if (g < (long)n * 112) Y[g] = v[jj] + bo[ch * 4 + jj];
            }
        }
    }
}

// ---------------- launch ----------------

extern "C" void kernel_launch(void* const* d_in, const int* in_sizes, int n_in,
                              void* d_out, int out_size, void* d_ws, size_t ws_size,
                              hipStream_t stream)
{
    const float* x   = (const float*)d_in[0];
    const int*   ei  = (const int*)d_in[1];
    const float* W1l = (const float*)d_in[2];
    const float* b1  = (const float*)d_in[3];
    const float* W1r = (const float*)d_in[4];
    const float* W2l = (const float*)d_in[5];
    const float* b2  = (const float*)d_in[6];
    const float* W2r = (const float*)d_in[7];
    const float* Wo  = (const float*)d_in[8];
    const float* bo  = (const float*)d_in[9];
    float* out = (float*)d_out;

    const int n = in_sizes[0] / 128;
    const int E = in_sizes[1] / 2;
    const int* srcI = ei;
    const int* dstI = ei + E;
    const int nchunk = (n + 1023) / 1024;
    const int nbkt   = (n + 511) >> 9;
    const size_t nn64 = (size_t)n * 64;
    const size_t csrCap = (size_t)E + (size_t)8 * n + 16;   // padded capacity

    unsigned short* A = (unsigned short*)d_ws;    // (n+1)*64 bf16 (row n = dummy zeros)
    unsigned short* C = A + nn64 + 64;            // n*64 bf16
    unsigned short* H = C + nn64;                 // n*64 bf16
    int*   rowptrP= (int*)(H + nn64);             // n+1 (padded positions)
    int*   degi   = rowptrP + n + 1;              // n (real degrees)
    int*   partial= degi + n;                     // 130
    int*   csr    = partial + 130;                // csrCap (byte offsets)
    int*   packed = csr + csrCap;                 // E
    int*   gcount = packed + E;                   // nbkt
    int*   gbase  = gcount + nbkt;                // nbkt+1
    int*   gcursor= gbase + nbkt + 1;             // nbkt
    short* PH1    = (short*)(gcursor + nbkt);     // 16384
    short* PL1    = PH1 + 16384;
    short* PH2    = PL1 + 16384;                  // 8192
    short* PL2    = PH2 + 8192;
    short* PHo    = PL2 + 8192;                   // 7168
    short* PLo    = PHo + 7168;

    const long ntile = ((long)n + 15) >> 4;
    const int gmf = (int)((ntile + 7) / 8);
    const int cntBlocks = (int)((E + 8191) / 8192);

    // ---- prep ----
    hipMemsetAsync(gcount, 0, (size_t)nbkt * sizeof(int), stream);
    pack_frags<<<16, 256, 0, stream>>>(W1l, W1r, W2l, W2r, Wo, PH1, PL1, PH2, PL2, PHo, PLo);

    // ---- GEMM1 overlapped with bucket_count ----
    fused_gemm1_count<<<gmf + cntBlocks, 512, 0, stream>>>(
        x, PH1, PL1, A, C, n, dstI, gcount, E, nbkt, gmf);

    // ---- CSR build (padded lists) ----
    bucket_scan<<<1, 256, 0, stream>>>(gcount, gbase, gcursor, nbkt, E);
    bucket_scatter<<<(int)((E + 4095) / 4096), 256, 0, stream>>>(srcI, dstI, gcursor, packed, E, nbkt);
    bucket_hist<<<nbkt, 256, 0, stream>>>(packed, gbase, degi, n);
    scan_chunk<<<nchunk, 256, 0, stream>>>(degi, rowptrP, partial, n);
    scan_partials<<<1, 64, 0, stream>>>(partial, nchunk);
    finalize_rowptr<<<(n + 256) / 256, 256, 0, stream>>>(rowptrP, partial,
                                                         (unsigned*)(A + nn64), n);
    bucket_fill<<<nbkt, 256, 0, stream>>>(packed, gbase, rowptrP, csr, n, n << 7);

    // ---- layer 1 aggregation ----
    pull_agg_pad<<<4096, 256, 0, stream>>>(A, rowptrP, degi, csr, C, b1, H, n);

    // ---- layer 2 ----
    dual_gemm_b16in<<<gmf, 512, 0, stream>>>(H, PH2, PL2, A, C, n);   // writes rows < n only
    pull_agg_pad<<<4096, 256, 0, stream>>>(A, rowptrP, degi, csr, C, b2, H, n);

    // ---- output projection ----
    gemm_out_mfma<<<gmf, 512, 0, stream>>>(H, PHo, PLo, bo, out, n);
}